// Round 11
// baseline (488.500 us; speedup 1.0000x reference)
//
#include <hip/hip_runtime.h>
#include <hip/hip_fp16.h>
#include <math.h>
#include <stdint.h>

#define NN 100000
#define NE 1600000
#define INC 128
#define DIM 64
#define EPS 1e-5f
#define SB 512    // stats blocks inside fused stats+hist kernel
#define NREP 8    // stats accumulator replicas (atomic-contention spreading)
#define NPART 8   // scatter partitions (~1 per XCD; write set 12.8MB/8 = 1.6MB < 4MB L2)
#define PART_SZ ((NN + NPART - 1) / NPART)
#define XB 12500  // xhat blocks fused into scatter dispatch (NN*INC/4/256)

struct __align__(8)  half4 { __half2 a, b; };
struct __align__(16) half8 { __half2 a, b, c, d; };

// fused: blocks [0,SB) do X stats (C=128) in f64; blocks [SB,...) do dst histogram
__global__ __launch_bounds__(256) void stats_hist_kernel(const float* __restrict__ X,
        const int* __restrict__ dst, int* __restrict__ counts,
        double* __restrict__ sum_out, double* __restrict__ sq_out) {
    __shared__ double ls[256], lq[256];
    if (blockIdx.x < SB) {
        int c  = threadIdx.x & 127;
        int rl = threadIdx.x >> 7;           // 2 rows per block step
        int row = blockIdx.x * 2 + rl;
        const int rstride = SB * 2;
        double s = 0.0, q = 0.0;
        for (int r = row; r < NN; r += rstride) {
            double v = (double)X[(size_t)r * INC + c];
            s += v; q += v * v;
        }
        ls[threadIdx.x] = s; lq[threadIdx.x] = q;
        __syncthreads();
        if (rl == 0) {
            s += ls[128 + c]; q += lq[128 + c];
            int rep = blockIdx.x & (NREP - 1);
            atomicAdd(&sum_out[rep * INC + c], s);
            atomicAdd(&sq_out[rep * INC + c], q);
        }
    } else {
        int e = (blockIdx.x - SB) * 256 + threadIdx.x;
        if (e < NE) atomicAdd(&counts[dst[e]], 1);
    }
}

// BN scale/shift from NREP-replicated f64 stats
template<int C>
__device__ inline void bn_fold_rep(int t, const double* dsum, const double* dsq,
                                   const float* g, const float* b, float* sc_s, float* sh_s) {
    if (t < C) {
        double s = 0.0, q = 0.0;
        #pragma unroll
        for (int r = 0; r < NREP; r++) { s += dsum[r * C + t]; q += dsq[r * C + t]; }
        double m = s / (double)NN;
        double v = q / (double)NN - m * m;
        double sc = (double)g[t] / sqrt(v + (double)EPS);
        sc_s[t] = (float)sc;
        sh_s[t] = (float)((double)b[t] - m * sc);
    }
}

// ---------------- CSR build: scan ----------------
__global__ __launch_bounds__(1024) void scan1_kernel(const int* __restrict__ counts,
                                                     int* __restrict__ offs, int* __restrict__ bsums) {
    __shared__ int tmp[2][1024];
    int t = threadIdx.x;
    int g = blockIdx.x * 1024 + t;
    int v = (g < NN) ? counts[g] : 0;
    tmp[0][t] = v;
    __syncthreads();
    int pin = 0;
    for (int d = 1; d < 1024; d <<= 1) {
        int x = tmp[pin][t] + ((t >= d) ? tmp[pin][t - d] : 0);
        tmp[pin ^ 1][t] = x;
        pin ^= 1;
        __syncthreads();
    }
    int incl = tmp[pin][t];
    if (g < NN) offs[g] = incl - v;
    if (t == 1023) bsums[blockIdx.x] = incl;
}

__global__ __launch_bounds__(128) void scan2_kernel(int* __restrict__ bsums, int nb) {
    __shared__ int tmp[2][128];
    int t = threadIdx.x;
    int v = (t < nb) ? bsums[t] : 0;
    tmp[0][t] = v;
    __syncthreads();
    int pin = 0;
    for (int d = 1; d < 128; d <<= 1) {
        int x = tmp[pin][t] + ((t >= d) ? tmp[pin][t - d] : 0);
        tmp[pin ^ 1][t] = x;
        pin ^= 1;
        __syncthreads();
    }
    if (t < nb) bsums[t] = tmp[pin][t] - v;
}

// final offsets + per-node scatter cursors
__global__ __launch_bounds__(256) void scan3_kernel(int* __restrict__ offs, const int* __restrict__ bsums,
                                                    int* __restrict__ cursor) {
    int g = blockIdx.x * 256 + threadIdx.x;
    if (g < NN) {
        int o = offs[g] + bsums[g >> 10];
        offs[g] = o;
        cursor[g] = o;
    }
    if (g == 0) offs[NN] = NE;
}

// fused: blocks [0,XB) do x̂->fp16; blocks [XB,...) do XCD-partitioned scatter.
// Both depend only on kernels already complete at launch (stats_hist, scan3).
__global__ __launch_bounds__(256) void xhat_scatter_kernel(const float* __restrict__ X,
        const double* __restrict__ dsum, const double* __restrict__ dsq,
        const float* __restrict__ g, const float* __restrict__ b,
        __half* __restrict__ Xh,
        const int* __restrict__ src, const int* __restrict__ dst,
        const float* __restrict__ ea, int* __restrict__ cursor,
        int2* __restrict__ src_ea) {
    if (blockIdx.x < XB) {
        __shared__ float sc_s[INC], sh_s[INC];
        bn_fold_rep<INC>(threadIdx.x, dsum, dsq, g, b, sc_s, sh_s);
        __syncthreads();
        size_t i = (size_t)blockIdx.x * 256 + threadIdx.x;   // one float4 per thread
        size_t e4 = i * 4;
        if (e4 >= (size_t)NN * INC) return;
        int c = (int)(e4 & 127);
        float4 x = *(const float4*)(X + e4);
        half4 h;
        h.a = __floats2half2_rn(fmaf(x.x, sc_s[c], sh_s[c]), fmaf(x.y, sc_s[c + 1], sh_s[c + 1]));
        h.b = __floats2half2_rn(fmaf(x.z, sc_s[c + 2], sh_s[c + 2]), fmaf(x.w, sc_s[c + 3], sh_s[c + 3]));
        *(half4*)(Xh + e4) = h;
    } else {
        const int bid = blockIdx.x - XB;
        const int p = bid & (NPART - 1);      // consecutive bid -> consecutive XCD (round-robin)
        const int blk = bid >> 3;
        const int nblk = (gridDim.x - XB) >> 3;
        const int lo = p * PART_SZ;
        const int hi = min(NN, lo + PART_SZ);
        for (int e = blk * 256 + threadIdx.x; e < NE; e += nblk * 256) {
            int d = dst[e];
            if (d >= lo && d < hi) {
                int pos = atomicAdd(&cursor[d], 1);
                src_ea[pos] = make_int2(src[e], __float_as_int(ea[e]));
            }
        }
    }
}

// ---------------- fused layer 0: gather-agg (fp16 x̂, quarter-wave, 4-deep MLP) + GEMM + tanh + stats ----------------
// 32 nodes per 512-thread block. t1 -> t1h [NN][64] fp16; per-channel stats -> dsum0/dsq0 (replicated)
__global__ __launch_bounds__(512) void gine0_kernel(const float* __restrict__ X,
        const __half* __restrict__ Xh,
        const int* __restrict__ offs, const int2* __restrict__ src_ea,
        const double* __restrict__ dsum, const double* __restrict__ dsq,
        const float* __restrict__ g, const float* __restrict__ b,
        const float* __restrict__ We, const float* __restrict__ be,
        const float* __restrict__ W, const float* __restrict__ bvec,
        __half* __restrict__ t1h, double* __restrict__ dsum0, double* __restrict__ dsq0) {
    __shared__ __align__(16) float u_s[32][INC + 4];   // 16.9 KB
    __shared__ __align__(16) float w_s[DIM][INC + 4];  // 33.8 KB (reused for stats reduce)
    __shared__ float sc_s[INC], sh_s[INC];
    const int t = threadIdx.x;
    const int row0 = blockIdx.x * 32;
    bn_fold_rep<INC>(t, dsum, dsq, g, b, sc_s, sh_s);
    for (int i = t; i < INC * DIM; i += 512) {
        int k = i >> 6, c = i & 63;
        w_s[c][k] = W[i];
    }
    __syncthreads();
    // gather: 8 waves x 4 nodes; wave split into 4 quarters of 16 lanes, each handles one edge
    const int wid = t >> 6, l = t & 63;
    const int quarter = l >> 4;
    const int c8 = (l & 15) * 8;
    float4 wv0 = *(const float4*)(We + c8);
    float4 wv1 = *(const float4*)(We + c8 + 4);
    float4 bv0 = *(const float4*)(be + c8);
    float4 bv1 = *(const float4*)(be + c8 + 4);
    for (int nn = 0; nn < 4; ++nn) {
        int r = wid * 4 + nn;
        int n = row0 + r;
        float a0 = 0.f, a1 = 0.f, a2 = 0.f, a3 = 0.f, a4 = 0.f, a5 = 0.f, a6 = 0.f, a7 = 0.f;
        if (n < NN) {
            int beg = offs[n], end = offs[n + 1];
            for (int base = beg; base < end; base += 64) {
                int j = base + l;
                int2 p = (j < end) ? src_ea[j] : make_int2(0, 0);
                float avf = __int_as_float(p.y);
                int cnt = min(64, end - base);
                int tt = 0;
                // 4-deep: issue 4 independent half8 loads before consuming
                for (; tt + 16 <= cnt; tt += 16) {
                    int e0 = tt + quarter, e1 = tt + 4 + quarter, e2 = tt + 8 + quarter, e3 = tt + 12 + quarter;
                    int s0 = __shfl(p.x, e0), s1 = __shfl(p.x, e1), s2 = __shfl(p.x, e2), s3 = __shfl(p.x, e3);
                    float av0 = __shfl(avf, e0), av1 = __shfl(avf, e1), av2 = __shfl(avf, e2), av3 = __shfl(avf, e3);
                    half8 v0 = *(const half8*)(Xh + (size_t)s0 * INC + c8);
                    half8 v1 = *(const half8*)(Xh + (size_t)s1 * INC + c8);
                    half8 v2 = *(const half8*)(Xh + (size_t)s2 * INC + c8);
                    half8 v3 = *(const half8*)(Xh + (size_t)s3 * INC + c8);
                    float2 f0, f1, f2, f3;
                    f0 = __half22float2(v0.a); f1 = __half22float2(v0.b);
                    f2 = __half22float2(v0.c); f3 = __half22float2(v0.d);
                    a0 += fmaxf(f0.x + fmaf(av0, wv0.x, bv0.x), 0.f);
                    a1 += fmaxf(f0.y + fmaf(av0, wv0.y, bv0.y), 0.f);
                    a2 += fmaxf(f1.x + fmaf(av0, wv0.z, bv0.z), 0.f);
                    a3 += fmaxf(f1.y + fmaf(av0, wv0.w, bv0.w), 0.f);
                    a4 += fmaxf(f2.x + fmaf(av0, wv1.x, bv1.x), 0.f);
                    a5 += fmaxf(f2.y + fmaf(av0, wv1.y, bv1.y), 0.f);
                    a6 += fmaxf(f3.x + fmaf(av0, wv1.z, bv1.z), 0.f);
                    a7 += fmaxf(f3.y + fmaf(av0, wv1.w, bv1.w), 0.f);
                    f0 = __half22float2(v1.a); f1 = __half22float2(v1.b);
                    f2 = __half22float2(v1.c); f3 = __half22float2(v1.d);
                    a0 += fmaxf(f0.x + fmaf(av1, wv0.x, bv0.x), 0.f);
                    a1 += fmaxf(f0.y + fmaf(av1, wv0.y, bv0.y), 0.f);
                    a2 += fmaxf(f1.x + fmaf(av1, wv0.z, bv0.z), 0.f);
                    a3 += fmaxf(f1.y + fmaf(av1, wv0.w, bv0.w), 0.f);
                    a4 += fmaxf(f2.x + fmaf(av1, wv1.x, bv1.x), 0.f);
                    a5 += fmaxf(f2.y + fmaf(av1, wv1.y, bv1.y), 0.f);
                    a6 += fmaxf(f3.x + fmaf(av1, wv1.z, bv1.z), 0.f);
                    a7 += fmaxf(f3.y + fmaf(av1, wv1.w, bv1.w), 0.f);
                    f0 = __half22float2(v2.a); f1 = __half22float2(v2.b);
                    f2 = __half22float2(v2.c); f3 = __half22float2(v2.d);
                    a0 += fmaxf(f0.x + fmaf(av2, wv0.x, bv0.x), 0.f);
                    a1 += fmaxf(f0.y + fmaf(av2, wv0.y, bv0.y), 0.f);
                    a2 += fmaxf(f1.x + fmaf(av2, wv0.z, bv0.z), 0.f);
                    a3 += fmaxf(f1.y + fmaf(av2, wv0.w, bv0.w), 0.f);
                    a4 += fmaxf(f2.x + fmaf(av2, wv1.x, bv1.x), 0.f);
                    a5 += fmaxf(f2.y + fmaf(av2, wv1.y, bv1.y), 0.f);
                    a6 += fmaxf(f3.x + fmaf(av2, wv1.z, bv1.z), 0.f);
                    a7 += fmaxf(f3.y + fmaf(av2, wv1.w, bv1.w), 0.f);
                    f0 = __half22float2(v3.a); f1 = __half22float2(v3.b);
                    f2 = __half22float2(v3.c); f3 = __half22float2(v3.d);
                    a0 += fmaxf(f0.x + fmaf(av3, wv0.x, bv0.x), 0.f);
                    a1 += fmaxf(f0.y + fmaf(av3, wv0.y, bv0.y), 0.f);
                    a2 += fmaxf(f1.x + fmaf(av3, wv0.z, bv0.z), 0.f);
                    a3 += fmaxf(f1.y + fmaf(av3, wv0.w, bv0.w), 0.f);
                    a4 += fmaxf(f2.x + fmaf(av3, wv1.x, bv1.x), 0.f);
                    a5 += fmaxf(f2.y + fmaf(av3, wv1.y, bv1.y), 0.f);
                    a6 += fmaxf(f3.x + fmaf(av3, wv1.z, bv1.z), 0.f);
                    a7 += fmaxf(f3.y + fmaf(av3, wv1.w, bv1.w), 0.f);
                }
                for (; tt < cnt; tt += 4) {
                    int e0 = tt + quarter;
                    int es = min(e0, cnt - 1);
                    int s0 = __shfl(p.x, es);
                    float av0 = __shfl(avf, es);
                    if (e0 < cnt) {
                        half8 v0 = *(const half8*)(Xh + (size_t)s0 * INC + c8);
                        float2 f0 = __half22float2(v0.a), f1 = __half22float2(v0.b);
                        float2 f2 = __half22float2(v0.c), f3 = __half22float2(v0.d);
                        a0 += fmaxf(f0.x + fmaf(av0, wv0.x, bv0.x), 0.f);
                        a1 += fmaxf(f0.y + fmaf(av0, wv0.y, bv0.y), 0.f);
                        a2 += fmaxf(f1.x + fmaf(av0, wv0.z, bv0.z), 0.f);
                        a3 += fmaxf(f1.y + fmaf(av0, wv0.w, bv0.w), 0.f);
                        a4 += fmaxf(f2.x + fmaf(av0, wv1.x, bv1.x), 0.f);
                        a5 += fmaxf(f2.y + fmaf(av0, wv1.y, bv1.y), 0.f);
                        a6 += fmaxf(f3.x + fmaf(av0, wv1.z, bv1.z), 0.f);
                        a7 += fmaxf(f3.y + fmaf(av0, wv1.w, bv1.w), 0.f);
                    }
                }
            }
        }
        // combine quarters
        a0 += __shfl_xor(a0, 16); a0 += __shfl_xor(a0, 32);
        a1 += __shfl_xor(a1, 16); a1 += __shfl_xor(a1, 32);
        a2 += __shfl_xor(a2, 16); a2 += __shfl_xor(a2, 32);
        a3 += __shfl_xor(a3, 16); a3 += __shfl_xor(a3, 32);
        a4 += __shfl_xor(a4, 16); a4 += __shfl_xor(a4, 32);
        a5 += __shfl_xor(a5, 16); a5 += __shfl_xor(a5, 32);
        a6 += __shfl_xor(a6, 16); a6 += __shfl_xor(a6, 32);
        a7 += __shfl_xor(a7, 16); a7 += __shfl_xor(a7, 32);
        if (quarter == 0) {
            if (n < NN) {
                // self term from f32 X for precision
                float4 x0 = *(const float4*)(X + (size_t)n * INC + c8);
                float4 x1 = *(const float4*)(X + (size_t)n * INC + c8 + 4);
                a0 += fmaf(x0.x, sc_s[c8],     sh_s[c8]);
                a1 += fmaf(x0.y, sc_s[c8 + 1], sh_s[c8 + 1]);
                a2 += fmaf(x0.z, sc_s[c8 + 2], sh_s[c8 + 2]);
                a3 += fmaf(x0.w, sc_s[c8 + 3], sh_s[c8 + 3]);
                a4 += fmaf(x1.x, sc_s[c8 + 4], sh_s[c8 + 4]);
                a5 += fmaf(x1.y, sc_s[c8 + 5], sh_s[c8 + 5]);
                a6 += fmaf(x1.z, sc_s[c8 + 6], sh_s[c8 + 6]);
                a7 += fmaf(x1.w, sc_s[c8 + 7], sh_s[c8 + 7]);
            }
            *(float4*)&u_s[r][c8]     = make_float4(a0, a1, a2, a3);
            *(float4*)&u_s[r][c8 + 4] = make_float4(a4, a5, a6, a7);
        }
    }
    __syncthreads();
    // GEMM: 32x64 outputs, 512 threads -> 4 outputs each
    const int cc = t & 15;
    const int rg = t >> 4;                 // row 0..31
    float acc0 = bvec[cc], acc1 = bvec[cc + 16], acc2 = bvec[cc + 32], acc3 = bvec[cc + 48];
    #pragma unroll 4
    for (int k = 0; k < INC; k += 4) {
        float4 w0 = *(const float4*)&w_s[cc][k];
        float4 w1 = *(const float4*)&w_s[cc + 16][k];
        float4 w2 = *(const float4*)&w_s[cc + 32][k];
        float4 w3 = *(const float4*)&w_s[cc + 48][k];
        float4 u = *(const float4*)&u_s[rg][k];
        acc0 = fmaf(u.x, w0.x, fmaf(u.y, w0.y, fmaf(u.z, w0.z, fmaf(u.w, w0.w, acc0))));
        acc1 = fmaf(u.x, w1.x, fmaf(u.y, w1.y, fmaf(u.z, w1.z, fmaf(u.w, w1.w, acc1))));
        acc2 = fmaf(u.x, w2.x, fmaf(u.y, w2.y, fmaf(u.z, w2.z, fmaf(u.w, w2.w, acc2))));
        acc3 = fmaf(u.x, w3.x, fmaf(u.y, w3.y, fmaf(u.z, w3.z, fmaf(u.w, w3.w, acc3))));
    }
    int rr = row0 + rg;
    float t0 = tanhf(acc0), t1v = tanhf(acc1), t2v = tanhf(acc2), t3v = tanhf(acc3);
    if (rr < NN) {
        __half* op = t1h + (size_t)rr * DIM;
        op[cc]      = __float2half_rn(t0);
        op[cc + 16] = __float2half_rn(t1v);
        op[cc + 32] = __float2half_rn(t2v);
        op[cc + 48] = __float2half_rn(t3v);
    }
    // fused per-channel stats from f32 values (reuse w_s as [32 rows][64 cols] x2)
    __syncthreads();
    float* red_s = (float*)w_s;
    float* red_q = red_s + 2048;
    bool ok = (rr < NN);
    red_s[rg * 64 + cc]      = ok ? t0 : 0.f;
    red_s[rg * 64 + cc + 16] = ok ? t1v : 0.f;
    red_s[rg * 64 + cc + 32] = ok ? t2v : 0.f;
    red_s[rg * 64 + cc + 48] = ok ? t3v : 0.f;
    red_q[rg * 64 + cc]      = ok ? t0 * t0 : 0.f;
    red_q[rg * 64 + cc + 16] = ok ? t1v * t1v : 0.f;
    red_q[rg * 64 + cc + 32] = ok ? t2v * t2v : 0.f;
    red_q[rg * 64 + cc + 48] = ok ? t3v * t3v : 0.f;
    __syncthreads();
    if (t < 64) {
        float s = 0.f, q = 0.f;
        #pragma unroll
        for (int i = 0; i < 32; i++) { s += red_s[i * 64 + t]; q += red_q[i * 64 + t]; }
        int rep = blockIdx.x & (NREP - 1);
        atomicAdd(&dsum0[rep * DIM + t], (double)s);
        atomicAdd(&dsq0[rep * DIM + t], (double)q);
    }
}

// ---------------- fused layer 1: BN(fp16 t1) on the fly + h1 write + gather-agg (4-deep) + GEMM + tanh + stats ----------------
// 64 nodes per 512-thread block. reads t1h fp16; h1 -> out[:,0:64]; t2 -> out[:,64:128]
__global__ __launch_bounds__(512) void gine1_kernel(const __half* __restrict__ t1h,
        const int* __restrict__ offs, const int2* __restrict__ src_ea,
        const double* __restrict__ dsum, const double* __restrict__ dsq,
        const float* __restrict__ g, const float* __restrict__ b,
        const float* __restrict__ We, const float* __restrict__ be,
        const float* __restrict__ W, const float* __restrict__ bvec,
        float* __restrict__ out, double* __restrict__ dsum1, double* __restrict__ dsq1) {
    __shared__ __align__(16) float u_s[64][DIM + 4];   // 17.4 KB
    __shared__ __align__(16) float w_s[DIM][DIM + 4];  // 17.4 KB (reused for stats reduce)
    __shared__ float sc_s[DIM], sh_s[DIM];
    const int t = threadIdx.x;
    const int row0 = blockIdx.x * 64;
    bn_fold_rep<DIM>(t, dsum, dsq, g, b, sc_s, sh_s);
    for (int i = t; i < DIM * DIM; i += 512) {
        int k = i >> 6, c = i & 63;
        w_s[c][k] = W[i];
    }
    __syncthreads();
    const int wid = t >> 6, l = t & 63;
    const int quarter = l >> 4;
    const int c4 = (l & 15) * 4;
    float4 wv = *(const float4*)(We + c4);
    float4 bv = *(const float4*)(be + c4);
    float4 sc4 = *(const float4*)(sc_s + c4);
    float4 sh4 = *(const float4*)(sh_s + c4);
    for (int nn = 0; nn < 8; ++nn) {
        int r = wid * 8 + nn;
        int n = row0 + r;
        float a0 = 0.f, a1 = 0.f, a2 = 0.f, a3 = 0.f;
        if (n < NN) {
            int beg = offs[n], end = offs[n + 1];
            for (int base = beg; base < end; base += 64) {
                int j = base + l;
                int2 p = (j < end) ? src_ea[j] : make_int2(0, 0);
                float avf = __int_as_float(p.y);
                int cnt = min(64, end - base);
                int tt = 0;
                for (; tt + 16 <= cnt; tt += 16) {
                    int e0 = tt + quarter, e1 = tt + 4 + quarter, e2 = tt + 8 + quarter, e3 = tt + 12 + quarter;
                    int s0 = __shfl(p.x, e0), s1 = __shfl(p.x, e1), s2 = __shfl(p.x, e2), s3 = __shfl(p.x, e3);
                    float av0 = __shfl(avf, e0), av1 = __shfl(avf, e1), av2 = __shfl(avf, e2), av3 = __shfl(avf, e3);
                    half4 v0 = *(const half4*)(t1h + (size_t)s0 * DIM + c4);
                    half4 v1 = *(const half4*)(t1h + (size_t)s1 * DIM + c4);
                    half4 v2 = *(const half4*)(t1h + (size_t)s2 * DIM + c4);
                    half4 v3 = *(const half4*)(t1h + (size_t)s3 * DIM + c4);
                    float2 f00 = __half22float2(v0.a), f01 = __half22float2(v0.b);
                    a0 += fmaxf(fmaf(f00.x, sc4.x, sh4.x) + fmaf(av0, wv.x, bv.x), 0.f);
                    a1 += fmaxf(fmaf(f00.y, sc4.y, sh4.y) + fmaf(av0, wv.y, bv.y), 0.f);
                    a2 += fmaxf(fmaf(f01.x, sc4.z, sh4.z) + fmaf(av0, wv.z, bv.z), 0.f);
                    a3 += fmaxf(fmaf(f01.y, sc4.w, sh4.w) + fmaf(av0, wv.w, bv.w), 0.f);
                    f00 = __half22float2(v1.a); f01 = __half22float2(v1.b);
                    a0 += fmaxf(fmaf(f00.x, sc4.x, sh4.x) + fmaf(av1, wv.x, bv.x), 0.f);
                    a1 += fmaxf(fmaf(f00.y, sc4.y, sh4.y) + fmaf(av1, wv.y, bv.y), 0.f);
                    a2 += fmaxf(fmaf(f01.x, sc4.z, sh4.z) + fmaf(av1, wv.z, bv.z), 0.f);
                    a3 += fmaxf(fmaf(f01.y, sc4.w, sh4.w) + fmaf(av1, wv.w, bv.w), 0.f);
                    f00 = __half22float2(v2.a); f01 = __half22float2(v2.b);
                    a0 += fmaxf(fmaf(f00.x, sc4.x, sh4.x) + fmaf(av2, wv.x, bv.x), 0.f);
                    a1 += fmaxf(fmaf(f00.y, sc4.y, sh4.y) + fmaf(av2, wv.y, bv.y), 0.f);
                    a2 += fmaxf(fmaf(f01.x, sc4.z, sh4.z) + fmaf(av2, wv.z, bv.z), 0.f);
                    a3 += fmaxf(fmaf(f01.y, sc4.w, sh4.w) + fmaf(av2, wv.w, bv.w), 0.f);
                    f00 = __half22float2(v3.a); f01 = __half22float2(v3.b);
                    a0 += fmaxf(fmaf(f00.x, sc4.x, sh4.x) + fmaf(av3, wv.x, bv.x), 0.f);
                    a1 += fmaxf(fmaf(f00.y, sc4.y, sh4.y) + fmaf(av3, wv.y, bv.y), 0.f);
                    a2 += fmaxf(fmaf(f01.x, sc4.z, sh4.z) + fmaf(av3, wv.z, bv.z), 0.f);
                    a3 += fmaxf(fmaf(f01.y, sc4.w, sh4.w) + fmaf(av3, wv.w, bv.w), 0.f);
                }
                for (; tt < cnt; tt += 4) {
                    int e0 = tt + quarter;
                    int es = min(e0, cnt - 1);
                    int s0 = __shfl(p.x, es);
                    float av0 = __shfl(avf, es);
                    if (e0 < cnt) {
                        half4 v0 = *(const half4*)(t1h + (size_t)s0 * DIM + c4);
                        float2 f00 = __half22float2(v0.a), f01 = __half22float2(v0.b);
                        a0 += fmaxf(fmaf(f00.x, sc4.x, sh4.x) + fmaf(av0, wv.x, bv.x), 0.f);
                        a1 += fmaxf(fmaf(f00.y, sc4.y, sh4.y) + fmaf(av0, wv.y, bv.y), 0.f);
                        a2 += fmaxf(fmaf(f01.x, sc4.z, sh4.z) + fmaf(av0, wv.z, bv.z), 0.f);
                        a3 += fmaxf(fmaf(f01.y, sc4.w, sh4.w) + fmaf(av0, wv.w, bv.w), 0.f);
                    }
                }
            }
        }
        a0 += __shfl_xor(a0, 16); a0 += __shfl_xor(a0, 32);
        a1 += __shfl_xor(a1, 16); a1 += __shfl_xor(a1, 32);
        a2 += __shfl_xor(a2, 16); a2 += __shfl_xor(a2, 32);
        a3 += __shfl_xor(a3, 16); a3 += __shfl_xor(a3, 32);
        if (quarter == 0) {
            if (n < NN) {
                half4 h = *(const half4*)(t1h + (size_t)n * DIM + c4);
                float2 f0 = __half22float2(h.a), f1 = __half22float2(h.b);
                float h0 = fmaf(f0.x, sc4.x, sh4.x);
                float h1 = fmaf(f0.y, sc4.y, sh4.y);
                float h2 = fmaf(f1.x, sc4.z, sh4.z);
                float h3 = fmaf(f1.y, sc4.w, sh4.w);
                *(float4*)(out + (size_t)n * 192 + c4) = make_float4(h0, h1, h2, h3);   // h1
                a0 += h0; a1 += h1; a2 += h2; a3 += h3;
            }
            *(float4*)&u_s[r][c4] = make_float4(a0, a1, a2, a3);
        }
    }
    __syncthreads();
    // GEMM: 64x64 outputs, 512 threads -> 8 outputs each (2 rows x 4 cols)
    const int cc = t & 15;
    const int r0 = (t >> 4) * 2;
    float acc[2][4];
    #pragma unroll
    for (int j = 0; j < 4; j++) {
        float bj = bvec[cc + 16 * j];
        acc[0][j] = bj; acc[1][j] = bj;
    }
    #pragma unroll 4
    for (int k = 0; k < DIM; k += 4) {
        float4 w0 = *(const float4*)&w_s[cc][k];
        float4 w1 = *(const float4*)&w_s[cc + 16][k];
        float4 w2 = *(const float4*)&w_s[cc + 32][k];
        float4 w3 = *(const float4*)&w_s[cc + 48][k];
        #pragma unroll
        for (int i = 0; i < 2; i++) {
            float4 u = *(const float4*)&u_s[r0 + i][k];
            acc[i][0] = fmaf(u.x, w0.x, fmaf(u.y, w0.y, fmaf(u.z, w0.z, fmaf(u.w, w0.w, acc[i][0]))));
            acc[i][1] = fmaf(u.x, w1.x, fmaf(u.y, w1.y, fmaf(u.z, w1.z, fmaf(u.w, w1.w, acc[i][1]))));
            acc[i][2] = fmaf(u.x, w2.x, fmaf(u.y, w2.y, fmaf(u.z, w2.z, fmaf(u.w, w2.w, acc[i][2]))));
            acc[i][3] = fmaf(u.x, w3.x, fmaf(u.y, w3.y, fmaf(u.z, w3.z, fmaf(u.w, w3.w, acc[i][3]))));
        }
    }
    float tv[2][4];
    #pragma unroll
    for (int i = 0; i < 2; i++) {
        int rr = row0 + r0 + i;
        #pragma unroll
        for (int j = 0; j < 4; j++) tv[i][j] = tanhf(acc[i][j]);
        if (rr < NN) {
            float* op = out + (size_t)rr * 192 + 64;
            #pragma unroll
            for (int j = 0; j < 4; j++) op[cc + 16 * j] = tv[i][j];
        }
    }
    // fused per-channel stats of t2 (reuse w_s as [32 rowgrps][64 cols] x2)
    __syncthreads();
    float* red_s = (float*)w_s;
    float* red_q = red_s + 2048;
    const int rgp = t >> 4;
    bool ok0 = (row0 + r0 < NN), ok1 = (row0 + r0 + 1 < NN);
    #pragma unroll
    for (int j = 0; j < 4; j++) {
        float v0 = ok0 ? tv[0][j] : 0.f;
        float v1 = ok1 ? tv[1][j] : 0.f;
        red_s[rgp * 64 + cc + 16 * j] = v0 + v1;
        red_q[rgp * 64 + cc + 16 * j] = v0 * v0 + v1 * v1;
    }
    __syncthreads();
    if (t < 64) {
        float s = 0.f, q = 0.f;
        #pragma unroll
        for (int i = 0; i < 32; i++) { s += red_s[i * 64 + t]; q += red_q[i * 64 + t]; }
        int rep = blockIdx.x & (NREP - 1);
        atomicAdd(&dsum1[rep * DIM + t], (double)s);
        atomicAdd(&dsq1[rep * DIM + t], (double)q);
    }
}

// ---------------- fused: finalize1 + h2 = BN(t2) in place + h3 = tanh(h2 @ Wfc) ----------------
__global__ __launch_bounds__(256) void fc_kernel(float* __restrict__ io,
        const double* __restrict__ dsum, const double* __restrict__ dsq,
        const float* __restrict__ g, const float* __restrict__ b,
        const float* __restrict__ W) {
    __shared__ __align__(16) float u_s[64][DIM + 4];
    __shared__ __align__(16) float w_s[DIM][DIM + 4];
    __shared__ float sc_s[DIM], sh_s[DIM];
    const int t = threadIdx.x;
    const int row0 = blockIdx.x * 64;
    bn_fold_rep<DIM>(t, dsum, dsq, g, b, sc_s, sh_s);
    __syncthreads();
    for (int i = t; i < DIM * DIM; i += 256) {
        int k = i >> 6, c = i & 63;
        w_s[c][k] = W[i];
    }
    for (int i = t; i < 64 * DIM; i += 256) {
        int r = i >> 6, k = i & 63;
        int rr = row0 + r;
        float v = 0.f;
        if (rr < NN) {
            size_t idx = (size_t)rr * 192 + 64 + k;
            v = fmaf(io[idx], sc_s[k], sh_s[k]);
            io[idx] = v;                       // h2
        }
        u_s[r][k] = v;
    }
    __syncthreads();
    const int cc = t & 15;
    const int r0 = (t >> 4) << 2;
    float acc[4][4];
    #pragma unroll
    for (int j = 0; j < 4; j++) { acc[0][j] = 0.f; acc[1][j] = 0.f; acc[2][j] = 0.f; acc[3][j] = 0.f; }
    #pragma unroll 4
    for (int k = 0; k < DIM; k += 4) {
        float4 w0 = *(const float4*)&w_s[cc][k];
        float4 w1 = *(const float4*)&w_s[cc + 16][k];
        float4 w2 = *(const float4*)&w_s[cc + 32][k];
        float4 w3 = *(const float4*)&w_s[cc + 48][k];
        #pragma unroll
        for (int i = 0; i < 4; i++) {
            float4 u = *(const float4*)&u_s[r0 + i][k];
            acc[i][0] = fmaf(u.x, w0.x, fmaf(u.y, w0.y, fmaf(u.z, w0.z, fmaf(u.w, w0.w, acc[i][0]))));
            acc[i][1] = fmaf(u.x, w1.x, fmaf(u.y, w1.y, fmaf(u.z, w1.z, fmaf(u.w, w1.w, acc[i][1]))));
            acc[i][2] = fmaf(u.x, w2.x, fmaf(u.y, w2.y, fmaf(u.z, w2.z, fmaf(u.w, w2.w, acc[i][2]))));
            acc[i][3] = fmaf(u.x, w3.x, fmaf(u.y, w3.y, fmaf(u.z, w3.z, fmaf(u.w, w3.w, acc[i][3]))));
        }
    }
    #pragma unroll
    for (int i = 0; i < 4; i++) {
        int rr = row0 + r0 + i;
        if (rr < NN) {
            #pragma unroll
            for (int j = 0; j < 4; j++)
                io[(size_t)rr * 192 + 128 + cc + 16 * j] = tanhf(acc[i][j]);
        }
    }
}

extern "C" void kernel_launch(void* const* d_in, const int* in_sizes, int n_in,
                              void* d_out, int out_size, void* d_ws, size_t ws_size,
                              hipStream_t stream) {
    const float* X      = (const float*)d_in[0];
    const int*   ei     = (const int*)  d_in[1];
    const float* ea     = (const float*)d_in[2];
    const float* bng    = (const float*)d_in[3];
    const float* bnb    = (const float*)d_in[4];
    const float* We0    = (const float*)d_in[5];
    const float* be0    = (const float*)d_in[6];
    const float* W0     = (const float*)d_in[7];
    const float* b0     = (const float*)d_in[8];
    const float* bn0g   = (const float*)d_in[9];
    const float* bn0b   = (const float*)d_in[10];
    const float* We1    = (const float*)d_in[11];
    const float* be1    = (const float*)d_in[12];
    const float* W1     = (const float*)d_in[13];
    const float* b1     = (const float*)d_in[14];
    const float* bn1g   = (const float*)d_in[15];
    const float* bn1b   = (const float*)d_in[16];
    const float* Wfc    = (const float*)d_in[17];

    const int* src = ei;
    const int* dst = ei + NE;
    float* out = (float*)d_out;

    // ---- workspace layout (~52 MB) ----
    int2*   src_ea  = (int2*)d_ws;                        // NE
    __half* t1h     = (__half*)(src_ea + NE);             // NN*DIM halves
    __half* Xh      = t1h + (size_t)NN * DIM;             // NN*INC halves
    int*    counts  = (int*)(Xh + (size_t)NN * INC);      // NN
    int*    offs    = counts + NN;                        // NN+1
    int*    cursor  = offs + NN + 1;                      // NN
    int*    bsums   = cursor + NN;                        // 128
    double* dstats = (double*)(((uintptr_t)(bsums + 128) + 15) & ~(uintptr_t)15);
    double* dsum_in = dstats;                          // NREP*128
    double* dsq_in  = dsum_in + NREP * INC;            // NREP*128
    double* dsum0   = dsq_in + NREP * INC;             // NREP*64
    double* dsq0    = dsum0 + NREP * DIM;              // NREP*64
    double* dsum1   = dsq0 + NREP * DIM;               // NREP*64
    double* dsq1    = dsum1 + NREP * DIM;              // NREP*64
    const size_t nstats = (size_t)NREP * (2 * INC + 4 * DIM);

    hipMemsetAsync(counts, 0, NN * sizeof(int), stream);
    hipMemsetAsync(dstats, 0, nstats * sizeof(double), stream);

    // fused input-BN stats + dst histogram
    stats_hist_kernel<<<SB + (NE + 255) / 256, 256, 0, stream>>>(X, dst, counts, dsum_in, dsq_in);

    // CSR build (shared by both layers)
    const int NB = (NN + 1023) / 1024;   // 98
    scan1_kernel<<<NB, 1024, 0, stream>>>(counts, offs, bsums);
    scan2_kernel<<<1, 128, 0, stream>>>(bsums, NB);
    scan3_kernel<<<(NN + 255) / 256, 256, 0, stream>>>(offs, bsums, cursor);

    // fused x̂->fp16 + XCD-partitioned scatter (both deps satisfied here)
    xhat_scatter_kernel<<<XB + 2048, 256, 0, stream>>>(X, dsum_in, dsq_in, bng, bnb, Xh,
                                                       src, dst, ea, cursor, src_ea);

    // layer 0 (fused agg + GEMM + stats0), gathers fp16 x̂, writes fp16 t1
    gine0_kernel<<<(NN + 31) / 32, 512, 0, stream>>>(X, Xh, offs, src_ea, dsum_in, dsq_in, bng, bnb,
                                                     We0, be0, W0, b0, t1h, dsum0, dsq0);

    // layer 1 (fused finalize0 + BN-on-fly + h1 write + agg + GEMM + stats1), gathers fp16 t1
    gine1_kernel<<<(NN + 63) / 64, 512, 0, stream>>>(t1h, offs, src_ea, dsum0, dsq0, bn0g, bn0b,
                                                     We1, be1, W1, b1, out, dsum1, dsq1);

    // h2 (in place) + h3 (fused finalize1)
    fc_kernel<<<(NN + 63) / 64, 256, 0, stream>>>(out, dsum1, dsq1, bn1g, bn1b, Wfc);
}

// Round 12
// 482.915 us; speedup vs baseline: 1.0116x; 1.0116x over previous
//
#include <hip/hip_runtime.h>
#include <hip/hip_fp16.h>
#include <math.h>
#include <stdint.h>

#define NN 100000
#define NE 1600000
#define INC 128
#define DIM 64
#define EPS 1e-5f
#define SB 512    // stats blocks inside fused stats+hist kernel
#define NREP 8    // stats accumulator replicas (atomic-contention spreading)
#define NPART 8   // scatter partitions (~1 per XCD; write set 12.8MB/8 = 1.6MB < 4MB L2)
#define PART_SZ ((NN + NPART - 1) / NPART)

struct __align__(8)  half4 { __half2 a, b; };
struct __align__(16) half8 { __half2 a, b, c, d; };

// fused: blocks [0,SB) do X stats (C=128) in f64; blocks [SB,...) do dst histogram
__global__ __launch_bounds__(256) void stats_hist_kernel(const float* __restrict__ X,
        const int* __restrict__ dst, int* __restrict__ counts,
        double* __restrict__ sum_out, double* __restrict__ sq_out) {
    __shared__ double ls[256], lq[256];
    if (blockIdx.x < SB) {
        int c  = threadIdx.x & 127;
        int rl = threadIdx.x >> 7;           // 2 rows per block step
        int row = blockIdx.x * 2 + rl;
        const int rstride = SB * 2;
        double s = 0.0, q = 0.0;
        for (int r = row; r < NN; r += rstride) {
            double v = (double)X[(size_t)r * INC + c];
            s += v; q += v * v;
        }
        ls[threadIdx.x] = s; lq[threadIdx.x] = q;
        __syncthreads();
        if (rl == 0) {
            s += ls[128 + c]; q += lq[128 + c];
            int rep = blockIdx.x & (NREP - 1);
            atomicAdd(&sum_out[rep * INC + c], s);
            atomicAdd(&sq_out[rep * INC + c], q);
        }
    } else {
        int e = (blockIdx.x - SB) * 256 + threadIdx.x;
        if (e < NE) atomicAdd(&counts[dst[e]], 1);
    }
}

// BN scale/shift from NREP-replicated f64 stats
template<int C>
__device__ inline void bn_fold_rep(int t, const double* dsum, const double* dsq,
                                   const float* g, const float* b, float* sc_s, float* sh_s) {
    if (t < C) {
        double s = 0.0, q = 0.0;
        #pragma unroll
        for (int r = 0; r < NREP; r++) { s += dsum[r * C + t]; q += dsq[r * C + t]; }
        double m = s / (double)NN;
        double v = q / (double)NN - m * m;
        double sc = (double)g[t] / sqrt(v + (double)EPS);
        sc_s[t] = (float)sc;
        sh_s[t] = (float)((double)b[t] - m * sc);
    }
}

// x̂ = BN(X) precomputed to fp16 [NN][128]
__global__ __launch_bounds__(256) void xhat_half_kernel(const float* __restrict__ X,
        const double* __restrict__ dsum, const double* __restrict__ dsq,
        const float* __restrict__ g, const float* __restrict__ b,
        __half* __restrict__ Xh) {
    __shared__ float sc_s[INC], sh_s[INC];
    bn_fold_rep<INC>(threadIdx.x, dsum, dsq, g, b, sc_s, sh_s);
    __syncthreads();
    size_t i = (size_t)blockIdx.x * 256 + threadIdx.x;   // one float4 per thread
    size_t e4 = i * 4;
    if (e4 >= (size_t)NN * INC) return;
    int c = (int)(e4 & 127);
    float4 x = *(const float4*)(X + e4);
    half4 h;
    h.a = __floats2half2_rn(fmaf(x.x, sc_s[c], sh_s[c]), fmaf(x.y, sc_s[c + 1], sh_s[c + 1]));
    h.b = __floats2half2_rn(fmaf(x.z, sc_s[c + 2], sh_s[c + 2]), fmaf(x.w, sc_s[c + 3], sh_s[c + 3]));
    *(half4*)(Xh + e4) = h;
}

// ---------------- CSR build: scan ----------------
__global__ __launch_bounds__(1024) void scan1_kernel(const int* __restrict__ counts,
                                                     int* __restrict__ offs, int* __restrict__ bsums) {
    __shared__ int tmp[2][1024];
    int t = threadIdx.x;
    int g = blockIdx.x * 1024 + t;
    int v = (g < NN) ? counts[g] : 0;
    tmp[0][t] = v;
    __syncthreads();
    int pin = 0;
    for (int d = 1; d < 1024; d <<= 1) {
        int x = tmp[pin][t] + ((t >= d) ? tmp[pin][t - d] : 0);
        tmp[pin ^ 1][t] = x;
        pin ^= 1;
        __syncthreads();
    }
    int incl = tmp[pin][t];
    if (g < NN) offs[g] = incl - v;
    if (t == 1023) bsums[blockIdx.x] = incl;
}

__global__ __launch_bounds__(128) void scan2_kernel(int* __restrict__ bsums, int nb) {
    __shared__ int tmp[2][128];
    int t = threadIdx.x;
    int v = (t < nb) ? bsums[t] : 0;
    tmp[0][t] = v;
    __syncthreads();
    int pin = 0;
    for (int d = 1; d < 128; d <<= 1) {
        int x = tmp[pin][t] + ((t >= d) ? tmp[pin][t - d] : 0);
        tmp[pin ^ 1][t] = x;
        pin ^= 1;
        __syncthreads();
    }
    if (t < nb) bsums[t] = tmp[pin][t] - v;
}

// final offsets + per-node scatter cursors
__global__ __launch_bounds__(256) void scan3_kernel(int* __restrict__ offs, const int* __restrict__ bsums,
                                                    int* __restrict__ cursor) {
    int g = blockIdx.x * 256 + threadIdx.x;
    if (g < NN) {
        int o = offs[g] + bsums[g >> 10];
        offs[g] = o;
        cursor[g] = o;
    }
    if (g == 0) offs[NN] = NE;
}

// XCD-partitioned scatter: blocks with blockIdx&7==p handle dst in partition p.
// Standalone 2048-block grid (resident in one dispatch wave -> round-robin XCD mapping holds).
__global__ __launch_bounds__(256) void scatter_kernel(const int* __restrict__ src, const int* __restrict__ dst,
                                                      const float* __restrict__ ea, int* __restrict__ cursor,
                                                      int2* __restrict__ src_ea) {
    const int p = blockIdx.x & (NPART - 1);
    const int blk = blockIdx.x >> 3;
    const int nblk = gridDim.x >> 3;
    const int lo = p * PART_SZ;
    const int hi = min(NN, lo + PART_SZ);
    for (int e = blk * 256 + threadIdx.x; e < NE; e += nblk * 256) {
        int d = dst[e];
        if (d >= lo && d < hi) {
            int pos = atomicAdd(&cursor[d], 1);
            src_ea[pos] = make_int2(src[e], __float_as_int(ea[e]));
        }
    }
}

// ---------------- fused layer 0: gather-agg (fp16 x̂, quarter-wave, tiered 4/2/1-deep) + GEMM + tanh + stats ----------------
// 32 nodes per 512-thread block. t1 -> t1h [NN][64] fp16; per-channel stats -> dsum0/dsq0 (replicated)
__global__ __launch_bounds__(512) void gine0_kernel(const float* __restrict__ X,
        const __half* __restrict__ Xh,
        const int* __restrict__ offs, const int2* __restrict__ src_ea,
        const double* __restrict__ dsum, const double* __restrict__ dsq,
        const float* __restrict__ g, const float* __restrict__ b,
        const float* __restrict__ We, const float* __restrict__ be,
        const float* __restrict__ W, const float* __restrict__ bvec,
        __half* __restrict__ t1h, double* __restrict__ dsum0, double* __restrict__ dsq0) {
    __shared__ __align__(16) float u_s[32][INC + 4];   // 16.9 KB
    __shared__ __align__(16) float w_s[DIM][INC + 4];  // 33.8 KB (reused for stats reduce)
    __shared__ float sc_s[INC], sh_s[INC];
    const int t = threadIdx.x;
    const int row0 = blockIdx.x * 32;
    bn_fold_rep<INC>(t, dsum, dsq, g, b, sc_s, sh_s);
    for (int i = t; i < INC * DIM; i += 512) {
        int k = i >> 6, c = i & 63;
        w_s[c][k] = W[i];
    }
    __syncthreads();
    const int wid = t >> 6, l = t & 63;
    const int quarter = l >> 4;
    const int c8 = (l & 15) * 8;
    float4 wv0 = *(const float4*)(We + c8);
    float4 wv1 = *(const float4*)(We + c8 + 4);
    float4 bv0 = *(const float4*)(be + c8);
    float4 bv1 = *(const float4*)(be + c8 + 4);

    #define G0_ACC(vh, av)  do { \
        float2 f0 = __half22float2((vh).a), f1 = __half22float2((vh).b); \
        float2 f2 = __half22float2((vh).c), f3 = __half22float2((vh).d); \
        a0 += fmaxf(f0.x + fmaf((av), wv0.x, bv0.x), 0.f); \
        a1 += fmaxf(f0.y + fmaf((av), wv0.y, bv0.y), 0.f); \
        a2 += fmaxf(f1.x + fmaf((av), wv0.z, bv0.z), 0.f); \
        a3 += fmaxf(f1.y + fmaf((av), wv0.w, bv0.w), 0.f); \
        a4 += fmaxf(f2.x + fmaf((av), wv1.x, bv1.x), 0.f); \
        a5 += fmaxf(f2.y + fmaf((av), wv1.y, bv1.y), 0.f); \
        a6 += fmaxf(f3.x + fmaf((av), wv1.z, bv1.z), 0.f); \
        a7 += fmaxf(f3.y + fmaf((av), wv1.w, bv1.w), 0.f); \
    } while (0)

    for (int nn = 0; nn < 4; ++nn) {
        int r = wid * 4 + nn;
        int n = row0 + r;
        float a0 = 0.f, a1 = 0.f, a2 = 0.f, a3 = 0.f, a4 = 0.f, a5 = 0.f, a6 = 0.f, a7 = 0.f;
        if (n < NN) {
            int beg = offs[n], end = offs[n + 1];
            for (int base = beg; base < end; base += 64) {
                int j = base + l;
                int2 p = (j < end) ? src_ea[j] : make_int2(0, 0);
                float avf = __int_as_float(p.y);
                int cnt = min(64, end - base);
                int tt = 0;
                // tier 1: 4 loads in flight
                for (; tt + 16 <= cnt; tt += 16) {
                    int e0 = tt + quarter, e1 = tt + 4 + quarter, e2 = tt + 8 + quarter, e3 = tt + 12 + quarter;
                    int s0 = __shfl(p.x, e0), s1 = __shfl(p.x, e1), s2 = __shfl(p.x, e2), s3 = __shfl(p.x, e3);
                    float av0 = __shfl(avf, e0), av1 = __shfl(avf, e1), av2 = __shfl(avf, e2), av3 = __shfl(avf, e3);
                    half8 v0 = *(const half8*)(Xh + (size_t)s0 * INC + c8);
                    half8 v1 = *(const half8*)(Xh + (size_t)s1 * INC + c8);
                    half8 v2 = *(const half8*)(Xh + (size_t)s2 * INC + c8);
                    half8 v3 = *(const half8*)(Xh + (size_t)s3 * INC + c8);
                    G0_ACC(v0, av0); G0_ACC(v1, av1); G0_ACC(v2, av2); G0_ACC(v3, av3);
                }
                // tier 2: 2 loads in flight
                for (; tt + 8 <= cnt; tt += 8) {
                    int e0 = tt + quarter, e1 = tt + 4 + quarter;
                    int s0 = __shfl(p.x, e0), s1 = __shfl(p.x, e1);
                    float av0 = __shfl(avf, e0), av1 = __shfl(avf, e1);
                    half8 v0 = *(const half8*)(Xh + (size_t)s0 * INC + c8);
                    half8 v1 = *(const half8*)(Xh + (size_t)s1 * INC + c8);
                    G0_ACC(v0, av0); G0_ACC(v1, av1);
                }
                // tier 3: remainder
                for (; tt < cnt; tt += 4) {
                    int e0 = tt + quarter;
                    int es = min(e0, cnt - 1);
                    int s0 = __shfl(p.x, es);
                    float av0 = __shfl(avf, es);
                    if (e0 < cnt) {
                        half8 v0 = *(const half8*)(Xh + (size_t)s0 * INC + c8);
                        G0_ACC(v0, av0);
                    }
                }
            }
        }
        // combine quarters
        a0 += __shfl_xor(a0, 16); a0 += __shfl_xor(a0, 32);
        a1 += __shfl_xor(a1, 16); a1 += __shfl_xor(a1, 32);
        a2 += __shfl_xor(a2, 16); a2 += __shfl_xor(a2, 32);
        a3 += __shfl_xor(a3, 16); a3 += __shfl_xor(a3, 32);
        a4 += __shfl_xor(a4, 16); a4 += __shfl_xor(a4, 32);
        a5 += __shfl_xor(a5, 16); a5 += __shfl_xor(a5, 32);
        a6 += __shfl_xor(a6, 16); a6 += __shfl_xor(a6, 32);
        a7 += __shfl_xor(a7, 16); a7 += __shfl_xor(a7, 32);
        if (quarter == 0) {
            if (n < NN) {
                // self term from f32 X for precision
                float4 x0 = *(const float4*)(X + (size_t)n * INC + c8);
                float4 x1 = *(const float4*)(X + (size_t)n * INC + c8 + 4);
                a0 += fmaf(x0.x, sc_s[c8],     sh_s[c8]);
                a1 += fmaf(x0.y, sc_s[c8 + 1], sh_s[c8 + 1]);
                a2 += fmaf(x0.z, sc_s[c8 + 2], sh_s[c8 + 2]);
                a3 += fmaf(x0.w, sc_s[c8 + 3], sh_s[c8 + 3]);
                a4 += fmaf(x1.x, sc_s[c8 + 4], sh_s[c8 + 4]);
                a5 += fmaf(x1.y, sc_s[c8 + 5], sh_s[c8 + 5]);
                a6 += fmaf(x1.z, sc_s[c8 + 6], sh_s[c8 + 6]);
                a7 += fmaf(x1.w, sc_s[c8 + 7], sh_s[c8 + 7]);
            }
            *(float4*)&u_s[r][c8]     = make_float4(a0, a1, a2, a3);
            *(float4*)&u_s[r][c8 + 4] = make_float4(a4, a5, a6, a7);
        }
    }
    #undef G0_ACC
    __syncthreads();
    // GEMM: 32x64 outputs, 512 threads -> 4 outputs each
    const int cc = t & 15;
    const int rg = t >> 4;                 // row 0..31
    float acc0 = bvec[cc], acc1 = bvec[cc + 16], acc2 = bvec[cc + 32], acc3 = bvec[cc + 48];
    #pragma unroll 4
    for (int k = 0; k < INC; k += 4) {
        float4 w0 = *(const float4*)&w_s[cc][k];
        float4 w1 = *(const float4*)&w_s[cc + 16][k];
        float4 w2 = *(const float4*)&w_s[cc + 32][k];
        float4 w3 = *(const float4*)&w_s[cc + 48][k];
        float4 u = *(const float4*)&u_s[rg][k];
        acc0 = fmaf(u.x, w0.x, fmaf(u.y, w0.y, fmaf(u.z, w0.z, fmaf(u.w, w0.w, acc0))));
        acc1 = fmaf(u.x, w1.x, fmaf(u.y, w1.y, fmaf(u.z, w1.z, fmaf(u.w, w1.w, acc1))));
        acc2 = fmaf(u.x, w2.x, fmaf(u.y, w2.y, fmaf(u.z, w2.z, fmaf(u.w, w2.w, acc2))));
        acc3 = fmaf(u.x, w3.x, fmaf(u.y, w3.y, fmaf(u.z, w3.z, fmaf(u.w, w3.w, acc3))));
    }
    int rr = row0 + rg;
    float t0 = tanhf(acc0), t1v = tanhf(acc1), t2v = tanhf(acc2), t3v = tanhf(acc3);
    if (rr < NN) {
        __half* op = t1h + (size_t)rr * DIM;
        op[cc]      = __float2half_rn(t0);
        op[cc + 16] = __float2half_rn(t1v);
        op[cc + 32] = __float2half_rn(t2v);
        op[cc + 48] = __float2half_rn(t3v);
    }
    // fused per-channel stats from f32 values (reuse w_s as [32 rows][64 cols] x2)
    __syncthreads();
    float* red_s = (float*)w_s;
    float* red_q = red_s + 2048;
    bool ok = (rr < NN);
    red_s[rg * 64 + cc]      = ok ? t0 : 0.f;
    red_s[rg * 64 + cc + 16] = ok ? t1v : 0.f;
    red_s[rg * 64 + cc + 32] = ok ? t2v : 0.f;
    red_s[rg * 64 + cc + 48] = ok ? t3v : 0.f;
    red_q[rg * 64 + cc]      = ok ? t0 * t0 : 0.f;
    red_q[rg * 64 + cc + 16] = ok ? t1v * t1v : 0.f;
    red_q[rg * 64 + cc + 32] = ok ? t2v * t2v : 0.f;
    red_q[rg * 64 + cc + 48] = ok ? t3v * t3v : 0.f;
    __syncthreads();
    if (t < 64) {
        float s = 0.f, q = 0.f;
        #pragma unroll
        for (int i = 0; i < 32; i++) { s += red_s[i * 64 + t]; q += red_q[i * 64 + t]; }
        int rep = blockIdx.x & (NREP - 1);
        atomicAdd(&dsum0[rep * DIM + t], (double)s);
        atomicAdd(&dsq0[rep * DIM + t], (double)q);
    }
}

// ---------------- fused layer 1: BN(fp16 t1) on the fly + h1 write + gather-agg (tiered) + GEMM + tanh + stats ----------------
// 64 nodes per 512-thread block. reads t1h fp16; h1 -> out[:,0:64]; t2 -> out[:,64:128]
__global__ __launch_bounds__(512) void gine1_kernel(const __half* __restrict__ t1h,
        const int* __restrict__ offs, const int2* __restrict__ src_ea,
        const double* __restrict__ dsum, const double* __restrict__ dsq,
        const float* __restrict__ g, const float* __restrict__ b,
        const float* __restrict__ We, const float* __restrict__ be,
        const float* __restrict__ W, const float* __restrict__ bvec,
        float* __restrict__ out, double* __restrict__ dsum1, double* __restrict__ dsq1) {
    __shared__ __align__(16) float u_s[64][DIM + 4];   // 17.4 KB
    __shared__ __align__(16) float w_s[DIM][DIM + 4];  // 17.4 KB (reused for stats reduce)
    __shared__ float sc_s[DIM], sh_s[DIM];
    const int t = threadIdx.x;
    const int row0 = blockIdx.x * 64;
    bn_fold_rep<DIM>(t, dsum, dsq, g, b, sc_s, sh_s);
    for (int i = t; i < DIM * DIM; i += 512) {
        int k = i >> 6, c = i & 63;
        w_s[c][k] = W[i];
    }
    __syncthreads();
    const int wid = t >> 6, l = t & 63;
    const int quarter = l >> 4;
    const int c4 = (l & 15) * 4;
    float4 wv = *(const float4*)(We + c4);
    float4 bv = *(const float4*)(be + c4);
    float4 sc4 = *(const float4*)(sc_s + c4);
    float4 sh4 = *(const float4*)(sh_s + c4);

    #define G1_ACC(vh, av)  do { \
        float2 f00 = __half22float2((vh).a), f01 = __half22float2((vh).b); \
        a0 += fmaxf(fmaf(f00.x, sc4.x, sh4.x) + fmaf((av), wv.x, bv.x), 0.f); \
        a1 += fmaxf(fmaf(f00.y, sc4.y, sh4.y) + fmaf((av), wv.y, bv.y), 0.f); \
        a2 += fmaxf(fmaf(f01.x, sc4.z, sh4.z) + fmaf((av), wv.z, bv.z), 0.f); \
        a3 += fmaxf(fmaf(f01.y, sc4.w, sh4.w) + fmaf((av), wv.w, bv.w), 0.f); \
    } while (0)

    for (int nn = 0; nn < 8; ++nn) {
        int r = wid * 8 + nn;
        int n = row0 + r;
        float a0 = 0.f, a1 = 0.f, a2 = 0.f, a3 = 0.f;
        if (n < NN) {
            int beg = offs[n], end = offs[n + 1];
            for (int base = beg; base < end; base += 64) {
                int j = base + l;
                int2 p = (j < end) ? src_ea[j] : make_int2(0, 0);
                float avf = __int_as_float(p.y);
                int cnt = min(64, end - base);
                int tt = 0;
                for (; tt + 16 <= cnt; tt += 16) {
                    int e0 = tt + quarter, e1 = tt + 4 + quarter, e2 = tt + 8 + quarter, e3 = tt + 12 + quarter;
                    int s0 = __shfl(p.x, e0), s1 = __shfl(p.x, e1), s2 = __shfl(p.x, e2), s3 = __shfl(p.x, e3);
                    float av0 = __shfl(avf, e0), av1 = __shfl(avf, e1), av2 = __shfl(avf, e2), av3 = __shfl(avf, e3);
                    half4 v0 = *(const half4*)(t1h + (size_t)s0 * DIM + c4);
                    half4 v1 = *(const half4*)(t1h + (size_t)s1 * DIM + c4);
                    half4 v2 = *(const half4*)(t1h + (size_t)s2 * DIM + c4);
                    half4 v3 = *(const half4*)(t1h + (size_t)s3 * DIM + c4);
                    G1_ACC(v0, av0); G1_ACC(v1, av1); G1_ACC(v2, av2); G1_ACC(v3, av3);
                }
                for (; tt + 8 <= cnt; tt += 8) {
                    int e0 = tt + quarter, e1 = tt + 4 + quarter;
                    int s0 = __shfl(p.x, e0), s1 = __shfl(p.x, e1);
                    float av0 = __shfl(avf, e0), av1 = __shfl(avf, e1);
                    half4 v0 = *(const half4*)(t1h + (size_t)s0 * DIM + c4);
                    half4 v1 = *(const half4*)(t1h + (size_t)s1 * DIM + c4);
                    G1_ACC(v0, av0); G1_ACC(v1, av1);
                }
                for (; tt < cnt; tt += 4) {
                    int e0 = tt + quarter;
                    int es = min(e0, cnt - 1);
                    int s0 = __shfl(p.x, es);
                    float av0 = __shfl(avf, es);
                    if (e0 < cnt) {
                        half4 v0 = *(const half4*)(t1h + (size_t)s0 * DIM + c4);
                        G1_ACC(v0, av0);
                    }
                }
            }
        }
        a0 += __shfl_xor(a0, 16); a0 += __shfl_xor(a0, 32);
        a1 += __shfl_xor(a1, 16); a1 += __shfl_xor(a1, 32);
        a2 += __shfl_xor(a2, 16); a2 += __shfl_xor(a2, 32);
        a3 += __shfl_xor(a3, 16); a3 += __shfl_xor(a3, 32);
        if (quarter == 0) {
            if (n < NN) {
                half4 h = *(const half4*)(t1h + (size_t)n * DIM + c4);
                float2 f0 = __half22float2(h.a), f1 = __half22float2(h.b);
                float h0 = fmaf(f0.x, sc4.x, sh4.x);
                float h1 = fmaf(f0.y, sc4.y, sh4.y);
                float h2 = fmaf(f1.x, sc4.z, sh4.z);
                float h3 = fmaf(f1.y, sc4.w, sh4.w);
                *(float4*)(out + (size_t)n * 192 + c4) = make_float4(h0, h1, h2, h3);   // h1
                a0 += h0; a1 += h1; a2 += h2; a3 += h3;
            }
            *(float4*)&u_s[r][c4] = make_float4(a0, a1, a2, a3);
        }
    }
    #undef G1_ACC
    __syncthreads();
    // GEMM: 64x64 outputs, 512 threads -> 8 outputs each (2 rows x 4 cols)
    const int cc = t & 15;
    const int r0 = (t >> 4) * 2;
    float acc[2][4];
    #pragma unroll
    for (int j = 0; j < 4; j++) {
        float bj = bvec[cc + 16 * j];
        acc[0][j] = bj; acc[1][j] = bj;
    }
    #pragma unroll 4
    for (int k = 0; k < DIM; k += 4) {
        float4 w0 = *(const float4*)&w_s[cc][k];
        float4 w1 = *(const float4*)&w_s[cc + 16][k];
        float4 w2 = *(const float4*)&w_s[cc + 32][k];
        float4 w3 = *(const float4*)&w_s[cc + 48][k];
        #pragma unroll
        for (int i = 0; i < 2; i++) {
            float4 u = *(const float4*)&u_s[r0 + i][k];
            acc[i][0] = fmaf(u.x, w0.x, fmaf(u.y, w0.y, fmaf(u.z, w0.z, fmaf(u.w, w0.w, acc[i][0]))));
            acc[i][1] = fmaf(u.x, w1.x, fmaf(u.y, w1.y, fmaf(u.z, w1.z, fmaf(u.w, w1.w, acc[i][1]))));
            acc[i][2] = fmaf(u.x, w2.x, fmaf(u.y, w2.y, fmaf(u.z, w2.z, fmaf(u.w, w2.w, acc[i][2]))));
            acc[i][3] = fmaf(u.x, w3.x, fmaf(u.y, w3.y, fmaf(u.z, w3.z, fmaf(u.w, w3.w, acc[i][3]))));
        }
    }
    float tv[2][4];
    #pragma unroll
    for (int i = 0; i < 2; i++) {
        int rr = row0 + r0 + i;
        #pragma unroll
        for (int j = 0; j < 4; j++) tv[i][j] = tanhf(acc[i][j]);
        if (rr < NN) {
            float* op = out + (size_t)rr * 192 + 64;
            #pragma unroll
            for (int j = 0; j < 4; j++) op[cc + 16 * j] = tv[i][j];
        }
    }
    // fused per-channel stats of t2 (reuse w_s as [32 rowgrps][64 cols] x2)
    __syncthreads();
    float* red_s = (float*)w_s;
    float* red_q = red_s + 2048;
    const int rgp = t >> 4;
    bool ok0 = (row0 + r0 < NN), ok1 = (row0 + r0 + 1 < NN);
    #pragma unroll
    for (int j = 0; j < 4; j++) {
        float v0 = ok0 ? tv[0][j] : 0.f;
        float v1 = ok1 ? tv[1][j] : 0.f;
        red_s[rgp * 64 + cc + 16 * j] = v0 + v1;
        red_q[rgp * 64 + cc + 16 * j] = v0 * v0 + v1 * v1;
    }
    __syncthreads();
    if (t < 64) {
        float s = 0.f, q = 0.f;
        #pragma unroll
        for (int i = 0; i < 32; i++) { s += red_s[i * 64 + t]; q += red_q[i * 64 + t]; }
        int rep = blockIdx.x & (NREP - 1);
        atomicAdd(&dsum1[rep * DIM + t], (double)s);
        atomicAdd(&dsq1[rep * DIM + t], (double)q);
    }
}

// ---------------- fused: finalize1 + h2 = BN(t2) in place + h3 = tanh(h2 @ Wfc) ----------------
__global__ __launch_bounds__(256) void fc_kernel(float* __restrict__ io,
        const double* __restrict__ dsum, const double* __restrict__ dsq,
        const float* __restrict__ g, const float* __restrict__ b,
        const float* __restrict__ W) {
    __shared__ __align__(16) float u_s[64][DIM + 4];
    __shared__ __align__(16) float w_s[DIM][DIM + 4];
    __shared__ float sc_s[DIM], sh_s[DIM];
    const int t = threadIdx.x;
    const int row0 = blockIdx.x * 64;
    bn_fold_rep<DIM>(t, dsum, dsq, g, b, sc_s, sh_s);
    __syncthreads();
    for (int i = t; i < DIM * DIM; i += 256) {
        int k = i >> 6, c = i & 63;
        w_s[c][k] = W[i];
    }
    for (int i = t; i < 64 * DIM; i += 256) {
        int r = i >> 6, k = i & 63;
        int rr = row0 + r;
        float v = 0.f;
        if (rr < NN) {
            size_t idx = (size_t)rr * 192 + 64 + k;
            v = fmaf(io[idx], sc_s[k], sh_s[k]);
            io[idx] = v;                       // h2
        }
        u_s[r][k] = v;
    }
    __syncthreads();
    const int cc = t & 15;
    const int r0 = (t >> 4) << 2;
    float acc[4][4];
    #pragma unroll
    for (int j = 0; j < 4; j++) { acc[0][j] = 0.f; acc[1][j] = 0.f; acc[2][j] = 0.f; acc[3][j] = 0.f; }
    #pragma unroll 4
    for (int k = 0; k < DIM; k += 4) {
        float4 w0 = *(const float4*)&w_s[cc][k];
        float4 w1 = *(const float4*)&w_s[cc + 16][k];
        float4 w2 = *(const float4*)&w_s[cc + 32][k];
        float4 w3 = *(const float4*)&w_s[cc + 48][k];
        #pragma unroll
        for (int i = 0; i < 4; i++) {
            float4 u = *(const float4*)&u_s[r0 + i][k];
            acc[i][0] = fmaf(u.x, w0.x, fmaf(u.y, w0.y, fmaf(u.z, w0.z, fmaf(u.w, w0.w, acc[i][0]))));
            acc[i][1] = fmaf(u.x, w1.x, fmaf(u.y, w1.y, fmaf(u.z, w1.z, fmaf(u.w, w1.w, acc[i][1]))));
            acc[i][2] = fmaf(u.x, w2.x, fmaf(u.y, w2.y, fmaf(u.z, w2.z, fmaf(u.w, w2.w, acc[i][2]))));
            acc[i][3] = fmaf(u.x, w3.x, fmaf(u.y, w3.y, fmaf(u.z, w3.z, fmaf(u.w, w3.w, acc[i][3]))));
        }
    }
    #pragma unroll
    for (int i = 0; i < 4; i++) {
        int rr = row0 + r0 + i;
        if (rr < NN) {
            #pragma unroll
            for (int j = 0; j < 4; j++)
                io[(size_t)rr * 192 + 128 + cc + 16 * j] = tanhf(acc[i][j]);
        }
    }
}

extern "C" void kernel_launch(void* const* d_in, const int* in_sizes, int n_in,
                              void* d_out, int out_size, void* d_ws, size_t ws_size,
                              hipStream_t stream) {
    const float* X      = (const float*)d_in[0];
    const int*   ei     = (const int*)  d_in[1];
    const float* ea     = (const float*)d_in[2];
    const float* bng    = (const float*)d_in[3];
    const float* bnb    = (const float*)d_in[4];
    const float* We0    = (const float*)d_in[5];
    const float* be0    = (const float*)d_in[6];
    const float* W0     = (const float*)d_in[7];
    const float* b0     = (const float*)d_in[8];
    const float* bn0g   = (const float*)d_in[9];
    const float* bn0b   = (const float*)d_in[10];
    const float* We1    = (const float*)d_in[11];
    const float* be1    = (const float*)d_in[12];
    const float* W1     = (const float*)d_in[13];
    const float* b1     = (const float*)d_in[14];
    const float* bn1g   = (const float*)d_in[15];
    const float* bn1b   = (const float*)d_in[16];
    const float* Wfc    = (const float*)d_in[17];

    const int* src = ei;
    const int* dst = ei + NE;
    float* out = (float*)d_out;

    // ---- workspace layout (~52 MB) ----
    int2*   src_ea  = (int2*)d_ws;                        // NE
    __half* t1h     = (__half*)(src_ea + NE);             // NN*DIM halves
    __half* Xh      = t1h + (size_t)NN * DIM;             // NN*INC halves
    int*    counts  = (int*)(Xh + (size_t)NN * INC);      // NN
    int*    offs    = counts + NN;                        // NN+1
    int*    cursor  = offs + NN + 1;                      // NN
    int*    bsums   = cursor + NN;                        // 128
    double* dstats = (double*)(((uintptr_t)(bsums + 128) + 15) & ~(uintptr_t)15);
    double* dsum_in = dstats;                          // NREP*128
    double* dsq_in  = dsum_in + NREP * INC;            // NREP*128
    double* dsum0   = dsq_in + NREP * INC;             // NREP*64
    double* dsq0    = dsum0 + NREP * DIM;              // NREP*64
    double* dsum1   = dsq0 + NREP * DIM;               // NREP*64
    double* dsq1    = dsum1 + NREP * DIM;              // NREP*64
    const size_t nstats = (size_t)NREP * (2 * INC + 4 * DIM);

    hipMemsetAsync(counts, 0, NN * sizeof(int), stream);
    hipMemsetAsync(dstats, 0, nstats * sizeof(double), stream);

    // fused input-BN stats + dst histogram
    stats_hist_kernel<<<SB + (NE + 255) / 256, 256, 0, stream>>>(X, dst, counts, dsum_in, dsq_in);

    // x̂ -> fp16 (depends only on stats)
    xhat_half_kernel<<<(NN * INC / 4 + 255) / 256, 256, 0, stream>>>(X, dsum_in, dsq_in, bng, bnb, Xh);

    // CSR build (shared by both layers)
    const int NB = (NN + 1023) / 1024;   // 98
    scan1_kernel<<<NB, 1024, 0, stream>>>(counts, offs, bsums);
    scan2_kernel<<<1, 128, 0, stream>>>(bsums, NB);
    scan3_kernel<<<(NN + 255) / 256, 256, 0, stream>>>(offs, bsums, cursor);
    // XCD-partitioned scatter: standalone 2048-block grid (resident in one wave)
    scatter_kernel<<<2048, 256, 0, stream>>>(src, dst, ea, cursor, src_ea);

    // layer 0 (fused agg + GEMM + stats0), gathers fp16 x̂, writes fp16 t1
    gine0_kernel<<<(NN + 31) / 32, 512, 0, stream>>>(X, Xh, offs, src_ea, dsum_in, dsq_in, bng, bnb,
                                                     We0, be0, W0, b0, t1h, dsum0, dsq0);

    // layer 1 (fused finalize0 + BN-on-fly + h1 write + agg + GEMM + stats1), gathers fp16 t1
    gine1_kernel<<<(NN + 63) / 64, 512, 0, stream>>>(t1h, offs, src_ea, dsum0, dsq0, bn0g, bn0b,
                                                     We1, be1, W1, b1, out, dsum1, dsq1);

    // h2 (in place) + h3 (fused finalize1)
    fc_kernel<<<(NN + 63) / 64, 256, 0, stream>>>(out, dsum1, dsq1, bn1g, bn1b, Wfc);
}

// Round 13
// 442.802 us; speedup vs baseline: 1.1032x; 1.0906x over previous
//
#include <hip/hip_runtime.h>
#include <hip/hip_fp16.h>
#include <math.h>
#include <stdint.h>

#define NN 100000
#define NE 1600000
#define INC 128
#define DIM 64
#define EPS 1e-5f
#define SB 512    // stats blocks inside fused stats+hist kernel
#define NREP 8    // stats accumulator replicas (atomic-contention spreading)
#define NPART 8   // scatter partitions (~1 per XCD; write set 12.8MB/8 = 1.6MB < 4MB L2)
#define PART_SZ ((NN + NPART - 1) / NPART)

struct __align__(8)  half4 { __half2 a, b; };
struct __align__(16) half8 { __half2 a, b, c, d; };

// fused: blocks [0,SB) do X stats (C=128) in f64; blocks [SB,...) do dst histogram
__global__ __launch_bounds__(256) void stats_hist_kernel(const float* __restrict__ X,
        const int* __restrict__ dst, int* __restrict__ counts,
        double* __restrict__ sum_out, double* __restrict__ sq_out) {
    __shared__ double ls[256], lq[256];
    if (blockIdx.x < SB) {
        int c  = threadIdx.x & 127;
        int rl = threadIdx.x >> 7;           // 2 rows per block step
        int row = blockIdx.x * 2 + rl;
        const int rstride = SB * 2;
        double s = 0.0, q = 0.0;
        for (int r = row; r < NN; r += rstride) {
            double v = (double)X[(size_t)r * INC + c];
            s += v; q += v * v;
        }
        ls[threadIdx.x] = s; lq[threadIdx.x] = q;
        __syncthreads();
        if (rl == 0) {
            s += ls[128 + c]; q += lq[128 + c];
            int rep = blockIdx.x & (NREP - 1);
            atomicAdd(&sum_out[rep * INC + c], s);
            atomicAdd(&sq_out[rep * INC + c], q);
        }
    } else {
        int e = (blockIdx.x - SB) * 256 + threadIdx.x;
        if (e < NE) atomicAdd(&counts[dst[e]], 1);
    }
}

// BN scale/shift from NREP-replicated f64 stats
template<int C>
__device__ inline void bn_fold_rep(int t, const double* dsum, const double* dsq,
                                   const float* g, const float* b, float* sc_s, float* sh_s) {
    if (t < C) {
        double s = 0.0, q = 0.0;
        #pragma unroll
        for (int r = 0; r < NREP; r++) { s += dsum[r * C + t]; q += dsq[r * C + t]; }
        double m = s / (double)NN;
        double v = q / (double)NN - m * m;
        double sc = (double)g[t] / sqrt(v + (double)EPS);
        sc_s[t] = (float)sc;
        sh_s[t] = (float)((double)b[t] - m * sc);
    }
}

// x̂ = BN(X) precomputed to fp16 [NN][128]
__global__ __launch_bounds__(256) void xhat_half_kernel(const float* __restrict__ X,
        const double* __restrict__ dsum, const double* __restrict__ dsq,
        const float* __restrict__ g, const float* __restrict__ b,
        __half* __restrict__ Xh) {
    __shared__ float sc_s[INC], sh_s[INC];
    bn_fold_rep<INC>(threadIdx.x, dsum, dsq, g, b, sc_s, sh_s);
    __syncthreads();
    size_t i = (size_t)blockIdx.x * 256 + threadIdx.x;   // one float4 per thread
    size_t e4 = i * 4;
    if (e4 >= (size_t)NN * INC) return;
    int c = (int)(e4 & 127);
    float4 x = *(const float4*)(X + e4);
    half4 h;
    h.a = __floats2half2_rn(fmaf(x.x, sc_s[c], sh_s[c]), fmaf(x.y, sc_s[c + 1], sh_s[c + 1]));
    h.b = __floats2half2_rn(fmaf(x.z, sc_s[c + 2], sh_s[c + 2]), fmaf(x.w, sc_s[c + 3], sh_s[c + 3]));
    *(half4*)(Xh + e4) = h;
}

// ---------------- CSR build: scan ----------------
__global__ __launch_bounds__(1024) void scan1_kernel(const int* __restrict__ counts,
                                                     int* __restrict__ offs, int* __restrict__ bsums) {
    __shared__ int tmp[2][1024];
    int t = threadIdx.x;
    int g = blockIdx.x * 1024 + t;
    int v = (g < NN) ? counts[g] : 0;
    tmp[0][t] = v;
    __syncthreads();
    int pin = 0;
    for (int d = 1; d < 1024; d <<= 1) {
        int x = tmp[pin][t] + ((t >= d) ? tmp[pin][t - d] : 0);
        tmp[pin ^ 1][t] = x;
        pin ^= 1;
        __syncthreads();
    }
    int incl = tmp[pin][t];
    if (g < NN) offs[g] = incl - v;
    if (t == 1023) bsums[blockIdx.x] = incl;
}

__global__ __launch_bounds__(128) void scan2_kernel(int* __restrict__ bsums, int nb) {
    __shared__ int tmp[2][128];
    int t = threadIdx.x;
    int v = (t < nb) ? bsums[t] : 0;
    tmp[0][t] = v;
    __syncthreads();
    int pin = 0;
    for (int d = 1; d < 128; d <<= 1) {
        int x = tmp[pin][t] + ((t >= d) ? tmp[pin][t - d] : 0);
        tmp[pin ^ 1][t] = x;
        pin ^= 1;
        __syncthreads();
    }
    if (t < nb) bsums[t] = tmp[pin][t] - v;
}

// final offsets + per-node scatter cursors
__global__ __launch_bounds__(256) void scan3_kernel(int* __restrict__ offs, const int* __restrict__ bsums,
                                                    int* __restrict__ cursor) {
    int g = blockIdx.x * 256 + threadIdx.x;
    if (g < NN) {
        int o = offs[g] + bsums[g >> 10];
        offs[g] = o;
        cursor[g] = o;
    }
    if (g == 0) offs[NN] = NE;
}

// XCD-partitioned scatter: blocks with blockIdx&7==p handle dst in partition p.
// Standalone 2048-block grid (resident in one dispatch wave -> round-robin XCD mapping holds).
__global__ __launch_bounds__(256) void scatter_kernel(const int* __restrict__ src, const int* __restrict__ dst,
                                                      const float* __restrict__ ea, int* __restrict__ cursor,
                                                      int2* __restrict__ src_ea) {
    const int p = blockIdx.x & (NPART - 1);
    const int blk = blockIdx.x >> 3;
    const int nblk = gridDim.x >> 3;
    const int lo = p * PART_SZ;
    const int hi = min(NN, lo + PART_SZ);
    for (int e = blk * 256 + threadIdx.x; e < NE; e += nblk * 256) {
        int d = dst[e];
        if (d >= lo && d < hi) {
            int pos = atomicAdd(&cursor[d], 1);
            src_ea[pos] = make_int2(src[e], __float_as_int(ea[e]));
        }
    }
}

// ---------------- fused layer 0: gather-agg (fp16 x̂, quarter-wave, 2-deep) + fp16-W GEMM + tanh + stats ----------------
// 32 nodes per 512-thread block. W0 in LDS as fp16 -> 35.3KB LDS -> 4 blocks/CU (32 waves).
__global__ __launch_bounds__(512, 8) void gine0_kernel(const float* __restrict__ X,
        const __half* __restrict__ Xh,
        const int* __restrict__ offs, const int2* __restrict__ src_ea,
        const double* __restrict__ dsum, const double* __restrict__ dsq,
        const float* __restrict__ g, const float* __restrict__ b,
        const float* __restrict__ We, const float* __restrict__ be,
        const float* __restrict__ W, const float* __restrict__ bvec,
        __half* __restrict__ t1h, double* __restrict__ dsum0, double* __restrict__ dsq0) {
    __shared__ __align__(16) float  u_s[32][INC + 4];    // 16.9 KB (reused for stats reduce)
    __shared__ __align__(16) __half w_sh[DIM][INC + 8];  // 17.4 KB, fp16 W, 16B-aligned rows
    __shared__ float sc_s[INC], sh_s[INC];
    const int t = threadIdx.x;
    const int row0 = blockIdx.x * 32;
    bn_fold_rep<INC>(t, dsum, dsq, g, b, sc_s, sh_s);
    for (int i = t; i < INC * DIM; i += 512) {
        int k = i >> 6, c = i & 63;
        w_sh[c][k] = __float2half_rn(W[i]);
    }
    __syncthreads();
    // gather: 8 waves x 4 nodes; wave split into 4 quarters of 16 lanes, each handles one edge (2-deep)
    const int wid = t >> 6, l = t & 63;
    const int quarter = l >> 4;
    const int c8 = (l & 15) * 8;
    float4 wv0 = *(const float4*)(We + c8);
    float4 wv1 = *(const float4*)(We + c8 + 4);
    float4 bv0 = *(const float4*)(be + c8);
    float4 bv1 = *(const float4*)(be + c8 + 4);

    #define G0_ACC(vh, av)  do { \
        float2 f0 = __half22float2((vh).a), f1 = __half22float2((vh).b); \
        float2 f2 = __half22float2((vh).c), f3 = __half22float2((vh).d); \
        a0 += fmaxf(f0.x + fmaf((av), wv0.x, bv0.x), 0.f); \
        a1 += fmaxf(f0.y + fmaf((av), wv0.y, bv0.y), 0.f); \
        a2 += fmaxf(f1.x + fmaf((av), wv0.z, bv0.z), 0.f); \
        a3 += fmaxf(f1.y + fmaf((av), wv0.w, bv0.w), 0.f); \
        a4 += fmaxf(f2.x + fmaf((av), wv1.x, bv1.x), 0.f); \
        a5 += fmaxf(f2.y + fmaf((av), wv1.y, bv1.y), 0.f); \
        a6 += fmaxf(f3.x + fmaf((av), wv1.z, bv1.z), 0.f); \
        a7 += fmaxf(f3.y + fmaf((av), wv1.w, bv1.w), 0.f); \
    } while (0)

    for (int nn = 0; nn < 4; ++nn) {
        int r = wid * 4 + nn;
        int n = row0 + r;
        float a0 = 0.f, a1 = 0.f, a2 = 0.f, a3 = 0.f, a4 = 0.f, a5 = 0.f, a6 = 0.f, a7 = 0.f;
        if (n < NN) {
            int beg = offs[n], end = offs[n + 1];
            for (int base = beg; base < end; base += 64) {
                int j = base + l;
                int2 p = (j < end) ? src_ea[j] : make_int2(0, 0);
                float avf = __int_as_float(p.y);
                int cnt = min(64, end - base);
                int tt = 0;
                for (; tt + 8 <= cnt; tt += 8) {
                    int e0 = tt + quarter, e1 = tt + 4 + quarter;
                    int s0 = __shfl(p.x, e0), s1 = __shfl(p.x, e1);
                    float av0 = __shfl(avf, e0), av1 = __shfl(avf, e1);
                    half8 v0 = *(const half8*)(Xh + (size_t)s0 * INC + c8);
                    half8 v1 = *(const half8*)(Xh + (size_t)s1 * INC + c8);
                    G0_ACC(v0, av0); G0_ACC(v1, av1);
                }
                for (; tt < cnt; tt += 4) {
                    int e0 = tt + quarter;
                    int es = min(e0, cnt - 1);
                    int s0 = __shfl(p.x, es);
                    float av0 = __shfl(avf, es);
                    if (e0 < cnt) {
                        half8 v0 = *(const half8*)(Xh + (size_t)s0 * INC + c8);
                        G0_ACC(v0, av0);
                    }
                }
            }
        }
        // combine quarters
        a0 += __shfl_xor(a0, 16); a0 += __shfl_xor(a0, 32);
        a1 += __shfl_xor(a1, 16); a1 += __shfl_xor(a1, 32);
        a2 += __shfl_xor(a2, 16); a2 += __shfl_xor(a2, 32);
        a3 += __shfl_xor(a3, 16); a3 += __shfl_xor(a3, 32);
        a4 += __shfl_xor(a4, 16); a4 += __shfl_xor(a4, 32);
        a5 += __shfl_xor(a5, 16); a5 += __shfl_xor(a5, 32);
        a6 += __shfl_xor(a6, 16); a6 += __shfl_xor(a6, 32);
        a7 += __shfl_xor(a7, 16); a7 += __shfl_xor(a7, 32);
        if (quarter == 0) {
            if (n < NN) {
                // self term from f32 X for precision
                float4 x0 = *(const float4*)(X + (size_t)n * INC + c8);
                float4 x1 = *(const float4*)(X + (size_t)n * INC + c8 + 4);
                a0 += fmaf(x0.x, sc_s[c8],     sh_s[c8]);
                a1 += fmaf(x0.y, sc_s[c8 + 1], sh_s[c8 + 1]);
                a2 += fmaf(x0.z, sc_s[c8 + 2], sh_s[c8 + 2]);
                a3 += fmaf(x0.w, sc_s[c8 + 3], sh_s[c8 + 3]);
                a4 += fmaf(x1.x, sc_s[c8 + 4], sh_s[c8 + 4]);
                a5 += fmaf(x1.y, sc_s[c8 + 5], sh_s[c8 + 5]);
                a6 += fmaf(x1.z, sc_s[c8 + 6], sh_s[c8 + 6]);
                a7 += fmaf(x1.w, sc_s[c8 + 7], sh_s[c8 + 7]);
            }
            *(float4*)&u_s[r][c8]     = make_float4(a0, a1, a2, a3);
            *(float4*)&u_s[r][c8 + 4] = make_float4(a4, a5, a6, a7);
        }
    }
    #undef G0_ACC
    __syncthreads();
    // GEMM (fp16 weights): 32x64 outputs, 512 threads -> 4 outputs each
    const int cc = t & 15;
    const int rg = t >> 4;                 // row 0..31
    float acc0 = bvec[cc], acc1 = bvec[cc + 16], acc2 = bvec[cc + 32], acc3 = bvec[cc + 48];
    #pragma unroll 2
    for (int k = 0; k < INC; k += 8) {
        float4 ua = *(const float4*)&u_s[rg][k];
        float4 ub = *(const float4*)&u_s[rg][k + 4];
        half8 w0 = *(const half8*)&w_sh[cc][k];
        half8 w1 = *(const half8*)&w_sh[cc + 16][k];
        half8 w2 = *(const half8*)&w_sh[cc + 32][k];
        half8 w3 = *(const half8*)&w_sh[cc + 48][k];
        float2 p;
        p = __half22float2(w0.a); acc0 = fmaf(ua.x, p.x, fmaf(ua.y, p.y, acc0));
        p = __half22float2(w0.b); acc0 = fmaf(ua.z, p.x, fmaf(ua.w, p.y, acc0));
        p = __half22float2(w0.c); acc0 = fmaf(ub.x, p.x, fmaf(ub.y, p.y, acc0));
        p = __half22float2(w0.d); acc0 = fmaf(ub.z, p.x, fmaf(ub.w, p.y, acc0));
        p = __half22float2(w1.a); acc1 = fmaf(ua.x, p.x, fmaf(ua.y, p.y, acc1));
        p = __half22float2(w1.b); acc1 = fmaf(ua.z, p.x, fmaf(ua.w, p.y, acc1));
        p = __half22float2(w1.c); acc1 = fmaf(ub.x, p.x, fmaf(ub.y, p.y, acc1));
        p = __half22float2(w1.d); acc1 = fmaf(ub.z, p.x, fmaf(ub.w, p.y, acc1));
        p = __half22float2(w2.a); acc2 = fmaf(ua.x, p.x, fmaf(ua.y, p.y, acc2));
        p = __half22float2(w2.b); acc2 = fmaf(ua.z, p.x, fmaf(ua.w, p.y, acc2));
        p = __half22float2(w2.c); acc2 = fmaf(ub.x, p.x, fmaf(ub.y, p.y, acc2));
        p = __half22float2(w2.d); acc2 = fmaf(ub.z, p.x, fmaf(ub.w, p.y, acc2));
        p = __half22float2(w3.a); acc3 = fmaf(ua.x, p.x, fmaf(ua.y, p.y, acc3));
        p = __half22float2(w3.b); acc3 = fmaf(ua.z, p.x, fmaf(ua.w, p.y, acc3));
        p = __half22float2(w3.c); acc3 = fmaf(ub.x, p.x, fmaf(ub.y, p.y, acc3));
        p = __half22float2(w3.d); acc3 = fmaf(ub.z, p.x, fmaf(ub.w, p.y, acc3));
    }
    int rr = row0 + rg;
    float t0 = tanhf(acc0), t1v = tanhf(acc1), t2v = tanhf(acc2), t3v = tanhf(acc3);
    if (rr < NN) {
        __half* op = t1h + (size_t)rr * DIM;
        op[cc]      = __float2half_rn(t0);
        op[cc + 16] = __float2half_rn(t1v);
        op[cc + 32] = __float2half_rn(t2v);
        op[cc + 48] = __float2half_rn(t3v);
    }
    // fused per-channel stats from f32 values (reuse u_s as [32 rows][64 cols] x2 = 16KB <= 16.9KB)
    __syncthreads();
    float* red_s = (float*)u_s;
    float* red_q = red_s + 2048;
    bool ok = (rr < NN);
    red_s[rg * 64 + cc]      = ok ? t0 : 0.f;
    red_s[rg * 64 + cc + 16] = ok ? t1v : 0.f;
    red_s[rg * 64 + cc + 32] = ok ? t2v : 0.f;
    red_s[rg * 64 + cc + 48] = ok ? t3v : 0.f;
    red_q[rg * 64 + cc]      = ok ? t0 * t0 : 0.f;
    red_q[rg * 64 + cc + 16] = ok ? t1v * t1v : 0.f;
    red_q[rg * 64 + cc + 32] = ok ? t2v * t2v : 0.f;
    red_q[rg * 64 + cc + 48] = ok ? t3v * t3v : 0.f;
    __syncthreads();
    if (t < 64) {
        float s = 0.f, q = 0.f;
        #pragma unroll
        for (int i = 0; i < 32; i++) { s += red_s[i * 64 + t]; q += red_q[i * 64 + t]; }
        int rep = blockIdx.x & (NREP - 1);
        atomicAdd(&dsum0[rep * DIM + t], (double)s);
        atomicAdd(&dsq0[rep * DIM + t], (double)q);
    }
}

// ---------------- fused layer 1: BN(fp16 t1) on the fly + h1 write + gather-agg (2-deep) + GEMM + tanh + stats ----------------
// 64 nodes per 512-thread block. reads t1h fp16; h1 -> out[:,0:64]; t2 -> out[:,64:128]
__global__ __launch_bounds__(512) void gine1_kernel(const __half* __restrict__ t1h,
        const int* __restrict__ offs, const int2* __restrict__ src_ea,
        const double* __restrict__ dsum, const double* __restrict__ dsq,
        const float* __restrict__ g, const float* __restrict__ b,
        const float* __restrict__ We, const float* __restrict__ be,
        const float* __restrict__ W, const float* __restrict__ bvec,
        float* __restrict__ out, double* __restrict__ dsum1, double* __restrict__ dsq1) {
    __shared__ __align__(16) float u_s[64][DIM + 4];   // 17.4 KB
    __shared__ __align__(16) float w_s[DIM][DIM + 4];  // 17.4 KB (reused for stats reduce)
    __shared__ float sc_s[DIM], sh_s[DIM];
    const int t = threadIdx.x;
    const int row0 = blockIdx.x * 64;
    bn_fold_rep<DIM>(t, dsum, dsq, g, b, sc_s, sh_s);
    for (int i = t; i < DIM * DIM; i += 512) {
        int k = i >> 6, c = i & 63;
        w_s[c][k] = W[i];
    }
    __syncthreads();
    const int wid = t >> 6, l = t & 63;
    const int quarter = l >> 4;
    const int c4 = (l & 15) * 4;
    float4 wv = *(const float4*)(We + c4);
    float4 bv = *(const float4*)(be + c4);
    float4 sc4 = *(const float4*)(sc_s + c4);
    float4 sh4 = *(const float4*)(sh_s + c4);

    #define G1_ACC(vh, av)  do { \
        float2 f00 = __half22float2((vh).a), f01 = __half22float2((vh).b); \
        a0 += fmaxf(fmaf(f00.x, sc4.x, sh4.x) + fmaf((av), wv.x, bv.x), 0.f); \
        a1 += fmaxf(fmaf(f00.y, sc4.y, sh4.y) + fmaf((av), wv.y, bv.y), 0.f); \
        a2 += fmaxf(fmaf(f01.x, sc4.z, sh4.z) + fmaf((av), wv.z, bv.z), 0.f); \
        a3 += fmaxf(fmaf(f01.y, sc4.w, sh4.w) + fmaf((av), wv.w, bv.w), 0.f); \
    } while (0)

    for (int nn = 0; nn < 8; ++nn) {
        int r = wid * 8 + nn;
        int n = row0 + r;
        float a0 = 0.f, a1 = 0.f, a2 = 0.f, a3 = 0.f;
        if (n < NN) {
            int beg = offs[n], end = offs[n + 1];
            for (int base = beg; base < end; base += 64) {
                int j = base + l;
                int2 p = (j < end) ? src_ea[j] : make_int2(0, 0);
                float avf = __int_as_float(p.y);
                int cnt = min(64, end - base);
                int tt = 0;
                for (; tt + 8 <= cnt; tt += 8) {
                    int e0 = tt + quarter, e1 = tt + 4 + quarter;
                    int s0 = __shfl(p.x, e0), s1 = __shfl(p.x, e1);
                    float av0 = __shfl(avf, e0), av1 = __shfl(avf, e1);
                    half4 v0 = *(const half4*)(t1h + (size_t)s0 * DIM + c4);
                    half4 v1 = *(const half4*)(t1h + (size_t)s1 * DIM + c4);
                    G1_ACC(v0, av0); G1_ACC(v1, av1);
                }
                for (; tt < cnt; tt += 4) {
                    int e0 = tt + quarter;
                    int es = min(e0, cnt - 1);
                    int s0 = __shfl(p.x, es);
                    float av0 = __shfl(avf, es);
                    if (e0 < cnt) {
                        half4 v0 = *(const half4*)(t1h + (size_t)s0 * DIM + c4);
                        G1_ACC(v0, av0);
                    }
                }
            }
        }
        a0 += __shfl_xor(a0, 16); a0 += __shfl_xor(a0, 32);
        a1 += __shfl_xor(a1, 16); a1 += __shfl_xor(a1, 32);
        a2 += __shfl_xor(a2, 16); a2 += __shfl_xor(a2, 32);
        a3 += __shfl_xor(a3, 16); a3 += __shfl_xor(a3, 32);
        if (quarter == 0) {
            if (n < NN) {
                half4 h = *(const half4*)(t1h + (size_t)n * DIM + c4);
                float2 f0 = __half22float2(h.a), f1 = __half22float2(h.b);
                float h0 = fmaf(f0.x, sc4.x, sh4.x);
                float h1 = fmaf(f0.y, sc4.y, sh4.y);
                float h2 = fmaf(f1.x, sc4.z, sh4.z);
                float h3 = fmaf(f1.y, sc4.w, sh4.w);
                *(float4*)(out + (size_t)n * 192 + c4) = make_float4(h0, h1, h2, h3);   // h1
                a0 += h0; a1 += h1; a2 += h2; a3 += h3;
            }
            *(float4*)&u_s[r][c4] = make_float4(a0, a1, a2, a3);
        }
    }
    #undef G1_ACC
    __syncthreads();
    // GEMM: 64x64 outputs, 512 threads -> 8 outputs each (2 rows x 4 cols)
    const int cc = t & 15;
    const int r0 = (t >> 4) * 2;
    float acc[2][4];
    #pragma unroll
    for (int j = 0; j < 4; j++) {
        float bj = bvec[cc + 16 * j];
        acc[0][j] = bj; acc[1][j] = bj;
    }
    #pragma unroll 4
    for (int k = 0; k < DIM; k += 4) {
        float4 w0 = *(const float4*)&w_s[cc][k];
        float4 w1 = *(const float4*)&w_s[cc + 16][k];
        float4 w2 = *(const float4*)&w_s[cc + 32][k];
        float4 w3 = *(const float4*)&w_s[cc + 48][k];
        #pragma unroll
        for (int i = 0; i < 2; i++) {
            float4 u = *(const float4*)&u_s[r0 + i][k];
            acc[i][0] = fmaf(u.x, w0.x, fmaf(u.y, w0.y, fmaf(u.z, w0.z, fmaf(u.w, w0.w, acc[i][0]))));
            acc[i][1] = fmaf(u.x, w1.x, fmaf(u.y, w1.y, fmaf(u.z, w1.z, fmaf(u.w, w1.w, acc[i][1]))));
            acc[i][2] = fmaf(u.x, w2.x, fmaf(u.y, w2.y, fmaf(u.z, w2.z, fmaf(u.w, w2.w, acc[i][2]))));
            acc[i][3] = fmaf(u.x, w3.x, fmaf(u.y, w3.y, fmaf(u.z, w3.z, fmaf(u.w, w3.w, acc[i][3]))));
        }
    }
    float tv[2][4];
    #pragma unroll
    for (int i = 0; i < 2; i++) {
        int rr = row0 + r0 + i;
        #pragma unroll
        for (int j = 0; j < 4; j++) tv[i][j] = tanhf(acc[i][j]);
        if (rr < NN) {
            float* op = out + (size_t)rr * 192 + 64;
            #pragma unroll
            for (int j = 0; j < 4; j++) op[cc + 16 * j] = tv[i][j];
        }
    }
    // fused per-channel stats of t2 (reuse w_s as [32 rowgrps][64 cols] x2)
    __syncthreads();
    float* red_s = (float*)w_s;
    float* red_q = red_s + 2048;
    const int rgp = t >> 4;
    bool ok0 = (row0 + r0 < NN), ok1 = (row0 + r0 + 1 < NN);
    #pragma unroll
    for (int j = 0; j < 4; j++) {
        float v0 = ok0 ? tv[0][j] : 0.f;
        float v1 = ok1 ? tv[1][j] : 0.f;
        red_s[rgp * 64 + cc + 16 * j] = v0 + v1;
        red_q[rgp * 64 + cc + 16 * j] = v0 * v0 + v1 * v1;
    }
    __syncthreads();
    if (t < 64) {
        float s = 0.f, q = 0.f;
        #pragma unroll
        for (int i = 0; i < 32; i++) { s += red_s[i * 64 + t]; q += red_q[i * 64 + t]; }
        int rep = blockIdx.x & (NREP - 1);
        atomicAdd(&dsum1[rep * DIM + t], (double)s);
        atomicAdd(&dsq1[rep * DIM + t], (double)q);
    }
}

// ---------------- fused: finalize1 + h2 = BN(t2) in place + h3 = tanh(h2 @ Wfc) ----------------
__global__ __launch_bounds__(256) void fc_kernel(float* __restrict__ io,
        const double* __restrict__ dsum, const double* __restrict__ dsq,
        const float* __restrict__ g, const float* __restrict__ b,
        const float* __restrict__ W) {
    __shared__ __align__(16) float u_s[64][DIM + 4];
    __shared__ __align__(16) float w_s[DIM][DIM + 4];
    __shared__ float sc_s[DIM], sh_s[DIM];
    const int t = threadIdx.x;
    const int row0 = blockIdx.x * 64;
    bn_fold_rep<DIM>(t, dsum, dsq, g, b, sc_s, sh_s);
    __syncthreads();
    for (int i = t; i < DIM * DIM; i += 256) {
        int k = i >> 6, c = i & 63;
        w_s[c][k] = W[i];
    }
    for (int i = t; i < 64 * DIM; i += 256) {
        int r = i >> 6, k = i & 63;
        int rr = row0 + r;
        float v = 0.f;
        if (rr < NN) {
            size_t idx = (size_t)rr * 192 + 64 + k;
            v = fmaf(io[idx], sc_s[k], sh_s[k]);
            io[idx] = v;                       // h2
        }
        u_s[r][k] = v;
    }
    __syncthreads();
    const int cc = t & 15;
    const int r0 = (t >> 4) << 2;
    float acc[4][4];
    #pragma unroll
    for (int j = 0; j < 4; j++) { acc[0][j] = 0.f; acc[1][j] = 0.f; acc[2][j] = 0.f; acc[3][j] = 0.f; }
    #pragma unroll 4
    for (int k = 0; k < DIM; k += 4) {
        float4 w0 = *(const float4*)&w_s[cc][k];
        float4 w1 = *(const float4*)&w_s[cc + 16][k];
        float4 w2 = *(const float4*)&w_s[cc + 32][k];
        float4 w3 = *(const float4*)&w_s[cc + 48][k];
        #pragma unroll
        for (int i = 0; i < 4; i++) {
            float4 u = *(const float4*)&u_s[r0 + i][k];
            acc[i][0] = fmaf(u.x, w0.x, fmaf(u.y, w0.y, fmaf(u.z, w0.z, fmaf(u.w, w0.w, acc[i][0]))));
            acc[i][1] = fmaf(u.x, w1.x, fmaf(u.y, w1.y, fmaf(u.z, w1.z, fmaf(u.w, w1.w, acc[i][1]))));
            acc[i][2] = fmaf(u.x, w2.x, fmaf(u.y, w2.y, fmaf(u.z, w2.z, fmaf(u.w, w2.w, acc[i][2]))));
            acc[i][3] = fmaf(u.x, w3.x, fmaf(u.y, w3.y, fmaf(u.z, w3.z, fmaf(u.w, w3.w, acc[i][3]))));
        }
    }
    #pragma unroll
    for (int i = 0; i < 4; i++) {
        int rr = row0 + r0 + i;
        if (rr < NN) {
            #pragma unroll
            for (int j = 0; j < 4; j++)
                io[(size_t)rr * 192 + 128 + cc + 16 * j] = tanhf(acc[i][j]);
        }
    }
}

extern "C" void kernel_launch(void* const* d_in, const int* in_sizes, int n_in,
                              void* d_out, int out_size, void* d_ws, size_t ws_size,
                              hipStream_t stream) {
    const float* X      = (const float*)d_in[0];
    const int*   ei     = (const int*)  d_in[1];
    const float* ea     = (const float*)d_in[2];
    const float* bng    = (const float*)d_in[3];
    const float* bnb    = (const float*)d_in[4];
    const float* We0    = (const float*)d_in[5];
    const float* be0    = (const float*)d_in[6];
    const float* W0     = (const float*)d_in[7];
    const float* b0     = (const float*)d_in[8];
    const float* bn0g   = (const float*)d_in[9];
    const float* bn0b   = (const float*)d_in[10];
    const float* We1    = (const float*)d_in[11];
    const float* be1    = (const float*)d_in[12];
    const float* W1     = (const float*)d_in[13];
    const float* b1     = (const float*)d_in[14];
    const float* bn1g   = (const float*)d_in[15];
    const float* bn1b   = (const float*)d_in[16];
    const float* Wfc    = (const float*)d_in[17];

    const int* src = ei;
    const int* dst = ei + NE;
    float* out = (float*)d_out;

    // ---- workspace layout (~52 MB) ----
    int2*   src_ea  = (int2*)d_ws;                        // NE
    __half* t1h     = (__half*)(src_ea + NE);             // NN*DIM halves
    __half* Xh      = t1h + (size_t)NN * DIM;             // NN*INC halves
    int*    counts  = (int*)(Xh + (size_t)NN * INC);      // NN
    int*    offs    = counts + NN;                        // NN+1
    int*    cursor  = offs + NN + 1;                      // NN
    int*    bsums   = cursor + NN;                        // 128
    double* dstats = (double*)(((uintptr_t)(bsums + 128) + 15) & ~(uintptr_t)15);
    double* dsum_in = dstats;                          // NREP*128
    double* dsq_in  = dsum_in + NREP * INC;            // NREP*128
    double* dsum0   = dsq_in + NREP * INC;             // NREP*64
    double* dsq0    = dsum0 + NREP * DIM;              // NREP*64
    double* dsum1   = dsq0 + NREP * DIM;               // NREP*64
    double* dsq1    = dsum1 + NREP * DIM;              // NREP*64
    const size_t nstats = (size_t)NREP * (2 * INC + 4 * DIM);

    hipMemsetAsync(counts, 0, NN * sizeof(int), stream);
    hipMemsetAsync(dstats, 0, nstats * sizeof(double), stream);

    // fused input-BN stats + dst histogram
    stats_hist_kernel<<<SB + (NE + 255) / 256, 256, 0, stream>>>(X, dst, counts, dsum_in, dsq_in);

    // x̂ -> fp16 (depends only on stats)
    xhat_half_kernel<<<(NN * INC / 4 + 255) / 256, 256, 0, stream>>>(X, dsum_in, dsq_in, bng, bnb, Xh);

    // CSR build (shared by both layers)
    const int NB = (NN + 1023) / 1024;   // 98
    scan1_kernel<<<NB, 1024, 0, stream>>>(counts, offs, bsums);
    scan2_kernel<<<1, 128, 0, stream>>>(bsums, NB);
    scan3_kernel<<<(NN + 255) / 256, 256, 0, stream>>>(offs, bsums, cursor);
    // XCD-partitioned scatter: standalone 2048-block grid (resident in one wave)
    scatter_kernel<<<2048, 256, 0, stream>>>(src, dst, ea, cursor, src_ea);

    // layer 0 (fused agg + fp16-W GEMM + stats0), gathers fp16 x̂, writes fp16 t1
    gine0_kernel<<<(NN + 31) / 32, 512, 0, stream>>>(X, Xh, offs, src_ea, dsum_in, dsq_in, bng, bnb,
                                                     We0, be0, W0, b0, t1h, dsum0, dsq0);

    // layer 1 (fused finalize0 + BN-on-fly + h1 write + agg + GEMM + stats1), gathers fp16 t1
    gine1_kernel<<<(NN + 63) / 64, 512, 0, stream>>>(t1h, offs, src_ea, dsum0, dsq0, bn0g, bn0b,
                                                     We1, be1, W1, b1, out, dsum1, dsq1);

    // h2 (in place) + h3 (fused finalize1)
    fc_kernel<<<(NN + 63) / 64, 256, 0, stream>>>(out, dsum1, dsq1, bn1g, bn1b, Wfc);
}

// Round 15
// 428.301 us; speedup vs baseline: 1.1406x; 1.0339x over previous
//
#include <hip/hip_runtime.h>
#include <hip/hip_fp16.h>
#include <math.h>
#include <stdint.h>

#define NN 100000
#define NE 1600000
#define INC 128
#define DIM 64
#define EPS 1e-5f
#define SB 512    // stats blocks inside fused stats+hist kernel
#define NREP 8    // replicas for stats accumulators AND histogram counters
#define NPART 8   // scatter partitions (~1 per XCD)
#define PART_SZ ((NN + NPART - 1) / NPART)

struct __align__(8)  half4 { __half2 a, b; };
struct __align__(16) half8 { __half2 a, b, c, d; };

// packed fp16 max (ROCm header lacks __hmax2; emit v_pk_max_f16 directly)
__device__ inline __half2 h2max(__half2 a, __half2 b) {
    __half2 r;
    asm("v_pk_max_f16 %0, %1, %2" : "=v"(r) : "v"(a), "v"(b));
    return r;
}

// fused: blocks [0,SB) do X stats (C=128) in f64; blocks [SB,...) do replicated dst histogram
__global__ __launch_bounds__(256) void stats_hist_kernel(const float* __restrict__ X,
        const int* __restrict__ dst, int* __restrict__ counts,
        double* __restrict__ sum_out, double* __restrict__ sq_out) {
    __shared__ double ls[256], lq[256];
    if (blockIdx.x < SB) {
        int c  = threadIdx.x & 127;
        int rl = threadIdx.x >> 7;           // 2 rows per block step
        int row = blockIdx.x * 2 + rl;
        const int rstride = SB * 2;
        double s = 0.0, q = 0.0;
        for (int r = row; r < NN; r += rstride) {
            double v = (double)X[(size_t)r * INC + c];
            s += v; q += v * v;
        }
        ls[threadIdx.x] = s; lq[threadIdx.x] = q;
        __syncthreads();
        if (rl == 0) {
            s += ls[128 + c]; q += lq[128 + c];
            int rep = blockIdx.x & (NREP - 1);
            atomicAdd(&sum_out[rep * INC + c], s);
            atomicAdd(&sq_out[rep * INC + c], q);
        }
    } else {
        int bb = blockIdx.x - SB;
        int e = bb * 256 + threadIdx.x;
        if (e < NE) atomicAdd(&counts[(bb & (NREP - 1)) * NN + dst[e]], 1);
    }
}

// BN scale/shift from NREP-replicated f64 stats
template<int C>
__device__ inline void bn_fold_rep(int t, const double* dsum, const double* dsq,
                                   const float* g, const float* b, float* sc_s, float* sh_s) {
    if (t < C) {
        double s = 0.0, q = 0.0;
        #pragma unroll
        for (int r = 0; r < NREP; r++) { s += dsum[r * C + t]; q += dsq[r * C + t]; }
        double m = s / (double)NN;
        double v = q / (double)NN - m * m;
        double sc = (double)g[t] / sqrt(v + (double)EPS);
        sc_s[t] = (float)sc;
        sh_s[t] = (float)((double)b[t] - m * sc);
    }
}

// x̂ = BN(X) precomputed to fp16 [NN][128]
__global__ __launch_bounds__(256) void xhat_half_kernel(const float* __restrict__ X,
        const double* __restrict__ dsum, const double* __restrict__ dsq,
        const float* __restrict__ g, const float* __restrict__ b,
        __half* __restrict__ Xh) {
    __shared__ float sc_s[INC], sh_s[INC];
    bn_fold_rep<INC>(threadIdx.x, dsum, dsq, g, b, sc_s, sh_s);
    __syncthreads();
    size_t i = (size_t)blockIdx.x * 256 + threadIdx.x;   // one float4 per thread
    size_t e4 = i * 4;
    if (e4 >= (size_t)NN * INC) return;
    int c = (int)(e4 & 127);
    float4 x = *(const float4*)(X + e4);
    half4 h;
    h.a = __floats2half2_rn(fmaf(x.x, sc_s[c], sh_s[c]), fmaf(x.y, sc_s[c + 1], sh_s[c + 1]));
    h.b = __floats2half2_rn(fmaf(x.z, sc_s[c + 2], sh_s[c + 2]), fmaf(x.w, sc_s[c + 3], sh_s[c + 3]));
    *(half4*)(Xh + e4) = h;
}

// ---------------- CSR build: scan ----------------
__global__ __launch_bounds__(1024) void scan1_kernel(const int* __restrict__ counts,
                                                     int* __restrict__ offs, int* __restrict__ bsums) {
    __shared__ int tmp[2][1024];
    int t = threadIdx.x;
    int g = blockIdx.x * 1024 + t;
    int v = 0;
    if (g < NN) {
        #pragma unroll
        for (int r = 0; r < NREP; r++) v += counts[r * NN + g];
    }
    tmp[0][t] = v;
    __syncthreads();
    int pin = 0;
    for (int d = 1; d < 1024; d <<= 1) {
        int x = tmp[pin][t] + ((t >= d) ? tmp[pin][t - d] : 0);
        tmp[pin ^ 1][t] = x;
        pin ^= 1;
        __syncthreads();
    }
    int incl = tmp[pin][t];
    if (g < NN) offs[g] = incl - v;
    if (t == 1023) bsums[blockIdx.x] = incl;
}

__global__ __launch_bounds__(128) void scan2_kernel(int* __restrict__ bsums, int nb) {
    __shared__ int tmp[2][128];
    int t = threadIdx.x;
    int v = (t < nb) ? bsums[t] : 0;
    tmp[0][t] = v;
    __syncthreads();
    int pin = 0;
    for (int d = 1; d < 128; d <<= 1) {
        int x = tmp[pin][t] + ((t >= d) ? tmp[pin][t - d] : 0);
        tmp[pin ^ 1][t] = x;
        pin ^= 1;
        __syncthreads();
    }
    if (t < nb) bsums[t] = tmp[pin][t] - v;
}

// final offsets + per-node scatter cursors
__global__ __launch_bounds__(256) void scan3_kernel(int* __restrict__ offs, const int* __restrict__ bsums,
                                                    int* __restrict__ cursor) {
    int g = blockIdx.x * 256 + threadIdx.x;
    if (g < NN) {
        int o = offs[g] + bsums[g >> 10];
        offs[g] = o;
        cursor[g] = o;
    }
    if (g == 0) offs[NN] = NE;
}

// XCD-partitioned scatter (standalone 2048-block grid)
__global__ __launch_bounds__(256) void scatter_kernel(const int* __restrict__ src, const int* __restrict__ dst,
                                                      const float* __restrict__ ea, int* __restrict__ cursor,
                                                      int2* __restrict__ src_ea) {
    const int p = blockIdx.x & (NPART - 1);
    const int blk = blockIdx.x >> 3;
    const int nblk = gridDim.x >> 3;
    const int lo = p * PART_SZ;
    const int hi = min(NN, lo + PART_SZ);
    for (int e = blk * 256 + threadIdx.x; e < NE; e += nblk * 256) {
        int d = dst[e];
        if (d >= lo && d < hi) {
            int pos = atomicAdd(&cursor[d], 1);
            src_ea[pos] = make_int2(src[e], __float_as_int(ea[e]));
        }
    }
}

// ---------------- fused layer 0: gather-agg (packed fp16 math, quarter-wave, 2-deep) + fp16-W GEMM + tanh + stats ----------------
// 32 nodes per 512-thread block. 35.3KB LDS -> 4 blocks/CU.
__global__ __launch_bounds__(512, 8) void gine0_kernel(const float* __restrict__ X,
        const __half* __restrict__ Xh,
        const int* __restrict__ offs, const int2* __restrict__ src_ea,
        const double* __restrict__ dsum, const double* __restrict__ dsq,
        const float* __restrict__ g, const float* __restrict__ b,
        const float* __restrict__ We, const float* __restrict__ be,
        const float* __restrict__ W, const float* __restrict__ bvec,
        __half* __restrict__ t1h, double* __restrict__ dsum0, double* __restrict__ dsq0) {
    __shared__ __align__(16) float  u_s[32][INC + 4];    // 16.9 KB (reused for stats reduce)
    __shared__ __align__(16) __half w_sh[DIM][INC + 8];  // 17.4 KB, fp16 W
    __shared__ float sc_s[INC], sh_s[INC];
    const int t = threadIdx.x;
    const int row0 = blockIdx.x * 32;
    bn_fold_rep<INC>(t, dsum, dsq, g, b, sc_s, sh_s);
    for (int i = t; i < INC * DIM; i += 512) {
        int k = i >> 6, c = i & 63;
        w_sh[c][k] = __float2half_rn(W[i]);
    }
    __syncthreads();
    const int wid = t >> 6, l = t & 63;
    const int quarter = l >> 4;
    const int c8 = (l & 15) * 8;
    const __half2 z2 = __float2half2_rn(0.f);
    __half2 wvh0 = __floats2half2_rn(We[c8],     We[c8 + 1]);
    __half2 wvh1 = __floats2half2_rn(We[c8 + 2], We[c8 + 3]);
    __half2 wvh2 = __floats2half2_rn(We[c8 + 4], We[c8 + 5]);
    __half2 wvh3 = __floats2half2_rn(We[c8 + 6], We[c8 + 7]);
    __half2 bvh0 = __floats2half2_rn(be[c8],     be[c8 + 1]);
    __half2 bvh1 = __floats2half2_rn(be[c8 + 2], be[c8 + 3]);
    __half2 bvh2 = __floats2half2_rn(be[c8 + 4], be[c8 + 5]);
    __half2 bvh3 = __floats2half2_rn(be[c8 + 6], be[c8 + 7]);

    // packed fp16: relu(x + (a*We+be)) accumulated in fp16 (short per-quarter sums)
    #define G0_ACC(vh, av2)  do { \
        ah0 = __hadd2(ah0, h2max(__hadd2((vh).a, __hfma2((av2), wvh0, bvh0)), z2)); \
        ah1 = __hadd2(ah1, h2max(__hadd2((vh).b, __hfma2((av2), wvh1, bvh1)), z2)); \
        ah2 = __hadd2(ah2, h2max(__hadd2((vh).c, __hfma2((av2), wvh2, bvh2)), z2)); \
        ah3 = __hadd2(ah3, h2max(__hadd2((vh).d, __hfma2((av2), wvh3, bvh3)), z2)); \
    } while (0)

    for (int nn = 0; nn < 4; ++nn) {
        int r = wid * 4 + nn;
        int n = row0 + r;
        __half2 ah0 = z2, ah1 = z2, ah2 = z2, ah3 = z2;
        if (n < NN) {
            int beg = offs[n], end = offs[n + 1];
            for (int base = beg; base < end; base += 64) {
                int j = base + l;
                int2 p = (j < end) ? src_ea[j] : make_int2(0, 0);
                float avf = __int_as_float(p.y);
                int cnt = min(64, end - base);
                int tt = 0;
                for (; tt + 8 <= cnt; tt += 8) {
                    int e0 = tt + quarter, e1 = tt + 4 + quarter;
                    int s0 = __shfl(p.x, e0), s1 = __shfl(p.x, e1);
                    float av0 = __shfl(avf, e0), av1 = __shfl(avf, e1);
                    half8 v0 = *(const half8*)(Xh + (size_t)s0 * INC + c8);
                    half8 v1 = *(const half8*)(Xh + (size_t)s1 * INC + c8);
                    __half2 a2_0 = __half2half2(__float2half_rn(av0));
                    __half2 a2_1 = __half2half2(__float2half_rn(av1));
                    G0_ACC(v0, a2_0); G0_ACC(v1, a2_1);
                }
                for (; tt < cnt; tt += 4) {
                    int e0 = tt + quarter;
                    int es = min(e0, cnt - 1);
                    int s0 = __shfl(p.x, es);
                    float av0 = __shfl(avf, es);
                    if (e0 < cnt) {
                        half8 v0 = *(const half8*)(Xh + (size_t)s0 * INC + c8);
                        __half2 a2_0 = __half2half2(__float2half_rn(av0));
                        G0_ACC(v0, a2_0);
                    }
                }
            }
        }
        // convert to f32, combine quarters
        float2 p0 = __half22float2(ah0), p1 = __half22float2(ah1);
        float2 p2 = __half22float2(ah2), p3 = __half22float2(ah3);
        float a0 = p0.x, a1 = p0.y, a2 = p1.x, a3 = p1.y;
        float a4 = p2.x, a5 = p2.y, a6 = p3.x, a7 = p3.y;
        a0 += __shfl_xor(a0, 16); a0 += __shfl_xor(a0, 32);
        a1 += __shfl_xor(a1, 16); a1 += __shfl_xor(a1, 32);
        a2 += __shfl_xor(a2, 16); a2 += __shfl_xor(a2, 32);
        a3 += __shfl_xor(a3, 16); a3 += __shfl_xor(a3, 32);
        a4 += __shfl_xor(a4, 16); a4 += __shfl_xor(a4, 32);
        a5 += __shfl_xor(a5, 16); a5 += __shfl_xor(a5, 32);
        a6 += __shfl_xor(a6, 16); a6 += __shfl_xor(a6, 32);
        a7 += __shfl_xor(a7, 16); a7 += __shfl_xor(a7, 32);
        if (quarter == 0) {
            if (n < NN) {
                // self term from f32 X for precision
                float4 x0 = *(const float4*)(X + (size_t)n * INC + c8);
                float4 x1 = *(const float4*)(X + (size_t)n * INC + c8 + 4);
                a0 += fmaf(x0.x, sc_s[c8],     sh_s[c8]);
                a1 += fmaf(x0.y, sc_s[c8 + 1], sh_s[c8 + 1]);
                a2 += fmaf(x0.z, sc_s[c8 + 2], sh_s[c8 + 2]);
                a3 += fmaf(x0.w, sc_s[c8 + 3], sh_s[c8 + 3]);
                a4 += fmaf(x1.x, sc_s[c8 + 4], sh_s[c8 + 4]);
                a5 += fmaf(x1.y, sc_s[c8 + 5], sh_s[c8 + 5]);
                a6 += fmaf(x1.z, sc_s[c8 + 6], sh_s[c8 + 6]);
                a7 += fmaf(x1.w, sc_s[c8 + 7], sh_s[c8 + 7]);
            }
            *(float4*)&u_s[r][c8]     = make_float4(a0, a1, a2, a3);
            *(float4*)&u_s[r][c8 + 4] = make_float4(a4, a5, a6, a7);
        }
    }
    #undef G0_ACC
    __syncthreads();
    // GEMM (fp16 weights): 32x64 outputs, 512 threads -> 4 outputs each
    const int cc = t & 15;
    const int rg = t >> 4;                 // row 0..31
    float acc0 = bvec[cc], acc1 = bvec[cc + 16], acc2 = bvec[cc + 32], acc3 = bvec[cc + 48];
    #pragma unroll 2
    for (int k = 0; k < INC; k += 8) {
        float4 ua = *(const float4*)&u_s[rg][k];
        float4 ub = *(const float4*)&u_s[rg][k + 4];
        half8 w0 = *(const half8*)&w_sh[cc][k];
        half8 w1 = *(const half8*)&w_sh[cc + 16][k];
        half8 w2 = *(const half8*)&w_sh[cc + 32][k];
        half8 w3 = *(const half8*)&w_sh[cc + 48][k];
        float2 p;
        p = __half22float2(w0.a); acc0 = fmaf(ua.x, p.x, fmaf(ua.y, p.y, acc0));
        p = __half22float2(w0.b); acc0 = fmaf(ua.z, p.x, fmaf(ua.w, p.y, acc0));
        p = __half22float2(w0.c); acc0 = fmaf(ub.x, p.x, fmaf(ub.y, p.y, acc0));
        p = __half22float2(w0.d); acc0 = fmaf(ub.z, p.x, fmaf(ub.w, p.y, acc0));
        p = __half22float2(w1.a); acc1 = fmaf(ua.x, p.x, fmaf(ua.y, p.y, acc1));
        p = __half22float2(w1.b); acc1 = fmaf(ua.z, p.x, fmaf(ua.w, p.y, acc1));
        p = __half22float2(w1.c); acc1 = fmaf(ub.x, p.x, fmaf(ub.y, p.y, acc1));
        p = __half22float2(w1.d); acc1 = fmaf(ub.z, p.x, fmaf(ub.w, p.y, acc1));
        p = __half22float2(w2.a); acc2 = fmaf(ua.x, p.x, fmaf(ua.y, p.y, acc2));
        p = __half22float2(w2.b); acc2 = fmaf(ua.z, p.x, fmaf(ua.w, p.y, acc2));
        p = __half22float2(w2.c); acc2 = fmaf(ub.x, p.x, fmaf(ub.y, p.y, acc2));
        p = __half22float2(w2.d); acc2 = fmaf(ub.z, p.x, fmaf(ub.w, p.y, acc2));
        p = __half22float2(w3.a); acc3 = fmaf(ua.x, p.x, fmaf(ua.y, p.y, acc3));
        p = __half22float2(w3.b); acc3 = fmaf(ua.z, p.x, fmaf(ua.w, p.y, acc3));
        p = __half22float2(w3.c); acc3 = fmaf(ub.x, p.x, fmaf(ub.y, p.y, acc3));
        p = __half22float2(w3.d); acc3 = fmaf(ub.z, p.x, fmaf(ub.w, p.y, acc3));
    }
    int rr = row0 + rg;
    float t0 = tanhf(acc0), t1v = tanhf(acc1), t2v = tanhf(acc2), t3v = tanhf(acc3);
    if (rr < NN) {
        __half* op = t1h + (size_t)rr * DIM;
        op[cc]      = __float2half_rn(t0);
        op[cc + 16] = __float2half_rn(t1v);
        op[cc + 32] = __float2half_rn(t2v);
        op[cc + 48] = __float2half_rn(t3v);
    }
    // fused per-channel stats from f32 values (reuse u_s)
    __syncthreads();
    float* red_s = (float*)u_s;
    float* red_q = red_s + 2048;
    bool ok = (rr < NN);
    red_s[rg * 64 + cc]      = ok ? t0 : 0.f;
    red_s[rg * 64 + cc + 16] = ok ? t1v : 0.f;
    red_s[rg * 64 + cc + 32] = ok ? t2v : 0.f;
    red_s[rg * 64 + cc + 48] = ok ? t3v : 0.f;
    red_q[rg * 64 + cc]      = ok ? t0 * t0 : 0.f;
    red_q[rg * 64 + cc + 16] = ok ? t1v * t1v : 0.f;
    red_q[rg * 64 + cc + 32] = ok ? t2v * t2v : 0.f;
    red_q[rg * 64 + cc + 48] = ok ? t3v * t3v : 0.f;
    __syncthreads();
    if (t < 64) {
        float s = 0.f, q = 0.f;
        #pragma unroll
        for (int i = 0; i < 32; i++) { s += red_s[i * 64 + t]; q += red_q[i * 64 + t]; }
        int rep = blockIdx.x & (NREP - 1);
        atomicAdd(&dsum0[rep * DIM + t], (double)s);
        atomicAdd(&dsq0[rep * DIM + t], (double)q);
    }
}

// ---------------- fused layer 1: BN(fp16 t1) on the fly (f32 math) + h1 write + gather-agg (2-deep) + GEMM + tanh + stats ----------------
__global__ __launch_bounds__(512) void gine1_kernel(const __half* __restrict__ t1h,
        const int* __restrict__ offs, const int2* __restrict__ src_ea,
        const double* __restrict__ dsum, const double* __restrict__ dsq,
        const float* __restrict__ g, const float* __restrict__ b,
        const float* __restrict__ We, const float* __restrict__ be,
        const float* __restrict__ W, const float* __restrict__ bvec,
        float* __restrict__ out, double* __restrict__ dsum1, double* __restrict__ dsq1) {
    __shared__ __align__(16) float u_s[64][DIM + 4];   // 17.4 KB
    __shared__ __align__(16) float w_s[DIM][DIM + 4];  // 17.4 KB (reused for stats reduce)
    __shared__ float sc_s[DIM], sh_s[DIM];
    const int t = threadIdx.x;
    const int row0 = blockIdx.x * 64;
    bn_fold_rep<DIM>(t, dsum, dsq, g, b, sc_s, sh_s);
    for (int i = t; i < DIM * DIM; i += 512) {
        int k = i >> 6, c = i & 63;
        w_s[c][k] = W[i];
    }
    __syncthreads();
    const int wid = t >> 6, l = t & 63;
    const int quarter = l >> 4;
    const int c4 = (l & 15) * 4;
    float4 wv = *(const float4*)(We + c4);
    float4 bv = *(const float4*)(be + c4);
    float4 sc4 = *(const float4*)(sc_s + c4);
    float4 sh4 = *(const float4*)(sh_s + c4);

    #define G1_ACC(vh, av)  do { \
        float2 f00 = __half22float2((vh).a), f01 = __half22float2((vh).b); \
        a0 += fmaxf(fmaf(f00.x, sc4.x, sh4.x) + fmaf((av), wv.x, bv.x), 0.f); \
        a1 += fmaxf(fmaf(f00.y, sc4.y, sh4.y) + fmaf((av), wv.y, bv.y), 0.f); \
        a2 += fmaxf(fmaf(f01.x, sc4.z, sh4.z) + fmaf((av), wv.z, bv.z), 0.f); \
        a3 += fmaxf(fmaf(f01.y, sc4.w, sh4.w) + fmaf((av), wv.w, bv.w), 0.f); \
    } while (0)

    for (int nn = 0; nn < 8; ++nn) {
        int r = wid * 8 + nn;
        int n = row0 + r;
        float a0 = 0.f, a1 = 0.f, a2 = 0.f, a3 = 0.f;
        if (n < NN) {
            int beg = offs[n], end = offs[n + 1];
            for (int base = beg; base < end; base += 64) {
                int j = base + l;
                int2 p = (j < end) ? src_ea[j] : make_int2(0, 0);
                float avf = __int_as_float(p.y);
                int cnt = min(64, end - base);
                int tt = 0;
                for (; tt + 8 <= cnt; tt += 8) {
                    int e0 = tt + quarter, e1 = tt + 4 + quarter;
                    int s0 = __shfl(p.x, e0), s1 = __shfl(p.x, e1);
                    float av0 = __shfl(avf, e0), av1 = __shfl(avf, e1);
                    half4 v0 = *(const half4*)(t1h + (size_t)s0 * DIM + c4);
                    half4 v1 = *(const half4*)(t1h + (size_t)s1 * DIM + c4);
                    G1_ACC(v0, av0); G1_ACC(v1, av1);
                }
                for (; tt < cnt; tt += 4) {
                    int e0 = tt + quarter;
                    int es = min(e0, cnt - 1);
                    int s0 = __shfl(p.x, es);
                    float av0 = __shfl(avf, es);
                    if (e0 < cnt) {
                        half4 v0 = *(const half4*)(t1h + (size_t)s0 * DIM + c4);
                        G1_ACC(v0, av0);
                    }
                }
            }
        }
        a0 += __shfl_xor(a0, 16); a0 += __shfl_xor(a0, 32);
        a1 += __shfl_xor(a1, 16); a1 += __shfl_xor(a1, 32);
        a2 += __shfl_xor(a2, 16); a2 += __shfl_xor(a2, 32);
        a3 += __shfl_xor(a3, 16); a3 += __shfl_xor(a3, 32);
        if (quarter == 0) {
            if (n < NN) {
                half4 h = *(const half4*)(t1h + (size_t)n * DIM + c4);
                float2 f0 = __half22float2(h.a), f1 = __half22float2(h.b);
                float h0 = fmaf(f0.x, sc4.x, sh4.x);
                float h1 = fmaf(f0.y, sc4.y, sh4.y);
                float h2 = fmaf(f1.x, sc4.z, sh4.z);
                float h3 = fmaf(f1.y, sc4.w, sh4.w);
                *(float4*)(out + (size_t)n * 192 + c4) = make_float4(h0, h1, h2, h3);   // h1
                a0 += h0; a1 += h1; a2 += h2; a3 += h3;
            }
            *(float4*)&u_s[r][c4] = make_float4(a0, a1, a2, a3);
        }
    }
    #undef G1_ACC
    __syncthreads();
    // GEMM: 64x64 outputs, 512 threads -> 8 outputs each (2 rows x 4 cols)
    const int cc = t & 15;
    const int r0 = (t >> 4) * 2;
    float acc[2][4];
    #pragma unroll
    for (int j = 0; j < 4; j++) {
        float bj = bvec[cc + 16 * j];
        acc[0][j] = bj; acc[1][j] = bj;
    }
    #pragma unroll 4
    for (int k = 0; k < DIM; k += 4) {
        float4 w0 = *(const float4*)&w_s[cc][k];
        float4 w1 = *(const float4*)&w_s[cc + 16][k];
        float4 w2 = *(const float4*)&w_s[cc + 32][k];
        float4 w3 = *(const float4*)&w_s[cc + 48][k];
        #pragma unroll
        for (int i = 0; i < 2; i++) {
            float4 u = *(const float4*)&u_s[r0 + i][k];
            acc[i][0] = fmaf(u.x, w0.x, fmaf(u.y, w0.y, fmaf(u.z, w0.z, fmaf(u.w, w0.w, acc[i][0]))));
            acc[i][1] = fmaf(u.x, w1.x, fmaf(u.y, w1.y, fmaf(u.z, w1.z, fmaf(u.w, w1.w, acc[i][1]))));
            acc[i][2] = fmaf(u.x, w2.x, fmaf(u.y, w2.y, fmaf(u.z, w2.z, fmaf(u.w, w2.w, acc[i][2]))));
            acc[i][3] = fmaf(u.x, w3.x, fmaf(u.y, w3.y, fmaf(u.z, w3.z, fmaf(u.w, w3.w, acc[i][3]))));
        }
    }
    float tv[2][4];
    #pragma unroll
    for (int i = 0; i < 2; i++) {
        int rr = row0 + r0 + i;
        #pragma unroll
        for (int j = 0; j < 4; j++) tv[i][j] = tanhf(acc[i][j]);
        if (rr < NN) {
            float* op = out + (size_t)rr * 192 + 64;
            #pragma unroll
            for (int j = 0; j < 4; j++) op[cc + 16 * j] = tv[i][j];
        }
    }
    // fused per-channel stats of t2 (reuse w_s)
    __syncthreads();
    float* red_s = (float*)w_s;
    float* red_q = red_s + 2048;
    const int rgp = t >> 4;
    bool ok0 = (row0 + r0 < NN), ok1 = (row0 + r0 + 1 < NN);
    #pragma unroll
    for (int j = 0; j < 4; j++) {
        float v0 = ok0 ? tv[0][j] : 0.f;
        float v1 = ok1 ? tv[1][j] : 0.f;
        red_s[rgp * 64 + cc + 16 * j] = v0 + v1;
        red_q[rgp * 64 + cc + 16 * j] = v0 * v0 + v1 * v1;
    }
    __syncthreads();
    if (t < 64) {
        float s = 0.f, q = 0.f;
        #pragma unroll
        for (int i = 0; i < 32; i++) { s += red_s[i * 64 + t]; q += red_q[i * 64 + t]; }
        int rep = blockIdx.x & (NREP - 1);
        atomicAdd(&dsum1[rep * DIM + t], (double)s);
        atomicAdd(&dsq1[rep * DIM + t], (double)q);
    }
}

// ---------------- fused: finalize1 + h2 = BN(t2) in place + h3 = tanh(h2 @ Wfc) ----------------
__global__ __launch_bounds__(256) void fc_kernel(float* __restrict__ io,
        const double* __restrict__ dsum, const double* __restrict__ dsq,
        const float* __restrict__ g, const float* __restrict__ b,
        const float* __restrict__ W) {
    __shared__ __align__(16) float u_s[64][DIM + 4];
    __shared__ __align__(16) float w_s[DIM][DIM + 4];
    __shared__ float sc_s[DIM], sh_s[DIM];
    const int t = threadIdx.x;
    const int row0 = blockIdx.x * 64;
    bn_fold_rep<DIM>(t, dsum, dsq, g, b, sc_s, sh_s);
    __syncthreads();
    for (int i = t; i < DIM * DIM; i += 256) {
        int k = i >> 6, c = i & 63;
        w_s[c][k] = W[i];
    }
    for (int i = t; i < 64 * DIM; i += 256) {
        int r = i >> 6, k = i & 63;
        int rr = row0 + r;
        float v = 0.f;
        if (rr < NN) {
            size_t idx = (size_t)rr * 192 + 64 + k;
            v = fmaf(io[idx], sc_s[k], sh_s[k]);
            io[idx] = v;                       // h2
        }
        u_s[r][k] = v;
    }
    __syncthreads();
    const int cc = t & 15;
    const int r0 = (t >> 4) << 2;
    float acc[4][4];
    #pragma unroll
    for (int j = 0; j < 4; j++) { acc[0][j] = 0.f; acc[1][j] = 0.f; acc[2][j] = 0.f; acc[3][j] = 0.f; }
    #pragma unroll 4
    for (int k = 0; k < DIM; k += 4) {
        float4 w0 = *(const float4*)&w_s[cc][k];
        float4 w1 = *(const float4*)&w_s[cc + 16][k];
        float4 w2 = *(const float4*)&w_s[cc + 32][k];
        float4 w3 = *(const float4*)&w_s[cc + 48][k];
        #pragma unroll
        for (int i = 0; i < 4; i++) {
            float4 u = *(const float4*)&u_s[r0 + i][k];
            acc[i][0] = fmaf(u.x, w0.x, fmaf(u.y, w0.y, fmaf(u.z, w0.z, fmaf(u.w, w0.w, acc[i][0]))));
            acc[i][1] = fmaf(u.x, w1.x, fmaf(u.y, w1.y, fmaf(u.z, w1.z, fmaf(u.w, w1.w, acc[i][1]))));
            acc[i][2] = fmaf(u.x, w2.x, fmaf(u.y, w2.y, fmaf(u.z, w2.z, fmaf(u.w, w2.w, acc[i][2]))));
            acc[i][3] = fmaf(u.x, w3.x, fmaf(u.y, w3.y, fmaf(u.z, w3.z, fmaf(u.w, w3.w, acc[i][3]))));
        }
    }
    #pragma unroll
    for (int i = 0; i < 4; i++) {
        int rr = row0 + r0 + i;
        if (rr < NN) {
            #pragma unroll
            for (int j = 0; j < 4; j++)
                io[(size_t)rr * 192 + 128 + cc + 16 * j] = tanhf(acc[i][j]);
        }
    }
}

extern "C" void kernel_launch(void* const* d_in, const int* in_sizes, int n_in,
                              void* d_out, int out_size, void* d_ws, size_t ws_size,
                              hipStream_t stream) {
    const float* X      = (const float*)d_in[0];
    const int*   ei     = (const int*)  d_in[1];
    const float* ea     = (const float*)d_in[2];
    const float* bng    = (const float*)d_in[3];
    const float* bnb    = (const float*)d_in[4];
    const float* We0    = (const float*)d_in[5];
    const float* be0    = (const float*)d_in[6];
    const float* W0     = (const float*)d_in[7];
    const float* b0     = (const float*)d_in[8];
    const float* bn0g   = (const float*)d_in[9];
    const float* bn0b   = (const float*)d_in[10];
    const float* We1    = (const float*)d_in[11];
    const float* be1    = (const float*)d_in[12];
    const float* W1     = (const float*)d_in[13];
    const float* b1     = (const float*)d_in[14];
    const float* bn1g   = (const float*)d_in[15];
    const float* bn1b   = (const float*)d_in[16];
    const float* Wfc    = (const float*)d_in[17];

    const int* src = ei;
    const int* dst = ei + NE;
    float* out = (float*)d_out;

    // ---- workspace layout (~55 MB) ----
    int2*   src_ea  = (int2*)d_ws;                        // NE
    __half* t1h     = (__half*)(src_ea + NE);             // NN*DIM halves
    __half* Xh      = t1h + (size_t)NN * DIM;             // NN*INC halves
    int*    counts  = (int*)(Xh + (size_t)NN * INC);      // NREP*NN
    int*    offs    = counts + (size_t)NREP * NN;         // NN+1
    int*    cursor  = offs + NN + 1;                      // NN
    int*    bsums   = cursor + NN;                        // 128
    double* dstats = (double*)(((uintptr_t)(bsums + 128) + 15) & ~(uintptr_t)15);
    double* dsum_in = dstats;                          // NREP*128
    double* dsq_in  = dsum_in + NREP * INC;            // NREP*128
    double* dsum0   = dsq_in + NREP * INC;             // NREP*64
    double* dsq0    = dsum0 + NREP * DIM;              // NREP*64
    double* dsum1   = dsq0 + NREP * DIM;               // NREP*64
    double* dsq1    = dsum1 + NREP * DIM;              // NREP*64
    const size_t nstats = (size_t)NREP * (2 * INC + 4 * DIM);

    hipMemsetAsync(counts, 0, (size_t)NREP * NN * sizeof(int), stream);
    hipMemsetAsync(dstats, 0, nstats * sizeof(double), stream);

    // fused input-BN stats + replicated dst histogram
    stats_hist_kernel<<<SB + (NE + 255) / 256, 256, 0, stream>>>(X, dst, counts, dsum_in, dsq_in);

    // x̂ -> fp16 (depends only on stats)
    xhat_half_kernel<<<(NN * INC / 4 + 255) / 256, 256, 0, stream>>>(X, dsum_in, dsq_in, bng, bnb, Xh);

    // CSR build (shared by both layers)
    const int NB = (NN + 1023) / 1024;   // 98
    scan1_kernel<<<NB, 1024, 0, stream>>>(counts, offs, bsums);
    scan2_kernel<<<1, 128, 0, stream>>>(bsums, NB);
    scan3_kernel<<<(NN + 255) / 256, 256, 0, stream>>>(offs, bsums, cursor);
    // XCD-partitioned scatter: standalone 2048-block grid (resident in one wave)
    scatter_kernel<<<2048, 256, 0, stream>>>(src, dst, ea, cursor, src_ea);

    // layer 0 (fused agg + fp16-W GEMM + stats0), packed-fp16 gather math
    gine0_kernel<<<(NN + 31) / 32, 512, 0, stream>>>(X, Xh, offs, src_ea, dsum_in, dsq_in, bng, bnb,
                                                     We0, be0, W0, b0, t1h, dsum0, dsq0);

    // layer 1 (fused finalize0 + BN-on-fly + h1 write + agg + GEMM + stats1), f32 gather math
    gine1_kernel<<<(NN + 63) / 64, 512, 0, stream>>>(t1h, offs, src_ea, dsum0, dsq0, bn0g, bn0b,
                                                     We1, be1, W1, b1, out, dsum1, dsq1);

    // h2 (in place) + h3 (fused finalize1)
    fc_kernel<<<(NN + 63) / 64, 256, 0, stream>>>(out, dsum1, dsq1, bn1g, bn1b, Wfc);
}

// Round 16
// 418.843 us; speedup vs baseline: 1.1663x; 1.0226x over previous
//
#include <hip/hip_runtime.h>
#include <hip/hip_fp16.h>
#include <math.h>
#include <stdint.h>

#define NN 100000
#define NE 1600000
#define INC 128
#define DIM 64
#define EPS 1e-5f
#define SB 512    // stats blocks inside fused stats+hist kernel
#define NREP 8    // replicas for stats accumulators AND histogram counters
#define NPART 4   // scatter partitions (write set 12.8MB/4 = 3.2MB < 4MB L2)
#define PART_SZ ((NN + NPART - 1) / NPART)

struct __align__(8)  half4 { __half2 a, b; };
struct __align__(16) half8 { __half2 a, b, c, d; };

// packed fp16 max (ROCm header lacks __hmax2; emit v_pk_max_f16 directly)
__device__ inline __half2 h2max(__half2 a, __half2 b) {
    __half2 r;
    asm("v_pk_max_f16 %0, %1, %2" : "=v"(r) : "v"(a), "v"(b));
    return r;
}

// fused: blocks [0,SB) do X stats (C=128) in f64; blocks [SB,...) do replicated dst histogram
__global__ __launch_bounds__(256) void stats_hist_kernel(const float* __restrict__ X,
        const int* __restrict__ dst, int* __restrict__ counts,
        double* __restrict__ sum_out, double* __restrict__ sq_out) {
    __shared__ double ls[256], lq[256];
    if (blockIdx.x < SB) {
        int c  = threadIdx.x & 127;
        int rl = threadIdx.x >> 7;           // 2 rows per block step
        int row = blockIdx.x * 2 + rl;
        const int rstride = SB * 2;
        double s = 0.0, q = 0.0;
        for (int r = row; r < NN; r += rstride) {
            double v = (double)X[(size_t)r * INC + c];
            s += v; q += v * v;
        }
        ls[threadIdx.x] = s; lq[threadIdx.x] = q;
        __syncthreads();
        if (rl == 0) {
            s += ls[128 + c]; q += lq[128 + c];
            int rep = blockIdx.x & (NREP - 1);
            atomicAdd(&sum_out[rep * INC + c], s);
            atomicAdd(&sq_out[rep * INC + c], q);
        }
    } else {
        int bb = blockIdx.x - SB;
        int e = bb * 256 + threadIdx.x;
        if (e < NE) atomicAdd(&counts[(bb & (NREP - 1)) * NN + dst[e]], 1);
    }
}

// BN scale/shift from NREP-replicated f64 stats
template<int C>
__device__ inline void bn_fold_rep(int t, const double* dsum, const double* dsq,
                                   const float* g, const float* b, float* sc_s, float* sh_s) {
    if (t < C) {
        double s = 0.0, q = 0.0;
        #pragma unroll
        for (int r = 0; r < NREP; r++) { s += dsum[r * C + t]; q += dsq[r * C + t]; }
        double m = s / (double)NN;
        double v = q / (double)NN - m * m;
        double sc = (double)g[t] / sqrt(v + (double)EPS);
        sc_s[t] = (float)sc;
        sh_s[t] = (float)((double)b[t] - m * sc);
    }
}

// x̂ = BN(X) precomputed to fp16 [NN][128]
__global__ __launch_bounds__(256) void xhat_half_kernel(const float* __restrict__ X,
        const double* __restrict__ dsum, const double* __restrict__ dsq,
        const float* __restrict__ g, const float* __restrict__ b,
        __half* __restrict__ Xh) {
    __shared__ float sc_s[INC], sh_s[INC];
    bn_fold_rep<INC>(threadIdx.x, dsum, dsq, g, b, sc_s, sh_s);
    __syncthreads();
    size_t i = (size_t)blockIdx.x * 256 + threadIdx.x;   // one float4 per thread
    size_t e4 = i * 4;
    if (e4 >= (size_t)NN * INC) return;
    int c = (int)(e4 & 127);
    float4 x = *(const float4*)(X + e4);
    half4 h;
    h.a = __floats2half2_rn(fmaf(x.x, sc_s[c], sh_s[c]), fmaf(x.y, sc_s[c + 1], sh_s[c + 1]));
    h.b = __floats2half2_rn(fmaf(x.z, sc_s[c + 2], sh_s[c + 2]), fmaf(x.w, sc_s[c + 3], sh_s[c + 3]));
    *(half4*)(Xh + e4) = h;
}

// h1 = BN0(t1): writes f32 to out[:,0:64] AND fp16 to h1h (gather table for gine1)
__global__ __launch_bounds__(256) void h1_kernel(const __half* __restrict__ t1h,
        const double* __restrict__ dsum, const double* __restrict__ dsq,
        const float* __restrict__ g, const float* __restrict__ b,
        float* __restrict__ out, __half* __restrict__ h1h) {
    __shared__ float sc_s[DIM], sh_s[DIM];
    bn_fold_rep<DIM>(threadIdx.x, dsum, dsq, g, b, sc_s, sh_s);
    __syncthreads();
    size_t i = (size_t)blockIdx.x * 256 + threadIdx.x;   // 4 channels per thread
    size_t e4 = i * 4;
    if (e4 >= (size_t)NN * DIM) return;
    int c = (int)(e4 & 63);
    size_t n = e4 >> 6;
    half4 tv = *(const half4*)(t1h + e4);
    float2 f0 = __half22float2(tv.a), f1 = __half22float2(tv.b);
    float h0 = fmaf(f0.x, sc_s[c],     sh_s[c]);
    float h1 = fmaf(f0.y, sc_s[c + 1], sh_s[c + 1]);
    float h2 = fmaf(f1.x, sc_s[c + 2], sh_s[c + 2]);
    float h3 = fmaf(f1.y, sc_s[c + 3], sh_s[c + 3]);
    *(float4*)(out + n * 192 + c) = make_float4(h0, h1, h2, h3);
    half4 hh;
    hh.a = __floats2half2_rn(h0, h1);
    hh.b = __floats2half2_rn(h2, h3);
    *(half4*)(h1h + e4) = hh;
}

// ---------------- CSR build: scan ----------------
__global__ __launch_bounds__(1024) void scan1_kernel(const int* __restrict__ counts,
                                                     int* __restrict__ offs, int* __restrict__ bsums) {
    __shared__ int tmp[2][1024];
    int t = threadIdx.x;
    int g = blockIdx.x * 1024 + t;
    int v = 0;
    if (g < NN) {
        #pragma unroll
        for (int r = 0; r < NREP; r++) v += counts[r * NN + g];
    }
    tmp[0][t] = v;
    __syncthreads();
    int pin = 0;
    for (int d = 1; d < 1024; d <<= 1) {
        int x = tmp[pin][t] + ((t >= d) ? tmp[pin][t - d] : 0);
        tmp[pin ^ 1][t] = x;
        pin ^= 1;
        __syncthreads();
    }
    int incl = tmp[pin][t];
    if (g < NN) offs[g] = incl - v;
    if (t == 1023) bsums[blockIdx.x] = incl;
}

__global__ __launch_bounds__(128) void scan2_kernel(int* __restrict__ bsums, int nb) {
    __shared__ int tmp[2][128];
    int t = threadIdx.x;
    int v = (t < nb) ? bsums[t] : 0;
    tmp[0][t] = v;
    __syncthreads();
    int pin = 0;
    for (int d = 1; d < 128; d <<= 1) {
        int x = tmp[pin][t] + ((t >= d) ? tmp[pin][t - d] : 0);
        tmp[pin ^ 1][t] = x;
        pin ^= 1;
        __syncthreads();
    }
    if (t < nb) bsums[t] = tmp[pin][t] - v;
}

// final offsets + per-node scatter cursors
__global__ __launch_bounds__(256) void scan3_kernel(int* __restrict__ offs, const int* __restrict__ bsums,
                                                    int* __restrict__ cursor) {
    int g = blockIdx.x * 256 + threadIdx.x;
    if (g < NN) {
        int o = offs[g] + bsums[g >> 10];
        offs[g] = o;
        cursor[g] = o;
    }
    if (g == 0) offs[NN] = NE;
}

// XCD-partitioned scatter (standalone 2048-block grid, 4 partitions -> 2 XCDs each)
__global__ __launch_bounds__(256) void scatter_kernel(const int* __restrict__ src, const int* __restrict__ dst,
                                                      const float* __restrict__ ea, int* __restrict__ cursor,
                                                      int2* __restrict__ src_ea) {
    const int p = blockIdx.x & (NPART - 1);
    const int blk = blockIdx.x >> 2;
    const int nblk = gridDim.x >> 2;
    const int lo = p * PART_SZ;
    const int hi = min(NN, lo + PART_SZ);
    for (int e = blk * 256 + threadIdx.x; e < NE; e += nblk * 256) {
        int d = dst[e];
        if (d >= lo && d < hi) {
            int pos = atomicAdd(&cursor[d], 1);
            src_ea[pos] = make_int2(src[e], __float_as_int(ea[e]));
        }
    }
}

// ---------------- fused layer 0: gather-agg (packed fp16, quarter-wave, 2-deep) + fp16-W GEMM + tanh + stats ----------------
__global__ __launch_bounds__(512, 8) void gine0_kernel(const float* __restrict__ X,
        const __half* __restrict__ Xh,
        const int* __restrict__ offs, const int2* __restrict__ src_ea,
        const double* __restrict__ dsum, const double* __restrict__ dsq,
        const float* __restrict__ g, const float* __restrict__ b,
        const float* __restrict__ We, const float* __restrict__ be,
        const float* __restrict__ W, const float* __restrict__ bvec,
        __half* __restrict__ t1h, double* __restrict__ dsum0, double* __restrict__ dsq0) {
    __shared__ __align__(16) float  u_s[32][INC + 4];    // 16.9 KB (reused for stats reduce)
    __shared__ __align__(16) __half w_sh[DIM][INC + 8];  // 17.4 KB, fp16 W
    __shared__ float sc_s[INC], sh_s[INC];
    const int t = threadIdx.x;
    const int row0 = blockIdx.x * 32;
    bn_fold_rep<INC>(t, dsum, dsq, g, b, sc_s, sh_s);
    for (int i = t; i < INC * DIM; i += 512) {
        int k = i >> 6, c = i & 63;
        w_sh[c][k] = __float2half_rn(W[i]);
    }
    __syncthreads();
    const int wid = t >> 6, l = t & 63;
    const int quarter = l >> 4;
    const int c8 = (l & 15) * 8;
    const __half2 z2 = __float2half2_rn(0.f);
    __half2 wvh0 = __floats2half2_rn(We[c8],     We[c8 + 1]);
    __half2 wvh1 = __floats2half2_rn(We[c8 + 2], We[c8 + 3]);
    __half2 wvh2 = __floats2half2_rn(We[c8 + 4], We[c8 + 5]);
    __half2 wvh3 = __floats2half2_rn(We[c8 + 6], We[c8 + 7]);
    __half2 bvh0 = __floats2half2_rn(be[c8],     be[c8 + 1]);
    __half2 bvh1 = __floats2half2_rn(be[c8 + 2], be[c8 + 3]);
    __half2 bvh2 = __floats2half2_rn(be[c8 + 4], be[c8 + 5]);
    __half2 bvh3 = __floats2half2_rn(be[c8 + 6], be[c8 + 7]);

    #define G0_ACC(vh, av2)  do { \
        ah0 = __hadd2(ah0, h2max(__hadd2((vh).a, __hfma2((av2), wvh0, bvh0)), z2)); \
        ah1 = __hadd2(ah1, h2max(__hadd2((vh).b, __hfma2((av2), wvh1, bvh1)), z2)); \
        ah2 = __hadd2(ah2, h2max(__hadd2((vh).c, __hfma2((av2), wvh2, bvh2)), z2)); \
        ah3 = __hadd2(ah3, h2max(__hadd2((vh).d, __hfma2((av2), wvh3, bvh3)), z2)); \
    } while (0)

    for (int nn = 0; nn < 4; ++nn) {
        int r = wid * 4 + nn;
        int n = row0 + r;
        __half2 ah0 = z2, ah1 = z2, ah2 = z2, ah3 = z2;
        if (n < NN) {
            int beg = offs[n], end = offs[n + 1];
            for (int base = beg; base < end; base += 64) {
                int j = base + l;
                int2 p = (j < end) ? src_ea[j] : make_int2(0, 0);
                float avf = __int_as_float(p.y);
                int cnt = min(64, end - base);
                int tt = 0;
                for (; tt + 8 <= cnt; tt += 8) {
                    int e0 = tt + quarter, e1 = tt + 4 + quarter;
                    int s0 = __shfl(p.x, e0), s1 = __shfl(p.x, e1);
                    float av0 = __shfl(avf, e0), av1 = __shfl(avf, e1);
                    half8 v0 = *(const half8*)(Xh + (size_t)s0 * INC + c8);
                    half8 v1 = *(const half8*)(Xh + (size_t)s1 * INC + c8);
                    __half2 a2_0 = __half2half2(__float2half_rn(av0));
                    __half2 a2_1 = __half2half2(__float2half_rn(av1));
                    G0_ACC(v0, a2_0); G0_ACC(v1, a2_1);
                }
                for (; tt < cnt; tt += 4) {
                    int e0 = tt + quarter;
                    int es = min(e0, cnt - 1);
                    int s0 = __shfl(p.x, es);
                    float av0 = __shfl(avf, es);
                    if (e0 < cnt) {
                        half8 v0 = *(const half8*)(Xh + (size_t)s0 * INC + c8);
                        __half2 a2_0 = __half2half2(__float2half_rn(av0));
                        G0_ACC(v0, a2_0);
                    }
                }
            }
        }
        float2 p0 = __half22float2(ah0), p1 = __half22float2(ah1);
        float2 p2 = __half22float2(ah2), p3 = __half22float2(ah3);
        float a0 = p0.x, a1 = p0.y, a2 = p1.x, a3 = p1.y;
        float a4 = p2.x, a5 = p2.y, a6 = p3.x, a7 = p3.y;
        a0 += __shfl_xor(a0, 16); a0 += __shfl_xor(a0, 32);
        a1 += __shfl_xor(a1, 16); a1 += __shfl_xor(a1, 32);
        a2 += __shfl_xor(a2, 16); a2 += __shfl_xor(a2, 32);
        a3 += __shfl_xor(a3, 16); a3 += __shfl_xor(a3, 32);
        a4 += __shfl_xor(a4, 16); a4 += __shfl_xor(a4, 32);
        a5 += __shfl_xor(a5, 16); a5 += __shfl_xor(a5, 32);
        a6 += __shfl_xor(a6, 16); a6 += __shfl_xor(a6, 32);
        a7 += __shfl_xor(a7, 16); a7 += __shfl_xor(a7, 32);
        if (quarter == 0) {
            if (n < NN) {
                float4 x0 = *(const float4*)(X + (size_t)n * INC + c8);
                float4 x1 = *(const float4*)(X + (size_t)n * INC + c8 + 4);
                a0 += fmaf(x0.x, sc_s[c8],     sh_s[c8]);
                a1 += fmaf(x0.y, sc_s[c8 + 1], sh_s[c8 + 1]);
                a2 += fmaf(x0.z, sc_s[c8 + 2], sh_s[c8 + 2]);
                a3 += fmaf(x0.w, sc_s[c8 + 3], sh_s[c8 + 3]);
                a4 += fmaf(x1.x, sc_s[c8 + 4], sh_s[c8 + 4]);
                a5 += fmaf(x1.y, sc_s[c8 + 5], sh_s[c8 + 5]);
                a6 += fmaf(x1.z, sc_s[c8 + 6], sh_s[c8 + 6]);
                a7 += fmaf(x1.w, sc_s[c8 + 7], sh_s[c8 + 7]);
            }
            *(float4*)&u_s[r][c8]     = make_float4(a0, a1, a2, a3);
            *(float4*)&u_s[r][c8 + 4] = make_float4(a4, a5, a6, a7);
        }
    }
    #undef G0_ACC
    __syncthreads();
    // GEMM (fp16 weights)
    const int cc = t & 15;
    const int rg = t >> 4;
    float acc0 = bvec[cc], acc1 = bvec[cc + 16], acc2 = bvec[cc + 32], acc3 = bvec[cc + 48];
    #pragma unroll 2
    for (int k = 0; k < INC; k += 8) {
        float4 ua = *(const float4*)&u_s[rg][k];
        float4 ub = *(const float4*)&u_s[rg][k + 4];
        half8 w0 = *(const half8*)&w_sh[cc][k];
        half8 w1 = *(const half8*)&w_sh[cc + 16][k];
        half8 w2 = *(const half8*)&w_sh[cc + 32][k];
        half8 w3 = *(const half8*)&w_sh[cc + 48][k];
        float2 p;
        p = __half22float2(w0.a); acc0 = fmaf(ua.x, p.x, fmaf(ua.y, p.y, acc0));
        p = __half22float2(w0.b); acc0 = fmaf(ua.z, p.x, fmaf(ua.w, p.y, acc0));
        p = __half22float2(w0.c); acc0 = fmaf(ub.x, p.x, fmaf(ub.y, p.y, acc0));
        p = __half22float2(w0.d); acc0 = fmaf(ub.z, p.x, fmaf(ub.w, p.y, acc0));
        p = __half22float2(w1.a); acc1 = fmaf(ua.x, p.x, fmaf(ua.y, p.y, acc1));
        p = __half22float2(w1.b); acc1 = fmaf(ua.z, p.x, fmaf(ua.w, p.y, acc1));
        p = __half22float2(w1.c); acc1 = fmaf(ub.x, p.x, fmaf(ub.y, p.y, acc1));
        p = __half22float2(w1.d); acc1 = fmaf(ub.z, p.x, fmaf(ub.w, p.y, acc1));
        p = __half22float2(w2.a); acc2 = fmaf(ua.x, p.x, fmaf(ua.y, p.y, acc2));
        p = __half22float2(w2.b); acc2 = fmaf(ua.z, p.x, fmaf(ua.w, p.y, acc2));
        p = __half22float2(w2.c); acc2 = fmaf(ub.x, p.x, fmaf(ub.y, p.y, acc2));
        p = __half22float2(w2.d); acc2 = fmaf(ub.z, p.x, fmaf(ub.w, p.y, acc2));
        p = __half22float2(w3.a); acc3 = fmaf(ua.x, p.x, fmaf(ua.y, p.y, acc3));
        p = __half22float2(w3.b); acc3 = fmaf(ua.z, p.x, fmaf(ua.w, p.y, acc3));
        p = __half22float2(w3.c); acc3 = fmaf(ub.x, p.x, fmaf(ub.y, p.y, acc3));
        p = __half22float2(w3.d); acc3 = fmaf(ub.z, p.x, fmaf(ub.w, p.y, acc3));
    }
    int rr = row0 + rg;
    float t0 = tanhf(acc0), t1v = tanhf(acc1), t2v = tanhf(acc2), t3v = tanhf(acc3);
    if (rr < NN) {
        __half* op = t1h + (size_t)rr * DIM;
        op[cc]      = __float2half_rn(t0);
        op[cc + 16] = __float2half_rn(t1v);
        op[cc + 32] = __float2half_rn(t2v);
        op[cc + 48] = __float2half_rn(t3v);
    }
    __syncthreads();
    float* red_s = (float*)u_s;
    float* red_q = red_s + 2048;
    bool ok = (rr < NN);
    red_s[rg * 64 + cc]      = ok ? t0 : 0.f;
    red_s[rg * 64 + cc + 16] = ok ? t1v : 0.f;
    red_s[rg * 64 + cc + 32] = ok ? t2v : 0.f;
    red_s[rg * 64 + cc + 48] = ok ? t3v : 0.f;
    red_q[rg * 64 + cc]      = ok ? t0 * t0 : 0.f;
    red_q[rg * 64 + cc + 16] = ok ? t1v * t1v : 0.f;
    red_q[rg * 64 + cc + 32] = ok ? t2v * t2v : 0.f;
    red_q[rg * 64 + cc + 48] = ok ? t3v * t3v : 0.f;
    __syncthreads();
    if (t < 64) {
        float s = 0.f, q = 0.f;
        #pragma unroll
        for (int i = 0; i < 32; i++) { s += red_s[i * 64 + t]; q += red_q[i * 64 + t]; }
        int rep = blockIdx.x & (NREP - 1);
        atomicAdd(&dsum0[rep * DIM + t], (double)s);
        atomicAdd(&dsq0[rep * DIM + t], (double)q);
    }
}

// ---------------- fused layer 1: gather-agg of fp16 h1 (packed fp16 math, 2-deep) + GEMM + tanh + stats ----------------
// 64 nodes per 512-thread block. reads h1h fp16 (already BN'd); t2 -> out[:,64:128]
__global__ __launch_bounds__(512) void gine1_kernel(const __half* __restrict__ h1h,
        const int* __restrict__ offs, const int2* __restrict__ src_ea,
        const float* __restrict__ We, const float* __restrict__ be,
        const float* __restrict__ W, const float* __restrict__ bvec,
        float* __restrict__ out, double* __restrict__ dsum1, double* __restrict__ dsq1) {
    __shared__ __align__(16) float u_s[64][DIM + 4];   // 17.4 KB
    __shared__ __align__(16) float w_s[DIM][DIM + 4];  // 17.4 KB (reused for stats reduce)
    const int t = threadIdx.x;
    const int row0 = blockIdx.x * 64;
    for (int i = t; i < DIM * DIM; i += 512) {
        int k = i >> 6, c = i & 63;
        w_s[c][k] = W[i];
    }
    __syncthreads();
    const int wid = t >> 6, l = t & 63;
    const int quarter = l >> 4;
    const int c4 = (l & 15) * 4;
    const __half2 z2 = __float2half2_rn(0.f);
    __half2 wvh0 = __floats2half2_rn(We[c4],     We[c4 + 1]);
    __half2 wvh1 = __floats2half2_rn(We[c4 + 2], We[c4 + 3]);
    __half2 bvh0 = __floats2half2_rn(be[c4],     be[c4 + 1]);
    __half2 bvh1 = __floats2half2_rn(be[c4 + 2], be[c4 + 3]);

    #define G1_ACC(vh, av2)  do { \
        ah0 = __hadd2(ah0, h2max(__hadd2((vh).a, __hfma2((av2), wvh0, bvh0)), z2)); \
        ah1 = __hadd2(ah1, h2max(__hadd2((vh).b, __hfma2((av2), wvh1, bvh1)), z2)); \
    } while (0)

    for (int nn = 0; nn < 8; ++nn) {
        int r = wid * 8 + nn;
        int n = row0 + r;
        __half2 ah0 = z2, ah1 = z2;
        if (n < NN) {
            int beg = offs[n], end = offs[n + 1];
            for (int base = beg; base < end; base += 64) {
                int j = base + l;
                int2 p = (j < end) ? src_ea[j] : make_int2(0, 0);
                float avf = __int_as_float(p.y);
                int cnt = min(64, end - base);
                int tt = 0;
                for (; tt + 8 <= cnt; tt += 8) {
                    int e0 = tt + quarter, e1 = tt + 4 + quarter;
                    int s0 = __shfl(p.x, e0), s1 = __shfl(p.x, e1);
                    float av0 = __shfl(avf, e0), av1 = __shfl(avf, e1);
                    half4 v0 = *(const half4*)(h1h + (size_t)s0 * DIM + c4);
                    half4 v1 = *(const half4*)(h1h + (size_t)s1 * DIM + c4);
                    __half2 a2_0 = __half2half2(__float2half_rn(av0));
                    __half2 a2_1 = __half2half2(__float2half_rn(av1));
                    G1_ACC(v0, a2_0); G1_ACC(v1, a2_1);
                }
                for (; tt < cnt; tt += 4) {
                    int e0 = tt + quarter;
                    int es = min(e0, cnt - 1);
                    int s0 = __shfl(p.x, es);
                    float av0 = __shfl(avf, es);
                    if (e0 < cnt) {
                        half4 v0 = *(const half4*)(h1h + (size_t)s0 * DIM + c4);
                        __half2 a2_0 = __half2half2(__float2half_rn(av0));
                        G1_ACC(v0, a2_0);
                    }
                }
            }
        }
        float2 p0 = __half22float2(ah0), p1 = __half22float2(ah1);
        float a0 = p0.x, a1 = p0.y, a2 = p1.x, a3 = p1.y;
        a0 += __shfl_xor(a0, 16); a0 += __shfl_xor(a0, 32);
        a1 += __shfl_xor(a1, 16); a1 += __shfl_xor(a1, 32);
        a2 += __shfl_xor(a2, 16); a2 += __shfl_xor(a2, 32);
        a3 += __shfl_xor(a3, 16); a3 += __shfl_xor(a3, 32);
        if (quarter == 0) {
            if (n < NN) {
                // self term h1 (fp16 table, tiny δ)
                half4 h = *(const half4*)(h1h + (size_t)n * DIM + c4);
                float2 f0 = __half22float2(h.a), f1 = __half22float2(h.b);
                a0 += f0.x; a1 += f0.y; a2 += f1.x; a3 += f1.y;
            }
            *(float4*)&u_s[r][c4] = make_float4(a0, a1, a2, a3);
        }
    }
    #undef G1_ACC
    __syncthreads();
    // GEMM: 64x64 outputs, 512 threads -> 8 outputs each (2 rows x 4 cols)
    const int cc = t & 15;
    const int r0 = (t >> 4) * 2;
    float acc[2][4];
    #pragma unroll
    for (int j = 0; j < 4; j++) {
        float bj = bvec[cc + 16 * j];
        acc[0][j] = bj; acc[1][j] = bj;
    }
    #pragma unroll 4
    for (int k = 0; k < DIM; k += 4) {
        float4 w0 = *(const float4*)&w_s[cc][k];
        float4 w1 = *(const float4*)&w_s[cc + 16][k];
        float4 w2 = *(const float4*)&w_s[cc + 32][k];
        float4 w3 = *(const float4*)&w_s[cc + 48][k];
        #pragma unroll
        for (int i = 0; i < 2; i++) {
            float4 u = *(const float4*)&u_s[r0 + i][k];
            acc[i][0] = fmaf(u.x, w0.x, fmaf(u.y, w0.y, fmaf(u.z, w0.z, fmaf(u.w, w0.w, acc[i][0]))));
            acc[i][1] = fmaf(u.x, w1.x, fmaf(u.y, w1.y, fmaf(u.z, w1.z, fmaf(u.w, w1.w, acc[i][1]))));
            acc[i][2] = fmaf(u.x, w2.x, fmaf(u.y, w2.y, fmaf(u.z, w2.z, fmaf(u.w, w2.w, acc[i][2]))));
            acc[i][3] = fmaf(u.x, w3.x, fmaf(u.y, w3.y, fmaf(u.z, w3.z, fmaf(u.w, w3.w, acc[i][3]))));
        }
    }
    float tv[2][4];
    #pragma unroll
    for (int i = 0; i < 2; i++) {
        int rr = row0 + r0 + i;
        #pragma unroll
        for (int j = 0; j < 4; j++) tv[i][j] = tanhf(acc[i][j]);
        if (rr < NN) {
            float* op = out + (size_t)rr * 192 + 64;
            #pragma unroll
            for (int j = 0; j < 4; j++) op[cc + 16 * j] = tv[i][j];
        }
    }
    // fused per-channel stats of t2 (reuse w_s)
    __syncthreads();
    float* red_s = (float*)w_s;
    float* red_q = red_s + 2048;
    const int rgp = t >> 4;
    bool ok0 = (row0 + r0 < NN), ok1 = (row0 + r0 + 1 < NN);
    #pragma unroll
    for (int j = 0; j < 4; j++) {
        float v0 = ok0 ? tv[0][j] : 0.f;
        float v1 = ok1 ? tv[1][j] : 0.f;
        red_s[rgp * 64 + cc + 16 * j] = v0 + v1;
        red_q[rgp * 64 + cc + 16 * j] = v0 * v0 + v1 * v1;
    }
    __syncthreads();
    if (t < 64) {
        float s = 0.f, q = 0.f;
        #pragma unroll
        for (int i = 0; i < 32; i++) { s += red_s[i * 64 + t]; q += red_q[i * 64 + t]; }
        int rep = blockIdx.x & (NREP - 1);
        atomicAdd(&dsum1[rep * DIM + t], (double)s);
        atomicAdd(&dsq1[rep * DIM + t], (double)q);
    }
}

// ---------------- fused: finalize1 + h2 = BN(t2) in place + h3 = tanh(h2 @ Wfc) ----------------
__global__ __launch_bounds__(256) void fc_kernel(float* __restrict__ io,
        const double* __restrict__ dsum, const double* __restrict__ dsq,
        const float* __restrict__ g, const float* __restrict__ b,
        const float* __restrict__ W) {
    __shared__ __align__(16) float u_s[64][DIM + 4];
    __shared__ __align__(16) float w_s[DIM][DIM + 4];
    __shared__ float sc_s[DIM], sh_s[DIM];
    const int t = threadIdx.x;
    const int row0 = blockIdx.x * 64;
    bn_fold_rep<DIM>(t, dsum, dsq, g, b, sc_s, sh_s);
    __syncthreads();
    for (int i = t; i < DIM * DIM; i += 256) {
        int k = i >> 6, c = i & 63;
        w_s[c][k] = W[i];
    }
    for (int i = t; i < 64 * DIM; i += 256) {
        int r = i >> 6, k = i & 63;
        int rr = row0 + r;
        float v = 0.f;
        if (rr < NN) {
            size_t idx = (size_t)rr * 192 + 64 + k;
            v = fmaf(io[idx], sc_s[k], sh_s[k]);
            io[idx] = v;                       // h2
        }
        u_s[r][k] = v;
    }
    __syncthreads();
    const int cc = t & 15;
    const int r0 = (t >> 4) << 2;
    float acc[4][4];
    #pragma unroll
    for (int j = 0; j < 4; j++) { acc[0][j] = 0.f; acc[1][j] = 0.f; acc[2][j] = 0.f; acc[3][j] = 0.f; }
    #pragma unroll 4
    for (int k = 0; k < DIM; k += 4) {
        float4 w0 = *(const float4*)&w_s[cc][k];
        float4 w1 = *(const float4*)&w_s[cc + 16][k];
        float4 w2 = *(const float4*)&w_s[cc + 32][k];
        float4 w3 = *(const float4*)&w_s[cc + 48][k];
        #pragma unroll
        for (int i = 0; i < 4; i++) {
            float4 u = *(const float4*)&u_s[r0 + i][k];
            acc[i][0] = fmaf(u.x, w0.x, fmaf(u.y, w0.y, fmaf(u.z, w0.z, fmaf(u.w, w0.w, acc[i][0]))));
            acc[i][1] = fmaf(u.x, w1.x, fmaf(u.y, w1.y, fmaf(u.z, w1.z, fmaf(u.w, w1.w, acc[i][1]))));
            acc[i][2] = fmaf(u.x, w2.x, fmaf(u.y, w2.y, fmaf(u.z, w2.z, fmaf(u.w, w2.w, acc[i][2]))));
            acc[i][3] = fmaf(u.x, w3.x, fmaf(u.y, w3.y, fmaf(u.z, w3.z, fmaf(u.w, w3.w, acc[i][3]))));
        }
    }
    #pragma unroll
    for (int i = 0; i < 4; i++) {
        int rr = row0 + r0 + i;
        if (rr < NN) {
            #pragma unroll
            for (int j = 0; j < 4; j++)
                io[(size_t)rr * 192 + 128 + cc + 16 * j] = tanhf(acc[i][j]);
        }
    }
}

extern "C" void kernel_launch(void* const* d_in, const int* in_sizes, int n_in,
                              void* d_out, int out_size, void* d_ws, size_t ws_size,
                              hipStream_t stream) {
    const float* X      = (const float*)d_in[0];
    const int*   ei     = (const int*)  d_in[1];
    const float* ea     = (const float*)d_in[2];
    const float* bng    = (const float*)d_in[3];
    const float* bnb    = (const float*)d_in[4];
    const float* We0    = (const float*)d_in[5];
    const float* be0    = (const float*)d_in[6];
    const float* W0     = (const float*)d_in[7];
    const float* b0     = (const float*)d_in[8];
    const float* bn0g   = (const float*)d_in[9];
    const float* bn0b   = (const float*)d_in[10];
    const float* We1    = (const float*)d_in[11];
    const float* be1    = (const float*)d_in[12];
    const float* W1     = (const float*)d_in[13];
    const float* b1     = (const float*)d_in[14];
    const float* bn1g   = (const float*)d_in[15];
    const float* bn1b   = (const float*)d_in[16];
    const float* Wfc    = (const float*)d_in[17];

    const int* src = ei;
    const int* dst = ei + NE;
    float* out = (float*)d_out;

    // ---- workspace layout (~56 MB); h1h aliases Xh (Xh dead after gine0) ----
    int2*   src_ea  = (int2*)d_ws;                        // NE
    __half* t1h     = (__half*)(src_ea + NE);             // NN*DIM halves
    __half* Xh      = t1h + (size_t)NN * DIM;             // NN*INC halves
    __half* h1h     = Xh;                                 // aliases Xh (NN*DIM <= NN*INC)
    int*    counts  = (int*)(Xh + (size_t)NN * INC);      // NREP*NN
    int*    offs    = counts + (size_t)NREP * NN;         // NN+1
    int*    cursor  = offs + NN + 1;                      // NN
    int*    bsums   = cursor + NN;                        // 128
    double* dstats = (double*)(((uintptr_t)(bsums + 128) + 15) & ~(uintptr_t)15);
    double* dsum_in = dstats;                          // NREP*128
    double* dsq_in  = dsum_in + NREP * INC;            // NREP*128
    double* dsum0   = dsq_in + NREP * INC;             // NREP*64
    double* dsq0    = dsum0 + NREP * DIM;              // NREP*64
    double* dsum1   = dsq0 + NREP * DIM;               // NREP*64
    double* dsq1    = dsum1 + NREP * DIM;              // NREP*64
    const size_t nstats = (size_t)NREP * (2 * INC + 4 * DIM);

    hipMemsetAsync(counts, 0, (size_t)NREP * NN * sizeof(int), stream);
    hipMemsetAsync(dstats, 0, nstats * sizeof(double), stream);

    // fused input-BN stats + replicated dst histogram
    stats_hist_kernel<<<SB + (NE + 255) / 256, 256, 0, stream>>>(X, dst, counts, dsum_in, dsq_in);

    // x̂ -> fp16 (depends only on stats)
    xhat_half_kernel<<<(NN * INC / 4 + 255) / 256, 256, 0, stream>>>(X, dsum_in, dsq_in, bng, bnb, Xh);

    // CSR build (shared by both layers)
    const int NB = (NN + 1023) / 1024;   // 98
    scan1_kernel<<<NB, 1024, 0, stream>>>(counts, offs, bsums);
    scan2_kernel<<<1, 128, 0, stream>>>(bsums, NB);
    scan3_kernel<<<(NN + 255) / 256, 256, 0, stream>>>(offs, bsums, cursor);
    // XCD-partitioned scatter (4 partitions)
    scatter_kernel<<<2048, 256, 0, stream>>>(src, dst, ea, cursor, src_ea);

    // layer 0 (fused agg + fp16-W GEMM + stats0), packed-fp16 gather math
    gine0_kernel<<<(NN + 31) / 32, 512, 0, stream>>>(X, Xh, offs, src_ea, dsum_in, dsq_in, bng, bnb,
                                                     We0, be0, W0, b0, t1h, dsum0, dsq0);

    // h1 = BN0(t1): f32 -> out[:,0:64], fp16 -> h1h (overwrites Xh, now dead)
    h1_kernel<<<(NN * DIM / 4 + 255) / 256, 256, 0, stream>>>(t1h, dsum0, dsq0, bn0g, bn0b, out, h1h);

    // layer 1 (fused agg of fp16 h1 + GEMM + stats1), packed-fp16 gather math
    gine1_kernel<<<(NN + 63) / 64, 512, 0, stream>>>(h1h, offs, src_ea, We1, be1, W1, b1,
                                                     out, dsum1, dsq1);

    // h2 (in place) + h3 (fused finalize1)
    fc_kernel<<<(NN + 63) / 64, 256, 0, stream>>>(out, dsum1, dsq1, bn1g, bn1b, Wfc);
}

// Round 17
// 406.675 us; speedup vs baseline: 1.2012x; 1.0299x over previous
//
#include <hip/hip_runtime.h>
#include <hip/hip_fp16.h>
#include <math.h>
#include <stdint.h>

#define NN 100000
#define NE 1600000
#define INC 128
#define DIM 64
#define EPS 1e-5f
#define SB 512    // stats blocks inside fused stats+hist kernel
#define NREP 8    // replicas for stats accumulators AND histogram counters
#define NPART 4   // scatter partitions (write set 12.8MB/4 = 3.2MB < 4MB L2)
#define PART_SZ ((NN + NPART - 1) / NPART)
#define XB1024 (NN * INC / 4 / 1024)   // 3125 xhat blocks (1024 thr, float4 each)
#define NB ((NN + 1023) / 1024)        // 98 scan chunks

struct __align__(8)  half4 { __half2 a, b; };
struct __align__(16) half8 { __half2 a, b, c, d; };

// packed fp16 max (ROCm header lacks __hmax2; emit v_pk_max_f16 directly)
__device__ inline __half2 h2max(__half2 a, __half2 b) {
    __half2 r;
    asm("v_pk_max_f16 %0, %1, %2" : "=v"(r) : "v"(a), "v"(b));
    return r;
}

// fused: blocks [0,SB) do X stats (C=128) in f64; blocks [SB,...) do replicated dst histogram
__global__ __launch_bounds__(256) void stats_hist_kernel(const float* __restrict__ X,
        const int* __restrict__ dst, int* __restrict__ counts,
        double* __restrict__ sum_out, double* __restrict__ sq_out) {
    __shared__ double ls[256], lq[256];
    if (blockIdx.x < SB) {
        int c  = threadIdx.x & 127;
        int rl = threadIdx.x >> 7;           // 2 rows per block step
        int row = blockIdx.x * 2 + rl;
        const int rstride = SB * 2;
        double s = 0.0, q = 0.0;
        for (int r = row; r < NN; r += rstride) {
            double v = (double)X[(size_t)r * INC + c];
            s += v; q += v * v;
        }
        ls[threadIdx.x] = s; lq[threadIdx.x] = q;
        __syncthreads();
        if (rl == 0) {
            s += ls[128 + c]; q += lq[128 + c];
            int rep = blockIdx.x & (NREP - 1);
            atomicAdd(&sum_out[rep * INC + c], s);
            atomicAdd(&sq_out[rep * INC + c], q);
        }
    } else {
        int bb = blockIdx.x - SB;
        int e = bb * 256 + threadIdx.x;
        if (e < NE) atomicAdd(&counts[(bb & (NREP - 1)) * NN + dst[e]], 1);
    }
}

// BN scale/shift from NREP-replicated f64 stats
template<int C>
__device__ inline void bn_fold_rep(int t, const double* dsum, const double* dsq,
                                   const float* g, const float* b, float* sc_s, float* sh_s) {
    if (t < C) {
        double s = 0.0, q = 0.0;
        #pragma unroll
        for (int r = 0; r < NREP; r++) { s += dsum[r * C + t]; q += dsq[r * C + t]; }
        double m = s / (double)NN;
        double v = q / (double)NN - m * m;
        double sc = (double)g[t] / sqrt(v + (double)EPS);
        sc_s[t] = (float)sc;
        sh_s[t] = (float)((double)b[t] - m * sc);
    }
}

// fused: blocks [0,XB1024) do x̂->fp16 (1024 thr, float4 each); blocks [XB1024,...) do scan1.
// Both depend only on stats_hist (+ memset), already complete at launch.
__global__ __launch_bounds__(1024) void xhat_scan1_kernel(const float* __restrict__ X,
        const double* __restrict__ dsum, const double* __restrict__ dsq,
        const float* __restrict__ g, const float* __restrict__ b,
        __half* __restrict__ Xh,
        const int* __restrict__ counts, int* __restrict__ offs, int* __restrict__ bsums) {
    if (blockIdx.x < XB1024) {
        __shared__ float sc_s[INC], sh_s[INC];
        bn_fold_rep<INC>(threadIdx.x, dsum, dsq, g, b, sc_s, sh_s);
        __syncthreads();
        size_t i = (size_t)blockIdx.x * 1024 + threadIdx.x;
        size_t e4 = i * 4;
        if (e4 >= (size_t)NN * INC) return;
        int c = (int)(e4 & 127);
        float4 x = *(const float4*)(X + e4);
        half4 h;
        h.a = __floats2half2_rn(fmaf(x.x, sc_s[c], sh_s[c]), fmaf(x.y, sc_s[c + 1], sh_s[c + 1]));
        h.b = __floats2half2_rn(fmaf(x.z, sc_s[c + 2], sh_s[c + 2]), fmaf(x.w, sc_s[c + 3], sh_s[c + 3]));
        *(half4*)(Xh + e4) = h;
    } else {
        __shared__ int tmp[2][1024];
        int t = threadIdx.x;
        int g1 = (blockIdx.x - XB1024) * 1024 + t;
        int v = 0;
        if (g1 < NN) {
            #pragma unroll
            for (int r = 0; r < NREP; r++) v += counts[r * NN + g1];
        }
        tmp[0][t] = v;
        __syncthreads();
        int pin = 0;
        for (int d = 1; d < 1024; d <<= 1) {
            int x = tmp[pin][t] + ((t >= d) ? tmp[pin][t - d] : 0);
            tmp[pin ^ 1][t] = x;
            pin ^= 1;
            __syncthreads();
        }
        int incl = tmp[pin][t];
        if (g1 < NN) offs[g1] = incl - v;
        if (t == 1023) bsums[blockIdx.x - XB1024] = incl;
    }
}

// scan2 folded in: each block redundantly scans raw bsums (98 entries) in LDS,
// then writes final offsets + cursors.
__global__ __launch_bounds__(256) void scan23_kernel(int* __restrict__ offs, const int* __restrict__ bsums,
                                                     int* __restrict__ cursor) {
    __shared__ int tmp[2][128];
    int t = threadIdx.x;
    if (t < 128) {
        int v = (t < NB) ? bsums[t] : 0;
        tmp[0][t] = v;
    }
    __syncthreads();
    int pin = 0;
    if (t < 128) {
        for (int d = 1; d < 128; d <<= 1) {
            int x = tmp[pin][t] + ((t >= d) ? tmp[pin][t - d] : 0);
            tmp[pin ^ 1][t] = x;
            pin ^= 1;
            __syncthreads();
        }
    } else {
        for (int d = 1; d < 128; d <<= 1) { pin ^= 1; __syncthreads(); }
    }
    __shared__ int excl[128];
    if (t < 128) excl[t] = tmp[pin][t] - ((t < NB) ? bsums[t] : 0);
    __syncthreads();
    int g = blockIdx.x * 256 + t;
    if (g < NN) {
        int o = offs[g] + excl[g >> 10];
        offs[g] = o;
        cursor[g] = o;
    }
    if (g == 0) offs[NN] = NE;
}

// XCD-partitioned scatter (standalone 2048-block grid, 4 partitions -> 2 XCDs each)
__global__ __launch_bounds__(256) void scatter_kernel(const int* __restrict__ src, const int* __restrict__ dst,
                                                      const float* __restrict__ ea, int* __restrict__ cursor,
                                                      int2* __restrict__ src_ea) {
    const int p = blockIdx.x & (NPART - 1);
    const int blk = blockIdx.x >> 2;
    const int nblk = gridDim.x >> 2;
    const int lo = p * PART_SZ;
    const int hi = min(NN, lo + PART_SZ);
    for (int e = blk * 256 + threadIdx.x; e < NE; e += nblk * 256) {
        int d = dst[e];
        if (d >= lo && d < hi) {
            int pos = atomicAdd(&cursor[d], 1);
            src_ea[pos] = make_int2(src[e], __float_as_int(ea[e]));
        }
    }
}

// h1 = BN0(t1): writes f32 to out[:,0:64] AND fp16 to h1h (gather table for gine1)
__global__ __launch_bounds__(256) void h1_kernel(const __half* __restrict__ t1h,
        const double* __restrict__ dsum, const double* __restrict__ dsq,
        const float* __restrict__ g, const float* __restrict__ b,
        float* __restrict__ out, __half* __restrict__ h1h) {
    __shared__ float sc_s[DIM], sh_s[DIM];
    bn_fold_rep<DIM>(threadIdx.x, dsum, dsq, g, b, sc_s, sh_s);
    __syncthreads();
    size_t i = (size_t)blockIdx.x * 256 + threadIdx.x;   // 4 channels per thread
    size_t e4 = i * 4;
    if (e4 >= (size_t)NN * DIM) return;
    int c = (int)(e4 & 63);
    size_t n = e4 >> 6;
    half4 tv = *(const half4*)(t1h + e4);
    float2 f0 = __half22float2(tv.a), f1 = __half22float2(tv.b);
    float h0 = fmaf(f0.x, sc_s[c],     sh_s[c]);
    float h1 = fmaf(f0.y, sc_s[c + 1], sh_s[c + 1]);
    float h2 = fmaf(f1.x, sc_s[c + 2], sh_s[c + 2]);
    float h3 = fmaf(f1.y, sc_s[c + 3], sh_s[c + 3]);
    *(float4*)(out + n * 192 + c) = make_float4(h0, h1, h2, h3);
    half4 hh;
    hh.a = __floats2half2_rn(h0, h1);
    hh.b = __floats2half2_rn(h2, h3);
    *(half4*)(h1h + e4) = hh;
}

// ---------------- fused layer 0: gather-agg (packed fp16, quarter-wave, 2-deep) + fp16-W GEMM + tanh + stats ----------------
__global__ __launch_bounds__(512, 8) void gine0_kernel(const float* __restrict__ X,
        const __half* __restrict__ Xh,
        const int* __restrict__ offs, const int2* __restrict__ src_ea,
        const double* __restrict__ dsum, const double* __restrict__ dsq,
        const float* __restrict__ g, const float* __restrict__ b,
        const float* __restrict__ We, const float* __restrict__ be,
        const float* __restrict__ W, const float* __restrict__ bvec,
        __half* __restrict__ t1h, double* __restrict__ dsum0, double* __restrict__ dsq0) {
    __shared__ __align__(16) float  u_s[32][INC + 4];    // 16.9 KB (reused for stats reduce)
    __shared__ __align__(16) __half w_sh[DIM][INC + 8];  // 17.4 KB, fp16 W
    __shared__ float sc_s[INC], sh_s[INC];
    const int t = threadIdx.x;
    const int row0 = blockIdx.x * 32;
    bn_fold_rep<INC>(t, dsum, dsq, g, b, sc_s, sh_s);
    for (int i = t; i < INC * DIM; i += 512) {
        int k = i >> 6, c = i & 63;
        w_sh[c][k] = __float2half_rn(W[i]);
    }
    __syncthreads();
    const int wid = t >> 6, l = t & 63;
    const int quarter = l >> 4;
    const int c8 = (l & 15) * 8;
    const __half2 z2 = __float2half2_rn(0.f);
    __half2 wvh0 = __floats2half2_rn(We[c8],     We[c8 + 1]);
    __half2 wvh1 = __floats2half2_rn(We[c8 + 2], We[c8 + 3]);
    __half2 wvh2 = __floats2half2_rn(We[c8 + 4], We[c8 + 5]);
    __half2 wvh3 = __floats2half2_rn(We[c8 + 6], We[c8 + 7]);
    __half2 bvh0 = __floats2half2_rn(be[c8],     be[c8 + 1]);
    __half2 bvh1 = __floats2half2_rn(be[c8 + 2], be[c8 + 3]);
    __half2 bvh2 = __floats2half2_rn(be[c8 + 4], be[c8 + 5]);
    __half2 bvh3 = __floats2half2_rn(be[c8 + 6], be[c8 + 7]);

    #define G0_ACC(vh, av2)  do { \
        ah0 = __hadd2(ah0, h2max(__hadd2((vh).a, __hfma2((av2), wvh0, bvh0)), z2)); \
        ah1 = __hadd2(ah1, h2max(__hadd2((vh).b, __hfma2((av2), wvh1, bvh1)), z2)); \
        ah2 = __hadd2(ah2, h2max(__hadd2((vh).c, __hfma2((av2), wvh2, bvh2)), z2)); \
        ah3 = __hadd2(ah3, h2max(__hadd2((vh).d, __hfma2((av2), wvh3, bvh3)), z2)); \
    } while (0)

    for (int nn = 0; nn < 4; ++nn) {
        int r = wid * 4 + nn;
        int n = row0 + r;
        __half2 ah0 = z2, ah1 = z2, ah2 = z2, ah3 = z2;
        if (n < NN) {
            int beg = offs[n], end = offs[n + 1];
            for (int base = beg; base < end; base += 64) {
                int j = base + l;
                int2 p = (j < end) ? src_ea[j] : make_int2(0, 0);
                float avf = __int_as_float(p.y);
                int cnt = min(64, end - base);
                int tt = 0;
                for (; tt + 8 <= cnt; tt += 8) {
                    int e0 = tt + quarter, e1 = tt + 4 + quarter;
                    int s0 = __shfl(p.x, e0), s1 = __shfl(p.x, e1);
                    float av0 = __shfl(avf, e0), av1 = __shfl(avf, e1);
                    half8 v0 = *(const half8*)(Xh + (size_t)s0 * INC + c8);
                    half8 v1 = *(const half8*)(Xh + (size_t)s1 * INC + c8);
                    __half2 a2_0 = __half2half2(__float2half_rn(av0));
                    __half2 a2_1 = __half2half2(__float2half_rn(av1));
                    G0_ACC(v0, a2_0); G0_ACC(v1, a2_1);
                }
                for (; tt < cnt; tt += 4) {
                    int e0 = tt + quarter;
                    int es = min(e0, cnt - 1);
                    int s0 = __shfl(p.x, es);
                    float av0 = __shfl(avf, es);
                    if (e0 < cnt) {
                        half8 v0 = *(const half8*)(Xh + (size_t)s0 * INC + c8);
                        __half2 a2_0 = __half2half2(__float2half_rn(av0));
                        G0_ACC(v0, a2_0);
                    }
                }
            }
        }
        float2 p0 = __half22float2(ah0), p1 = __half22float2(ah1);
        float2 p2 = __half22float2(ah2), p3 = __half22float2(ah3);
        float a0 = p0.x, a1 = p0.y, a2 = p1.x, a3 = p1.y;
        float a4 = p2.x, a5 = p2.y, a6 = p3.x, a7 = p3.y;
        a0 += __shfl_xor(a0, 16); a0 += __shfl_xor(a0, 32);
        a1 += __shfl_xor(a1, 16); a1 += __shfl_xor(a1, 32);
        a2 += __shfl_xor(a2, 16); a2 += __shfl_xor(a2, 32);
        a3 += __shfl_xor(a3, 16); a3 += __shfl_xor(a3, 32);
        a4 += __shfl_xor(a4, 16); a4 += __shfl_xor(a4, 32);
        a5 += __shfl_xor(a5, 16); a5 += __shfl_xor(a5, 32);
        a6 += __shfl_xor(a6, 16); a6 += __shfl_xor(a6, 32);
        a7 += __shfl_xor(a7, 16); a7 += __shfl_xor(a7, 32);
        if (quarter == 0) {
            if (n < NN) {
                float4 x0 = *(const float4*)(X + (size_t)n * INC + c8);
                float4 x1 = *(const float4*)(X + (size_t)n * INC + c8 + 4);
                a0 += fmaf(x0.x, sc_s[c8],     sh_s[c8]);
                a1 += fmaf(x0.y, sc_s[c8 + 1], sh_s[c8 + 1]);
                a2 += fmaf(x0.z, sc_s[c8 + 2], sh_s[c8 + 2]);
                a3 += fmaf(x0.w, sc_s[c8 + 3], sh_s[c8 + 3]);
                a4 += fmaf(x1.x, sc_s[c8 + 4], sh_s[c8 + 4]);
                a5 += fmaf(x1.y, sc_s[c8 + 5], sh_s[c8 + 5]);
                a6 += fmaf(x1.z, sc_s[c8 + 6], sh_s[c8 + 6]);
                a7 += fmaf(x1.w, sc_s[c8 + 7], sh_s[c8 + 7]);
            }
            *(float4*)&u_s[r][c8]     = make_float4(a0, a1, a2, a3);
            *(float4*)&u_s[r][c8 + 4] = make_float4(a4, a5, a6, a7);
        }
    }
    #undef G0_ACC
    __syncthreads();
    // GEMM (fp16 weights)
    const int cc = t & 15;
    const int rg = t >> 4;
    float acc0 = bvec[cc], acc1 = bvec[cc + 16], acc2 = bvec[cc + 32], acc3 = bvec[cc + 48];
    #pragma unroll 2
    for (int k = 0; k < INC; k += 8) {
        float4 ua = *(const float4*)&u_s[rg][k];
        float4 ub = *(const float4*)&u_s[rg][k + 4];
        half8 w0 = *(const half8*)&w_sh[cc][k];
        half8 w1 = *(const half8*)&w_sh[cc + 16][k];
        half8 w2 = *(const half8*)&w_sh[cc + 32][k];
        half8 w3 = *(const half8*)&w_sh[cc + 48][k];
        float2 p;
        p = __half22float2(w0.a); acc0 = fmaf(ua.x, p.x, fmaf(ua.y, p.y, acc0));
        p = __half22float2(w0.b); acc0 = fmaf(ua.z, p.x, fmaf(ua.w, p.y, acc0));
        p = __half22float2(w0.c); acc0 = fmaf(ub.x, p.x, fmaf(ub.y, p.y, acc0));
        p = __half22float2(w0.d); acc0 = fmaf(ub.z, p.x, fmaf(ub.w, p.y, acc0));
        p = __half22float2(w1.a); acc1 = fmaf(ua.x, p.x, fmaf(ua.y, p.y, acc1));
        p = __half22float2(w1.b); acc1 = fmaf(ua.z, p.x, fmaf(ua.w, p.y, acc1));
        p = __half22float2(w1.c); acc1 = fmaf(ub.x, p.x, fmaf(ub.y, p.y, acc1));
        p = __half22float2(w1.d); acc1 = fmaf(ub.z, p.x, fmaf(ub.w, p.y, acc1));
        p = __half22float2(w2.a); acc2 = fmaf(ua.x, p.x, fmaf(ua.y, p.y, acc2));
        p = __half22float2(w2.b); acc2 = fmaf(ua.z, p.x, fmaf(ua.w, p.y, acc2));
        p = __half22float2(w2.c); acc2 = fmaf(ub.x, p.x, fmaf(ub.y, p.y, acc2));
        p = __half22float2(w2.d); acc2 = fmaf(ub.z, p.x, fmaf(ub.w, p.y, acc2));
        p = __half22float2(w3.a); acc3 = fmaf(ua.x, p.x, fmaf(ua.y, p.y, acc3));
        p = __half22float2(w3.b); acc3 = fmaf(ua.z, p.x, fmaf(ua.w, p.y, acc3));
        p = __half22float2(w3.c); acc3 = fmaf(ub.x, p.x, fmaf(ub.y, p.y, acc3));
        p = __half22float2(w3.d); acc3 = fmaf(ub.z, p.x, fmaf(ub.w, p.y, acc3));
    }
    int rr = row0 + rg;
    float t0 = tanhf(acc0), t1v = tanhf(acc1), t2v = tanhf(acc2), t3v = tanhf(acc3);
    if (rr < NN) {
        __half* op = t1h + (size_t)rr * DIM;
        op[cc]      = __float2half_rn(t0);
        op[cc + 16] = __float2half_rn(t1v);
        op[cc + 32] = __float2half_rn(t2v);
        op[cc + 48] = __float2half_rn(t3v);
    }
    __syncthreads();
    float* red_s = (float*)u_s;
    float* red_q = red_s + 2048;
    bool ok = (rr < NN);
    red_s[rg * 64 + cc]      = ok ? t0 : 0.f;
    red_s[rg * 64 + cc + 16] = ok ? t1v : 0.f;
    red_s[rg * 64 + cc + 32] = ok ? t2v : 0.f;
    red_s[rg * 64 + cc + 48] = ok ? t3v : 0.f;
    red_q[rg * 64 + cc]      = ok ? t0 * t0 : 0.f;
    red_q[rg * 64 + cc + 16] = ok ? t1v * t1v : 0.f;
    red_q[rg * 64 + cc + 32] = ok ? t2v * t2v : 0.f;
    red_q[rg * 64 + cc + 48] = ok ? t3v * t3v : 0.f;
    __syncthreads();
    if (t < 64) {
        float s = 0.f, q = 0.f;
        #pragma unroll
        for (int i = 0; i < 32; i++) { s += red_s[i * 64 + t]; q += red_q[i * 64 + t]; }
        int rep = blockIdx.x & (NREP - 1);
        atomicAdd(&dsum0[rep * DIM + t], (double)s);
        atomicAdd(&dsq0[rep * DIM + t], (double)q);
    }
}

// ---------------- fused layer 1: gather-agg of fp16 h1 (packed fp16, 2-deep) + GEMM + tanh + stats ----------------
__global__ __launch_bounds__(512) void gine1_kernel(const __half* __restrict__ h1h,
        const int* __restrict__ offs, const int2* __restrict__ src_ea,
        const float* __restrict__ We, const float* __restrict__ be,
        const float* __restrict__ W, const float* __restrict__ bvec,
        float* __restrict__ out, double* __restrict__ dsum1, double* __restrict__ dsq1) {
    __shared__ __align__(16) float u_s[64][DIM + 4];   // 17.4 KB
    __shared__ __align__(16) float w_s[DIM][DIM + 4];  // 17.4 KB (reused for stats reduce)
    const int t = threadIdx.x;
    const int row0 = blockIdx.x * 64;
    for (int i = t; i < DIM * DIM; i += 512) {
        int k = i >> 6, c = i & 63;
        w_s[c][k] = W[i];
    }
    __syncthreads();
    const int wid = t >> 6, l = t & 63;
    const int quarter = l >> 4;
    const int c4 = (l & 15) * 4;
    const __half2 z2 = __float2half2_rn(0.f);
    __half2 wvh0 = __floats2half2_rn(We[c4],     We[c4 + 1]);
    __half2 wvh1 = __floats2half2_rn(We[c4 + 2], We[c4 + 3]);
    __half2 bvh0 = __floats2half2_rn(be[c4],     be[c4 + 1]);
    __half2 bvh1 = __floats2half2_rn(be[c4 + 2], be[c4 + 3]);

    #define G1_ACC(vh, av2)  do { \
        ah0 = __hadd2(ah0, h2max(__hadd2((vh).a, __hfma2((av2), wvh0, bvh0)), z2)); \
        ah1 = __hadd2(ah1, h2max(__hadd2((vh).b, __hfma2((av2), wvh1, bvh1)), z2)); \
    } while (0)

    for (int nn = 0; nn < 8; ++nn) {
        int r = wid * 8 + nn;
        int n = row0 + r;
        __half2 ah0 = z2, ah1 = z2;
        if (n < NN) {
            int beg = offs[n], end = offs[n + 1];
            for (int base = beg; base < end; base += 64) {
                int j = base + l;
                int2 p = (j < end) ? src_ea[j] : make_int2(0, 0);
                float avf = __int_as_float(p.y);
                int cnt = min(64, end - base);
                int tt = 0;
                for (; tt + 8 <= cnt; tt += 8) {
                    int e0 = tt + quarter, e1 = tt + 4 + quarter;
                    int s0 = __shfl(p.x, e0), s1 = __shfl(p.x, e1);
                    float av0 = __shfl(avf, e0), av1 = __shfl(avf, e1);
                    half4 v0 = *(const half4*)(h1h + (size_t)s0 * DIM + c4);
                    half4 v1 = *(const half4*)(h1h + (size_t)s1 * DIM + c4);
                    __half2 a2_0 = __half2half2(__float2half_rn(av0));
                    __half2 a2_1 = __half2half2(__float2half_rn(av1));
                    G1_ACC(v0, a2_0); G1_ACC(v1, a2_1);
                }
                for (; tt < cnt; tt += 4) {
                    int e0 = tt + quarter;
                    int es = min(e0, cnt - 1);
                    int s0 = __shfl(p.x, es);
                    float av0 = __shfl(avf, es);
                    if (e0 < cnt) {
                        half4 v0 = *(const half4*)(h1h + (size_t)s0 * DIM + c4);
                        __half2 a2_0 = __half2half2(__float2half_rn(av0));
                        G1_ACC(v0, a2_0);
                    }
                }
            }
        }
        float2 p0 = __half22float2(ah0), p1 = __half22float2(ah1);
        float a0 = p0.x, a1 = p0.y, a2 = p1.x, a3 = p1.y;
        a0 += __shfl_xor(a0, 16); a0 += __shfl_xor(a0, 32);
        a1 += __shfl_xor(a1, 16); a1 += __shfl_xor(a1, 32);
        a2 += __shfl_xor(a2, 16); a2 += __shfl_xor(a2, 32);
        a3 += __shfl_xor(a3, 16); a3 += __shfl_xor(a3, 32);
        if (quarter == 0) {
            if (n < NN) {
                half4 h = *(const half4*)(h1h + (size_t)n * DIM + c4);
                float2 f0 = __half22float2(h.a), f1 = __half22float2(h.b);
                a0 += f0.x; a1 += f0.y; a2 += f1.x; a3 += f1.y;
            }
            *(float4*)&u_s[r][c4] = make_float4(a0, a1, a2, a3);
        }
    }
    #undef G1_ACC
    __syncthreads();
    // GEMM: 64x64 outputs, 512 threads -> 8 outputs each (2 rows x 4 cols)
    const int cc = t & 15;
    const int r0 = (t >> 4) * 2;
    float acc[2][4];
    #pragma unroll
    for (int j = 0; j < 4; j++) {
        float bj = bvec[cc + 16 * j];
        acc[0][j] = bj; acc[1][j] = bj;
    }
    #pragma unroll 4
    for (int k = 0; k < DIM; k += 4) {
        float4 w0 = *(const float4*)&w_s[cc][k];
        float4 w1 = *(const float4*)&w_s[cc + 16][k];
        float4 w2 = *(const float4*)&w_s[cc + 32][k];
        float4 w3 = *(const float4*)&w_s[cc + 48][k];
        #pragma unroll
        for (int i = 0; i < 2; i++) {
            float4 u = *(const float4*)&u_s[r0 + i][k];
            acc[i][0] = fmaf(u.x, w0.x, fmaf(u.y, w0.y, fmaf(u.z, w0.z, fmaf(u.w, w0.w, acc[i][0]))));
            acc[i][1] = fmaf(u.x, w1.x, fmaf(u.y, w1.y, fmaf(u.z, w1.z, fmaf(u.w, w1.w, acc[i][1]))));
            acc[i][2] = fmaf(u.x, w2.x, fmaf(u.y, w2.y, fmaf(u.z, w2.z, fmaf(u.w, w2.w, acc[i][2]))));
            acc[i][3] = fmaf(u.x, w3.x, fmaf(u.y, w3.y, fmaf(u.z, w3.z, fmaf(u.w, w3.w, acc[i][3]))));
        }
    }
    float tv[2][4];
    #pragma unroll
    for (int i = 0; i < 2; i++) {
        int rr = row0 + r0 + i;
        #pragma unroll
        for (int j = 0; j < 4; j++) tv[i][j] = tanhf(acc[i][j]);
        if (rr < NN) {
            float* op = out + (size_t)rr * 192 + 64;
            #pragma unroll
            for (int j = 0; j < 4; j++) op[cc + 16 * j] = tv[i][j];
        }
    }
    // fused per-channel stats of t2 (reuse w_s)
    __syncthreads();
    float* red_s = (float*)w_s;
    float* red_q = red_s + 2048;
    const int rgp = t >> 4;
    bool ok0 = (row0 + r0 < NN), ok1 = (row0 + r0 + 1 < NN);
    #pragma unroll
    for (int j = 0; j < 4; j++) {
        float v0 = ok0 ? tv[0][j] : 0.f;
        float v1 = ok1 ? tv[1][j] : 0.f;
        red_s[rgp * 64 + cc + 16 * j] = v0 + v1;
        red_q[rgp * 64 + cc + 16 * j] = v0 * v0 + v1 * v1;
    }
    __syncthreads();
    if (t < 64) {
        float s = 0.f, q = 0.f;
        #pragma unroll
        for (int i = 0; i < 32; i++) { s += red_s[i * 64 + t]; q += red_q[i * 64 + t]; }
        int rep = blockIdx.x & (NREP - 1);
        atomicAdd(&dsum1[rep * DIM + t], (double)s);
        atomicAdd(&dsq1[rep * DIM + t], (double)q);
    }
}

// ---------------- fused: finalize1 + h2 = BN(t2) in place + h3 = tanh(h2 @ Wfc) ----------------
__global__ __launch_bounds__(256) void fc_kernel(float* __restrict__ io,
        const double* __restrict__ dsum, const double* __restrict__ dsq,
        const float* __restrict__ g, const float* __restrict__ b,
        const float* __restrict__ W) {
    __shared__ __align__(16) float u_s[64][DIM + 4];
    __shared__ __align__(16) float w_s[DIM][DIM + 4];
    __shared__ float sc_s[DIM], sh_s[DIM];
    const int t = threadIdx.x;
    const int row0 = blockIdx.x * 64;
    bn_fold_rep<DIM>(t, dsum, dsq, g, b, sc_s, sh_s);
    __syncthreads();
    for (int i = t; i < DIM * DIM; i += 256) {
        int k = i >> 6, c = i & 63;
        w_s[c][k] = W[i];
    }
    for (int i = t; i < 64 * DIM; i += 256) {
        int r = i >> 6, k = i & 63;
        int rr = row0 + r;
        float v = 0.f;
        if (rr < NN) {
            size_t idx = (size_t)rr * 192 + 64 + k;
            v = fmaf(io[idx], sc_s[k], sh_s[k]);
            io[idx] = v;                       // h2
        }
        u_s[r][k] = v;
    }
    __syncthreads();
    const int cc = t & 15;
    const int r0 = (t >> 4) << 2;
    float acc[4][4];
    #pragma unroll
    for (int j = 0; j < 4; j++) { acc[0][j] = 0.f; acc[1][j] = 0.f; acc[2][j] = 0.f; acc[3][j] = 0.f; }
    #pragma unroll 4
    for (int k = 0; k < DIM; k += 4) {
        float4 w0 = *(const float4*)&w_s[cc][k];
        float4 w1 = *(const float4*)&w_s[cc + 16][k];
        float4 w2 = *(const float4*)&w_s[cc + 32][k];
        float4 w3 = *(const float4*)&w_s[cc + 48][k];
        #pragma unroll
        for (int i = 0; i < 4; i++) {
            float4 u = *(const float4*)&u_s[r0 + i][k];
            acc[i][0] = fmaf(u.x, w0.x, fmaf(u.y, w0.y, fmaf(u.z, w0.z, fmaf(u.w, w0.w, acc[i][0]))));
            acc[i][1] = fmaf(u.x, w1.x, fmaf(u.y, w1.y, fmaf(u.z, w1.z, fmaf(u.w, w1.w, acc[i][1]))));
            acc[i][2] = fmaf(u.x, w2.x, fmaf(u.y, w2.y, fmaf(u.z, w2.z, fmaf(u.w, w2.w, acc[i][2]))));
            acc[i][3] = fmaf(u.x, w3.x, fmaf(u.y, w3.y, fmaf(u.z, w3.z, fmaf(u.w, w3.w, acc[i][3]))));
        }
    }
    #pragma unroll
    for (int i = 0; i < 4; i++) {
        int rr = row0 + r0 + i;
        if (rr < NN) {
            #pragma unroll
            for (int j = 0; j < 4; j++)
                io[(size_t)rr * 192 + 128 + cc + 16 * j] = tanhf(acc[i][j]);
        }
    }
}

extern "C" void kernel_launch(void* const* d_in, const int* in_sizes, int n_in,
                              void* d_out, int out_size, void* d_ws, size_t ws_size,
                              hipStream_t stream) {
    const float* X      = (const float*)d_in[0];
    const int*   ei     = (const int*)  d_in[1];
    const float* ea     = (const float*)d_in[2];
    const float* bng    = (const float*)d_in[3];
    const float* bnb    = (const float*)d_in[4];
    const float* We0    = (const float*)d_in[5];
    const float* be0    = (const float*)d_in[6];
    const float* W0     = (const float*)d_in[7];
    const float* b0     = (const float*)d_in[8];
    const float* bn0g   = (const float*)d_in[9];
    const float* bn0b   = (const float*)d_in[10];
    const float* We1    = (const float*)d_in[11];
    const float* be1    = (const float*)d_in[12];
    const float* W1     = (const float*)d_in[13];
    const float* b1     = (const float*)d_in[14];
    const float* bn1g   = (const float*)d_in[15];
    const float* bn1b   = (const float*)d_in[16];
    const float* Wfc    = (const float*)d_in[17];

    const int* src = ei;
    const int* dst = ei + NE;
    float* out = (float*)d_out;

    // ---- workspace layout (~56 MB); h1h aliases Xh (Xh dead after gine0) ----
    int2*   src_ea  = (int2*)d_ws;                        // NE
    __half* t1h     = (__half*)(src_ea + NE);             // NN*DIM halves
    __half* Xh      = t1h + (size_t)NN * DIM;             // NN*INC halves
    __half* h1h     = Xh;                                 // aliases Xh
    int*    counts  = (int*)(Xh + (size_t)NN * INC);      // NREP*NN
    int*    offs    = counts + (size_t)NREP * NN;         // NN+1
    int*    cursor  = offs + NN + 1;                      // NN
    int*    bsums   = cursor + NN;                        // 128
    double* dstats = (double*)(((uintptr_t)(bsums + 128) + 15) & ~(uintptr_t)15);
    double* dsum_in = dstats;                          // NREP*128
    double* dsq_in  = dsum_in + NREP * INC;            // NREP*128
    double* dsum0   = dsq_in + NREP * INC;             // NREP*64
    double* dsq0    = dsum0 + NREP * DIM;              // NREP*64
    double* dsum1   = dsq0 + NREP * DIM;               // NREP*64
    double* dsq1    = dsum1 + NREP * DIM;              // NREP*64
    const size_t nstats = (size_t)NREP * (2 * INC + 4 * DIM);

    // single memset: counts .. end of dstats (intermediate arrays harmlessly zeroed)
    size_t zbytes = (char*)(dstats + nstats) - (char*)counts;
    hipMemsetAsync(counts, 0, zbytes, stream);

    // fused input-BN stats + replicated dst histogram
    stats_hist_kernel<<<SB + (NE + 255) / 256, 256, 0, stream>>>(X, dst, counts, dsum_in, dsq_in);

    // fused x̂->fp16 + scan1 (both depend only on stats_hist)
    xhat_scan1_kernel<<<XB1024 + NB, 1024, 0, stream>>>(X, dsum_in, dsq_in, bng, bnb, Xh,
                                                        counts, offs, bsums);

    // scan2 folded into scan3
    scan23_kernel<<<(NN + 255) / 256, 256, 0, stream>>>(offs, bsums, cursor);

    // XCD-partitioned scatter (4 partitions)
    scatter_kernel<<<2048, 256, 0, stream>>>(src, dst, ea, cursor, src_ea);

    // layer 0 (fused agg + fp16-W GEMM + stats0), packed-fp16 gather math
    gine0_kernel<<<(NN + 31) / 32, 512, 0, stream>>>(X, Xh, offs, src_ea, dsum_in, dsq_in, bng, bnb,
                                                     We0, be0, W0, b0, t1h, dsum0, dsq0);

    // h1 = BN0(t1): f32 -> out[:,0:64], fp16 -> h1h (overwrites Xh, now dead)
    h1_kernel<<<(NN * DIM / 4 + 255) / 256, 256, 0, stream>>>(t1h, dsum0, dsq0, bn0g, bn0b, out, h1h);

    // layer 1 (fused agg of fp16 h1 + GEMM + stats1), packed-fp16 gather math
    gine1_kernel<<<(NN + 63) / 64, 512, 0, stream>>>(h1h, offs, src_ea, We1, be1, W1, b1,
                                                     out, dsum1, dsq1);

    // h2 (in place) + h3 (fused finalize1)
    fc_kernel<<<(NN + 63) / 64, 256, 0, stream>>>(out, dsum1, dsq1, bn1g, bn1b, Wfc);
}

// Round 18
// 399.594 us; speedup vs baseline: 1.2225x; 1.0177x over previous
//
#include <hip/hip_runtime.h>
#include <hip/hip_fp16.h>
#include <math.h>
#include <stdint.h>

#define NN 100000
#define NE 1600000
#define INC 128
#define DIM 64
#define EPS 1e-5f
#define SB 512    // stats blocks inside fused stats+hist kernel
#define NREP 8    // replicas for stats accumulators AND histogram counters
#define NPART 4   // scatter partitions (write set 12.8MB/4 = 3.2MB < 4MB L2)
#define PART_SZ ((NN + NPART - 1) / NPART)
#define XB1024 (NN * INC / 4 / 1024)   // 3125 xhat blocks (1024 thr, float4 each)
#define NB ((NN + 1023) / 1024)        // 98 scan chunks

struct __align__(8)  half4 { __half2 a, b; };
struct __align__(16) half8 { __half2 a, b, c, d; };

// packed fp16 max (ROCm header lacks __hmax2; emit v_pk_max_f16 directly)
__device__ inline __half2 h2max(__half2 a, __half2 b) {
    __half2 r;
    asm("v_pk_max_f16 %0, %1, %2" : "=v"(r) : "v"(a), "v"(b));
    return r;
}

// fused: blocks [0,SB) do X stats (C=128) in f64; blocks [SB,...) do replicated dst histogram
__global__ __launch_bounds__(256) void stats_hist_kernel(const float* __restrict__ X,
        const int* __restrict__ dst, int* __restrict__ counts,
        double* __restrict__ sum_out, double* __restrict__ sq_out) {
    __shared__ double ls[256], lq[256];
    if (blockIdx.x < SB) {
        int c  = threadIdx.x & 127;
        int rl = threadIdx.x >> 7;           // 2 rows per block step
        int row = blockIdx.x * 2 + rl;
        const int rstride = SB * 2;
        double s = 0.0, q = 0.0;
        for (int r = row; r < NN; r += rstride) {
            double v = (double)X[(size_t)r * INC + c];
            s += v; q += v * v;
        }
        ls[threadIdx.x] = s; lq[threadIdx.x] = q;
        __syncthreads();
        if (rl == 0) {
            s += ls[128 + c]; q += lq[128 + c];
            int rep = blockIdx.x & (NREP - 1);
            atomicAdd(&sum_out[rep * INC + c], s);
            atomicAdd(&sq_out[rep * INC + c], q);
        }
    } else {
        int bb = blockIdx.x - SB;
        int e = bb * 256 + threadIdx.x;
        if (e < NE) atomicAdd(&counts[(bb & (NREP - 1)) * NN + dst[e]], 1);
    }
}

// BN scale/shift from NREP-replicated f64 stats
template<int C>
__device__ inline void bn_fold_rep(int t, const double* dsum, const double* dsq,
                                   const float* g, const float* b, float* sc_s, float* sh_s) {
    if (t < C) {
        double s = 0.0, q = 0.0;
        #pragma unroll
        for (int r = 0; r < NREP; r++) { s += dsum[r * C + t]; q += dsq[r * C + t]; }
        double m = s / (double)NN;
        double v = q / (double)NN - m * m;
        double sc = (double)g[t] / sqrt(v + (double)EPS);
        sc_s[t] = (float)sc;
        sh_s[t] = (float)((double)b[t] - m * sc);
    }
}

// fused: blocks [0,XB1024) do x̂->fp16 (1024 thr, float4 each); blocks [XB1024,...) do scan1.
__global__ __launch_bounds__(1024) void xhat_scan1_kernel(const float* __restrict__ X,
        const double* __restrict__ dsum, const double* __restrict__ dsq,
        const float* __restrict__ g, const float* __restrict__ b,
        __half* __restrict__ Xh,
        const int* __restrict__ counts, int* __restrict__ offs, int* __restrict__ bsums) {
    if (blockIdx.x < XB1024) {
        __shared__ float sc_s[INC], sh_s[INC];
        bn_fold_rep<INC>(threadIdx.x, dsum, dsq, g, b, sc_s, sh_s);
        __syncthreads();
        size_t i = (size_t)blockIdx.x * 1024 + threadIdx.x;
        size_t e4 = i * 4;
        if (e4 >= (size_t)NN * INC) return;
        int c = (int)(e4 & 127);
        float4 x = *(const float4*)(X + e4);
        half4 h;
        h.a = __floats2half2_rn(fmaf(x.x, sc_s[c], sh_s[c]), fmaf(x.y, sc_s[c + 1], sh_s[c + 1]));
        h.b = __floats2half2_rn(fmaf(x.z, sc_s[c + 2], sh_s[c + 2]), fmaf(x.w, sc_s[c + 3], sh_s[c + 3]));
        *(half4*)(Xh + e4) = h;
    } else {
        __shared__ int tmp[2][1024];
        int t = threadIdx.x;
        int g1 = (blockIdx.x - XB1024) * 1024 + t;
        int v = 0;
        if (g1 < NN) {
            #pragma unroll
            for (int r = 0; r < NREP; r++) v += counts[r * NN + g1];
        }
        tmp[0][t] = v;
        __syncthreads();
        int pin = 0;
        for (int d = 1; d < 1024; d <<= 1) {
            int x = tmp[pin][t] + ((t >= d) ? tmp[pin][t - d] : 0);
            tmp[pin ^ 1][t] = x;
            pin ^= 1;
            __syncthreads();
        }
        int incl = tmp[pin][t];
        if (g1 < NN) offs[g1] = incl - v;
        if (t == 1023) bsums[blockIdx.x - XB1024] = incl;
    }
}

// scan2 folded in: each block redundantly scans raw bsums (98 entries) in LDS,
// then writes final offsets + cursors.
__global__ __launch_bounds__(256) void scan23_kernel(int* __restrict__ offs, const int* __restrict__ bsums,
                                                     int* __restrict__ cursor) {
    __shared__ int tmp[2][128];
    int t = threadIdx.x;
    if (t < 128) {
        int v = (t < NB) ? bsums[t] : 0;
        tmp[0][t] = v;
    }
    __syncthreads();
    int pin = 0;
    if (t < 128) {
        for (int d = 1; d < 128; d <<= 1) {
            int x = tmp[pin][t] + ((t >= d) ? tmp[pin][t - d] : 0);
            tmp[pin ^ 1][t] = x;
            pin ^= 1;
            __syncthreads();
        }
    } else {
        for (int d = 1; d < 128; d <<= 1) { pin ^= 1; __syncthreads(); }
    }
    __shared__ int excl[128];
    if (t < 128) excl[t] = tmp[pin][t] - ((t < NB) ? bsums[t] : 0);
    __syncthreads();
    int g = blockIdx.x * 256 + t;
    if (g < NN) {
        int o = offs[g] + excl[g >> 10];
        offs[g] = o;
        cursor[g] = o;
    }
    if (g == 0) offs[NN] = NE;
}

// XCD-partitioned scatter (standalone 2048-block grid, 4 partitions -> 2 XCDs each)
__global__ __launch_bounds__(256) void scatter_kernel(const int* __restrict__ src, const int* __restrict__ dst,
                                                      const float* __restrict__ ea, int* __restrict__ cursor,
                                                      int2* __restrict__ src_ea) {
    const int p = blockIdx.x & (NPART - 1);
    const int blk = blockIdx.x >> 2;
    const int nblk = gridDim.x >> 2;
    const int lo = p * PART_SZ;
    const int hi = min(NN, lo + PART_SZ);
    for (int e = blk * 256 + threadIdx.x; e < NE; e += nblk * 256) {
        int d = dst[e];
        if (d >= lo && d < hi) {
            int pos = atomicAdd(&cursor[d], 1);
            src_ea[pos] = make_int2(src[e], __float_as_int(ea[e]));
        }
    }
}

// h1 = BN0(t1): writes f32 to out[:,0:64] AND fp16 to h1h (gather table for gine1)
__global__ __launch_bounds__(256) void h1_kernel(const __half* __restrict__ t1h,
        const double* __restrict__ dsum, const double* __restrict__ dsq,
        const float* __restrict__ g, const float* __restrict__ b,
        float* __restrict__ out, __half* __restrict__ h1h) {
    __shared__ float sc_s[DIM], sh_s[DIM];
    bn_fold_rep<DIM>(threadIdx.x, dsum, dsq, g, b, sc_s, sh_s);
    __syncthreads();
    size_t i = (size_t)blockIdx.x * 256 + threadIdx.x;   // 4 channels per thread
    size_t e4 = i * 4;
    if (e4 >= (size_t)NN * DIM) return;
    int c = (int)(e4 & 63);
    size_t n = e4 >> 6;
    half4 tv = *(const half4*)(t1h + e4);
    float2 f0 = __half22float2(tv.a), f1 = __half22float2(tv.b);
    float h0 = fmaf(f0.x, sc_s[c],     sh_s[c]);
    float h1 = fmaf(f0.y, sc_s[c + 1], sh_s[c + 1]);
    float h2 = fmaf(f1.x, sc_s[c + 2], sh_s[c + 2]);
    float h3 = fmaf(f1.y, sc_s[c + 3], sh_s[c + 3]);
    *(float4*)(out + n * 192 + c) = make_float4(h0, h1, h2, h3);
    half4 hh;
    hh.a = __floats2half2_rn(h0, h1);
    hh.b = __floats2half2_rn(h2, h3);
    *(half4*)(h1h + e4) = hh;
}

// ---------------- fused layer 0: gather-agg (packed fp16, quarter-wave, 2-deep) + fp16-W GEMM + tanh + stats ----------------
// Self term taken from Xh (fp16) — no f32 X read, no bn_fold. 34.3KB LDS -> 4 blocks/CU.
__global__ __launch_bounds__(512, 8) void gine0_kernel(const __half* __restrict__ Xh,
        const int* __restrict__ offs, const int2* __restrict__ src_ea,
        const float* __restrict__ We, const float* __restrict__ be,
        const float* __restrict__ W, const float* __restrict__ bvec,
        __half* __restrict__ t1h, double* __restrict__ dsum0, double* __restrict__ dsq0) {
    __shared__ __align__(16) float  u_s[32][INC + 4];    // 16.9 KB (reused for stats reduce)
    __shared__ __align__(16) __half w_sh[DIM][INC + 8];  // 17.4 KB, fp16 W
    const int t = threadIdx.x;
    const int row0 = blockIdx.x * 32;
    for (int i = t; i < INC * DIM; i += 512) {
        int k = i >> 6, c = i & 63;
        w_sh[c][k] = __float2half_rn(W[i]);
    }
    __syncthreads();
    const int wid = t >> 6, l = t & 63;
    const int quarter = l >> 4;
    const int c8 = (l & 15) * 8;
    const __half2 z2 = __float2half2_rn(0.f);
    __half2 wvh0 = __floats2half2_rn(We[c8],     We[c8 + 1]);
    __half2 wvh1 = __floats2half2_rn(We[c8 + 2], We[c8 + 3]);
    __half2 wvh2 = __floats2half2_rn(We[c8 + 4], We[c8 + 5]);
    __half2 wvh3 = __floats2half2_rn(We[c8 + 6], We[c8 + 7]);
    __half2 bvh0 = __floats2half2_rn(be[c8],     be[c8 + 1]);
    __half2 bvh1 = __floats2half2_rn(be[c8 + 2], be[c8 + 3]);
    __half2 bvh2 = __floats2half2_rn(be[c8 + 4], be[c8 + 5]);
    __half2 bvh3 = __floats2half2_rn(be[c8 + 6], be[c8 + 7]);

    #define G0_ACC(vh, av2)  do { \
        ah0 = __hadd2(ah0, h2max(__hadd2((vh).a, __hfma2((av2), wvh0, bvh0)), z2)); \
        ah1 = __hadd2(ah1, h2max(__hadd2((vh).b, __hfma2((av2), wvh1, bvh1)), z2)); \
        ah2 = __hadd2(ah2, h2max(__hadd2((vh).c, __hfma2((av2), wvh2, bvh2)), z2)); \
        ah3 = __hadd2(ah3, h2max(__hadd2((vh).d, __hfma2((av2), wvh3, bvh3)), z2)); \
    } while (0)

    for (int nn = 0; nn < 4; ++nn) {
        int r = wid * 4 + nn;
        int n = row0 + r;
        __half2 ah0 = z2, ah1 = z2, ah2 = z2, ah3 = z2;
        if (n < NN) {
            int beg = offs[n], end = offs[n + 1];
            for (int base = beg; base < end; base += 64) {
                int j = base + l;
                int2 p = (j < end) ? src_ea[j] : make_int2(0, 0);
                float avf = __int_as_float(p.y);
                int cnt = min(64, end - base);
                int tt = 0;
                for (; tt + 8 <= cnt; tt += 8) {
                    int e0 = tt + quarter, e1 = tt + 4 + quarter;
                    int s0 = __shfl(p.x, e0), s1 = __shfl(p.x, e1);
                    float av0 = __shfl(avf, e0), av1 = __shfl(avf, e1);
                    half8 v0 = *(const half8*)(Xh + (size_t)s0 * INC + c8);
                    half8 v1 = *(const half8*)(Xh + (size_t)s1 * INC + c8);
                    __half2 a2_0 = __half2half2(__float2half_rn(av0));
                    __half2 a2_1 = __half2half2(__float2half_rn(av1));
                    G0_ACC(v0, a2_0); G0_ACC(v1, a2_1);
                }
                for (; tt < cnt; tt += 4) {
                    int e0 = tt + quarter;
                    int es = min(e0, cnt - 1);
                    int s0 = __shfl(p.x, es);
                    float av0 = __shfl(avf, es);
                    if (e0 < cnt) {
                        half8 v0 = *(const half8*)(Xh + (size_t)s0 * INC + c8);
                        __half2 a2_0 = __half2half2(__float2half_rn(av0));
                        G0_ACC(v0, a2_0);
                    }
                }
            }
        }
        float2 p0 = __half22float2(ah0), p1 = __half22float2(ah1);
        float2 p2 = __half22float2(ah2), p3 = __half22float2(ah3);
        float a0 = p0.x, a1 = p0.y, a2 = p1.x, a3 = p1.y;
        float a4 = p2.x, a5 = p2.y, a6 = p3.x, a7 = p3.y;
        a0 += __shfl_xor(a0, 16); a0 += __shfl_xor(a0, 32);
        a1 += __shfl_xor(a1, 16); a1 += __shfl_xor(a1, 32);
        a2 += __shfl_xor(a2, 16); a2 += __shfl_xor(a2, 32);
        a3 += __shfl_xor(a3, 16); a3 += __shfl_xor(a3, 32);
        a4 += __shfl_xor(a4, 16); a4 += __shfl_xor(a4, 32);
        a5 += __shfl_xor(a5, 16); a5 += __shfl_xor(a5, 32);
        a6 += __shfl_xor(a6, 16); a6 += __shfl_xor(a6, 32);
        a7 += __shfl_xor(a7, 16); a7 += __shfl_xor(a7, 32);
        if (quarter == 0) {
            if (n < NN) {
                // self term from fp16 x̂ (tiny δ, already BN'd)
                half8 xv = *(const half8*)(Xh + (size_t)n * INC + c8);
                float2 f0 = __half22float2(xv.a), f1 = __half22float2(xv.b);
                float2 f2 = __half22float2(xv.c), f3 = __half22float2(xv.d);
                a0 += f0.x; a1 += f0.y; a2 += f1.x; a3 += f1.y;
                a4 += f2.x; a5 += f2.y; a6 += f3.x; a7 += f3.y;
            }
            *(float4*)&u_s[r][c8]     = make_float4(a0, a1, a2, a3);
            *(float4*)&u_s[r][c8 + 4] = make_float4(a4, a5, a6, a7);
        }
    }
    #undef G0_ACC
    __syncthreads();
    // GEMM (fp16 weights)
    const int cc = t & 15;
    const int rg = t >> 4;
    float acc0 = bvec[cc], acc1 = bvec[cc + 16], acc2 = bvec[cc + 32], acc3 = bvec[cc + 48];
    #pragma unroll 2
    for (int k = 0; k < INC; k += 8) {
        float4 ua = *(const float4*)&u_s[rg][k];
        float4 ub = *(const float4*)&u_s[rg][k + 4];
        half8 w0 = *(const half8*)&w_sh[cc][k];
        half8 w1 = *(const half8*)&w_sh[cc + 16][k];
        half8 w2 = *(const half8*)&w_sh[cc + 32][k];
        half8 w3 = *(const half8*)&w_sh[cc + 48][k];
        float2 p;
        p = __half22float2(w0.a); acc0 = fmaf(ua.x, p.x, fmaf(ua.y, p.y, acc0));
        p = __half22float2(w0.b); acc0 = fmaf(ua.z, p.x, fmaf(ua.w, p.y, acc0));
        p = __half22float2(w0.c); acc0 = fmaf(ub.x, p.x, fmaf(ub.y, p.y, acc0));
        p = __half22float2(w0.d); acc0 = fmaf(ub.z, p.x, fmaf(ub.w, p.y, acc0));
        p = __half22float2(w1.a); acc1 = fmaf(ua.x, p.x, fmaf(ua.y, p.y, acc1));
        p = __half22float2(w1.b); acc1 = fmaf(ua.z, p.x, fmaf(ua.w, p.y, acc1));
        p = __half22float2(w1.c); acc1 = fmaf(ub.x, p.x, fmaf(ub.y, p.y, acc1));
        p = __half22float2(w1.d); acc1 = fmaf(ub.z, p.x, fmaf(ub.w, p.y, acc1));
        p = __half22float2(w2.a); acc2 = fmaf(ua.x, p.x, fmaf(ua.y, p.y, acc2));
        p = __half22float2(w2.b); acc2 = fmaf(ua.z, p.x, fmaf(ua.w, p.y, acc2));
        p = __half22float2(w2.c); acc2 = fmaf(ub.x, p.x, fmaf(ub.y, p.y, acc2));
        p = __half22float2(w2.d); acc2 = fmaf(ub.z, p.x, fmaf(ub.w, p.y, acc2));
        p = __half22float2(w3.a); acc3 = fmaf(ua.x, p.x, fmaf(ua.y, p.y, acc3));
        p = __half22float2(w3.b); acc3 = fmaf(ua.z, p.x, fmaf(ua.w, p.y, acc3));
        p = __half22float2(w3.c); acc3 = fmaf(ub.x, p.x, fmaf(ub.y, p.y, acc3));
        p = __half22float2(w3.d); acc3 = fmaf(ub.z, p.x, fmaf(ub.w, p.y, acc3));
    }
    int rr = row0 + rg;
    float t0 = tanhf(acc0), t1v = tanhf(acc1), t2v = tanhf(acc2), t3v = tanhf(acc3);
    if (rr < NN) {
        __half* op = t1h + (size_t)rr * DIM;
        op[cc]      = __float2half_rn(t0);
        op[cc + 16] = __float2half_rn(t1v);
        op[cc + 32] = __float2half_rn(t2v);
        op[cc + 48] = __float2half_rn(t3v);
    }
    __syncthreads();
    float* red_s = (float*)u_s;
    float* red_q = red_s + 2048;
    bool ok = (rr < NN);
    red_s[rg * 64 + cc]      = ok ? t0 : 0.f;
    red_s[rg * 64 + cc + 16] = ok ? t1v : 0.f;
    red_s[rg * 64 + cc + 32] = ok ? t2v : 0.f;
    red_s[rg * 64 + cc + 48] = ok ? t3v : 0.f;
    red_q[rg * 64 + cc]      = ok ? t0 * t0 : 0.f;
    red_q[rg * 64 + cc + 16] = ok ? t1v * t1v : 0.f;
    red_q[rg * 64 + cc + 32] = ok ? t2v * t2v : 0.f;
    red_q[rg * 64 + cc + 48] = ok ? t3v * t3v : 0.f;
    __syncthreads();
    if (t < 64) {
        float s = 0.f, q = 0.f;
        #pragma unroll
        for (int i = 0; i < 32; i++) { s += red_s[i * 64 + t]; q += red_q[i * 64 + t]; }
        int rep = blockIdx.x & (NREP - 1);
        atomicAdd(&dsum0[rep * DIM + t], (double)s);
        atomicAdd(&dsq0[rep * DIM + t], (double)q);
    }
}

// ---------------- fused layer 1: gather-agg of fp16 h1 (packed fp16, 2-deep) + GEMM + tanh + stats ----------------
__global__ __launch_bounds__(512, 8) void gine1_kernel(const __half* __restrict__ h1h,
        const int* __restrict__ offs, const int2* __restrict__ src_ea,
        const float* __restrict__ We, const float* __restrict__ be,
        const float* __restrict__ W, const float* __restrict__ bvec,
        float* __restrict__ out, double* __restrict__ dsum1, double* __restrict__ dsq1) {
    __shared__ __align__(16) float u_s[64][DIM + 4];   // 17.4 KB
    __shared__ __align__(16) float w_s[DIM][DIM + 4];  // 17.4 KB (reused for stats reduce)
    const int t = threadIdx.x;
    const int row0 = blockIdx.x * 64;
    for (int i = t; i < DIM * DIM; i += 512) {
        int k = i >> 6, c = i & 63;
        w_s[c][k] = W[i];
    }
    __syncthreads();
    const int wid = t >> 6, l = t & 63;
    const int quarter = l >> 4;
    const int c4 = (l & 15) * 4;
    const __half2 z2 = __float2half2_rn(0.f);
    __half2 wvh0 = __floats2half2_rn(We[c4],     We[c4 + 1]);
    __half2 wvh1 = __floats2half2_rn(We[c4 + 2], We[c4 + 3]);
    __half2 bvh0 = __floats2half2_rn(be[c4],     be[c4 + 1]);
    __half2 bvh1 = __floats2half2_rn(be[c4 + 2], be[c4 + 3]);

    #define G1_ACC(vh, av2)  do { \
        ah0 = __hadd2(ah0, h2max(__hadd2((vh).a, __hfma2((av2), wvh0, bvh0)), z2)); \
        ah1 = __hadd2(ah1, h2max(__hadd2((vh).b, __hfma2((av2), wvh1, bvh1)), z2)); \
    } while (0)

    for (int nn = 0; nn < 8; ++nn) {
        int r = wid * 8 + nn;
        int n = row0 + r;
        __half2 ah0 = z2, ah1 = z2;
        if (n < NN) {
            int beg = offs[n], end = offs[n + 1];
            for (int base = beg; base < end; base += 64) {
                int j = base + l;
                int2 p = (j < end) ? src_ea[j] : make_int2(0, 0);
                float avf = __int_as_float(p.y);
                int cnt = min(64, end - base);
                int tt = 0;
                for (; tt + 8 <= cnt; tt += 8) {
                    int e0 = tt + quarter, e1 = tt + 4 + quarter;
                    int s0 = __shfl(p.x, e0), s1 = __shfl(p.x, e1);
                    float av0 = __shfl(avf, e0), av1 = __shfl(avf, e1);
                    half4 v0 = *(const half4*)(h1h + (size_t)s0 * DIM + c4);
                    half4 v1 = *(const half4*)(h1h + (size_t)s1 * DIM + c4);
                    __half2 a2_0 = __half2half2(__float2half_rn(av0));
                    __half2 a2_1 = __half2half2(__float2half_rn(av1));
                    G1_ACC(v0, a2_0); G1_ACC(v1, a2_1);
                }
                for (; tt < cnt; tt += 4) {
                    int e0 = tt + quarter;
                    int es = min(e0, cnt - 1);
                    int s0 = __shfl(p.x, es);
                    float av0 = __shfl(avf, es);
                    if (e0 < cnt) {
                        half4 v0 = *(const half4*)(h1h + (size_t)s0 * DIM + c4);
                        __half2 a2_0 = __half2half2(__float2half_rn(av0));
                        G1_ACC(v0, a2_0);
                    }
                }
            }
        }
        float2 p0 = __half22float2(ah0), p1 = __half22float2(ah1);
        float a0 = p0.x, a1 = p0.y, a2 = p1.x, a3 = p1.y;
        a0 += __shfl_xor(a0, 16); a0 += __shfl_xor(a0, 32);
        a1 += __shfl_xor(a1, 16); a1 += __shfl_xor(a1, 32);
        a2 += __shfl_xor(a2, 16); a2 += __shfl_xor(a2, 32);
        a3 += __shfl_xor(a3, 16); a3 += __shfl_xor(a3, 32);
        if (quarter == 0) {
            if (n < NN) {
                half4 h = *(const half4*)(h1h + (size_t)n * DIM + c4);
                float2 f0 = __half22float2(h.a), f1 = __half22float2(h.b);
                a0 += f0.x; a1 += f0.y; a2 += f1.x; a3 += f1.y;
            }
            *(float4*)&u_s[r][c4] = make_float4(a0, a1, a2, a3);
        }
    }
    #undef G1_ACC
    __syncthreads();
    // GEMM: 64x64 outputs, 512 threads -> 8 outputs each (2 rows x 4 cols)
    const int cc = t & 15;
    const int r0 = (t >> 4) * 2;
    float acc[2][4];
    #pragma unroll
    for (int j = 0; j < 4; j++) {
        float bj = bvec[cc + 16 * j];
        acc[0][j] = bj; acc[1][j] = bj;
    }
    #pragma unroll 4
    for (int k = 0; k < DIM; k += 4) {
        float4 w0 = *(const float4*)&w_s[cc][k];
        float4 w1 = *(const float4*)&w_s[cc + 16][k];
        float4 w2 = *(const float4*)&w_s[cc + 32][k];
        float4 w3 = *(const float4*)&w_s[cc + 48][k];
        #pragma unroll
        for (int i = 0; i < 2; i++) {
            float4 u = *(const float4*)&u_s[r0 + i][k];
            acc[i][0] = fmaf(u.x, w0.x, fmaf(u.y, w0.y, fmaf(u.z, w0.z, fmaf(u.w, w0.w, acc[i][0]))));
            acc[i][1] = fmaf(u.x, w1.x, fmaf(u.y, w1.y, fmaf(u.z, w1.z, fmaf(u.w, w1.w, acc[i][1]))));
            acc[i][2] = fmaf(u.x, w2.x, fmaf(u.y, w2.y, fmaf(u.z, w2.z, fmaf(u.w, w2.w, acc[i][2]))));
            acc[i][3] = fmaf(u.x, w3.x, fmaf(u.y, w3.y, fmaf(u.z, w3.z, fmaf(u.w, w3.w, acc[i][3]))));
        }
    }
    float tv[2][4];
    #pragma unroll
    for (int i = 0; i < 2; i++) {
        int rr = row0 + r0 + i;
        #pragma unroll
        for (int j = 0; j < 4; j++) tv[i][j] = tanhf(acc[i][j]);
        if (rr < NN) {
            float* op = out + (size_t)rr * 192 + 64;
            #pragma unroll
            for (int j = 0; j < 4; j++) op[cc + 16 * j] = tv[i][j];
        }
    }
    // fused per-channel stats of t2 (reuse w_s)
    __syncthreads();
    float* red_s = (float*)w_s;
    float* red_q = red_s + 2048;
    const int rgp = t >> 4;
    bool ok0 = (row0 + r0 < NN), ok1 = (row0 + r0 + 1 < NN);
    #pragma unroll
    for (int j = 0; j < 4; j++) {
        float v0 = ok0 ? tv[0][j] : 0.f;
        float v1 = ok1 ? tv[1][j] : 0.f;
        red_s[rgp * 64 + cc + 16 * j] = v0 + v1;
        red_q[rgp * 64 + cc + 16 * j] = v0 * v0 + v1 * v1;
    }
    __syncthreads();
    if (t < 64) {
        float s = 0.f, q = 0.f;
        #pragma unroll
        for (int i = 0; i < 32; i++) { s += red_s[i * 64 + t]; q += red_q[i * 64 + t]; }
        int rep = blockIdx.x & (NREP - 1);
        atomicAdd(&dsum1[rep * DIM + t], (double)s);
        atomicAdd(&dsq1[rep * DIM + t], (double)q);
    }
}

// ---------------- fused: finalize1 + h2 = BN(t2) in place + h3 = tanh(h2 @ Wfc) ----------------
__global__ __launch_bounds__(256) void fc_kernel(float* __restrict__ io,
        const double* __restrict__ dsum, const double* __restrict__ dsq,
        const float* __restrict__ g, const float* __restrict__ b,
        const float* __restrict__ W) {
    __shared__ __align__(16) float u_s[64][DIM + 4];
    __shared__ __align__(16) float w_s[DIM][DIM + 4];
    __shared__ float sc_s[DIM], sh_s[DIM];
    const int t = threadIdx.x;
    const int row0 = blockIdx.x * 64;
    bn_fold_rep<DIM>(t, dsum, dsq, g, b, sc_s, sh_s);
    __syncthreads();
    for (int i = t; i < DIM * DIM; i += 256) {
        int k = i >> 6, c = i & 63;
        w_s[c][k] = W[i];
    }
    for (int i = t; i < 64 * DIM; i += 256) {
        int r = i >> 6, k = i & 63;
        int rr = row0 + r;
        float v = 0.f;
        if (rr < NN) {
            size_t idx = (size_t)rr * 192 + 64 + k;
            v = fmaf(io[idx], sc_s[k], sh_s[k]);
            io[idx] = v;                       // h2
        }
        u_s[r][k] = v;
    }
    __syncthreads();
    const int cc = t & 15;
    const int r0 = (t >> 4) << 2;
    float acc[4][4];
    #pragma unroll
    for (int j = 0; j < 4; j++) { acc[0][j] = 0.f; acc[1][j] = 0.f; acc[2][j] = 0.f; acc[3][j] = 0.f; }
    #pragma unroll 4
    for (int k = 0; k < DIM; k += 4) {
        float4 w0 = *(const float4*)&w_s[cc][k];
        float4 w1 = *(const float4*)&w_s[cc + 16][k];
        float4 w2 = *(const float4*)&w_s[cc + 32][k];
        float4 w3 = *(const float4*)&w_s[cc + 48][k];
        #pragma unroll
        for (int i = 0; i < 4; i++) {
            float4 u = *(const float4*)&u_s[r0 + i][k];
            acc[i][0] = fmaf(u.x, w0.x, fmaf(u.y, w0.y, fmaf(u.z, w0.z, fmaf(u.w, w0.w, acc[i][0]))));
            acc[i][1] = fmaf(u.x, w1.x, fmaf(u.y, w1.y, fmaf(u.z, w1.z, fmaf(u.w, w1.w, acc[i][1]))));
            acc[i][2] = fmaf(u.x, w2.x, fmaf(u.y, w2.y, fmaf(u.z, w2.z, fmaf(u.w, w2.w, acc[i][2]))));
            acc[i][3] = fmaf(u.x, w3.x, fmaf(u.y, w3.y, fmaf(u.z, w3.z, fmaf(u.w, w3.w, acc[i][3]))));
        }
    }
    #pragma unroll
    for (int i = 0; i < 4; i++) {
        int rr = row0 + r0 + i;
        if (rr < NN) {
            #pragma unroll
            for (int j = 0; j < 4; j++)
                io[(size_t)rr * 192 + 128 + cc + 16 * j] = tanhf(acc[i][j]);
        }
    }
}

extern "C" void kernel_launch(void* const* d_in, const int* in_sizes, int n_in,
                              void* d_out, int out_size, void* d_ws, size_t ws_size,
                              hipStream_t stream) {
    const float* X      = (const float*)d_in[0];
    const int*   ei     = (const int*)  d_in[1];
    const float* ea     = (const float*)d_in[2];
    const float* bng    = (const float*)d_in[3];
    const float* bnb    = (const float*)d_in[4];
    const float* We0    = (const float*)d_in[5];
    const float* be0    = (const float*)d_in[6];
    const float* W0     = (const float*)d_in[7];
    const float* b0     = (const float*)d_in[8];
    const float* bn0g   = (const float*)d_in[9];
    const float* bn0b   = (const float*)d_in[10];
    const float* We1    = (const float*)d_in[11];
    const float* be1    = (const float*)d_in[12];
    const float* W1     = (const float*)d_in[13];
    const float* b1     = (const float*)d_in[14];
    const float* bn1g   = (const float*)d_in[15];
    const float* bn1b   = (const float*)d_in[16];
    const float* Wfc    = (const float*)d_in[17];

    const int* src = ei;
    const int* dst = ei + NE;
    float* out = (float*)d_out;

    // ---- workspace layout (~56 MB); h1h aliases Xh (Xh dead after gine0) ----
    int2*   src_ea  = (int2*)d_ws;                        // NE
    __half* t1h     = (__half*)(src_ea + NE);             // NN*DIM halves
    __half* Xh      = t1h + (size_t)NN * DIM;             // NN*INC halves
    __half* h1h     = Xh;                                 // aliases Xh
    int*    counts  = (int*)(Xh + (size_t)NN * INC);      // NREP*NN
    int*    offs    = counts + (size_t)NREP * NN;         // NN+1
    int*    cursor  = offs + NN + 1;                      // NN
    int*    bsums   = cursor + NN;                        // 128
    double* dstats = (double*)(((uintptr_t)(bsums + 128) + 15) & ~(uintptr_t)15);
    double* dsum_in = dstats;                          // NREP*128
    double* dsq_in  = dsum_in + NREP * INC;            // NREP*128
    double* dsum0   = dsq_in + NREP * INC;             // NREP*64
    double* dsq0    = dsum0 + NREP * DIM;              // NREP*64
    double* dsum1   = dsq0 + NREP * DIM;               // NREP*64
    double* dsq1    = dsum1 + NREP * DIM;              // NREP*64
    const size_t nstats = (size_t)NREP * (2 * INC + 4 * DIM);

    // single memset: counts .. end of dstats
    size_t zbytes = (char*)(dstats + nstats) - (char*)counts;
    hipMemsetAsync(counts, 0, zbytes, stream);

    // fused input-BN stats + replicated dst histogram
    stats_hist_kernel<<<SB + (NE + 255) / 256, 256, 0, stream>>>(X, dst, counts, dsum_in, dsq_in);

    // fused x̂->fp16 + scan1
    xhat_scan1_kernel<<<XB1024 + NB, 1024, 0, stream>>>(X, dsum_in, dsq_in, bng, bnb, Xh,
                                                        counts, offs, bsums);

    // scan2 folded into scan3
    scan23_kernel<<<(NN + 255) / 256, 256, 0, stream>>>(offs, bsums, cursor);

    // XCD-partitioned scatter (4 partitions)
    scatter_kernel<<<2048, 256, 0, stream>>>(src, dst, ea, cursor, src_ea);

    // layer 0 (fused agg + fp16-W GEMM + stats0), all-fp16 inputs
    gine0_kernel<<<(NN + 31) / 32, 512, 0, stream>>>(Xh, offs, src_ea,
                                                     We0, be0, W0, b0, t1h, dsum0, dsq0);

    // h1 = BN0(t1): f32 -> out[:,0:64], fp16 -> h1h (overwrites Xh, now dead)
    h1_kernel<<<(NN * DIM / 4 + 255) / 256, 256, 0, stream>>>(t1h, dsum0, dsq0, bn0g, bn0b, out, h1h);

    // layer 1 (fused agg of fp16 h1 + GEMM + stats1), packed-fp16 gather math
    gine1_kernel<<<(NN + 63) / 64, 512, 0, stream>>>(h1h, offs, src_ea, We1, be1, W1, b1,
                                                     out, dsum1, dsq1);

    // h2 (in place) + h3 (fused finalize1)
    fc_kernel<<<(NN + 63) / 64, 256, 0, stream>>>(out, dsum1, dsq1, bn1g, bn1b, Wfc);
}